// Round 1
// baseline (2046.844 us; speedup 1.0000x reference)
//
#include <hip/hip_runtime.h>
#include <hip/hip_bf16.h>
#include <math.h>

constexpr int IN_DIM  = 768;
constexpr int HID     = 128;
constexpr int HEADS   = 4;
constexpr int OUT_DIM = 256;
constexpr int SEM     = 512;     // HID*HEADS
constexpr int N_USER  = 50000;
constexpr int N_LLM   = 5000;
constexpr int NE      = 400000;

static inline int cdiv(int a, int b) { return (a + b - 1) / b; }

// ---------------- generic fp32 GEMM: C[M,N] = A[M,K] @ B[K,N] (+bias) ------
// 64x64 tile, BK=16, 256 threads, 4x4 per thread. K%16==0, N%64==0 required.
__global__ __launch_bounds__(256) void gemm_f32(
    const float* __restrict__ A, const float* __restrict__ B,
    float* __restrict__ C, const float* __restrict__ bias,
    int M, int N, int K)
{
  __shared__ float As[16][68];   // [k][m], padded to 68 (16B-aligned rows)
  __shared__ float Bs[16][64];   // [k][n]
  const int t  = threadIdx.x;
  const int bm = blockIdx.y * 64;
  const int bn = blockIdx.x * 64;
  const int tm = t >> 4;           // 0..15
  const int tn = t & 15;           // 0..15
  const int arow = t >> 2;         // 0..63
  const int acol = (t & 3) * 4;    // 0,4,8,12
  const int brow = t >> 4;         // 0..15
  const int bcol = (t & 15) * 4;   // 0..60

  float acc[4][4] = {};

  for (int k0 = 0; k0 < K; k0 += 16) {
    float4 av = make_float4(0.f, 0.f, 0.f, 0.f);
    int gar = bm + arow;
    if (gar < M) av = *(const float4*)(A + (size_t)gar * K + k0 + acol);
    As[acol + 0][arow] = av.x;
    As[acol + 1][arow] = av.y;
    As[acol + 2][arow] = av.z;
    As[acol + 3][arow] = av.w;
    float4 bv = *(const float4*)(B + (size_t)(k0 + brow) * N + bn + bcol);
    *(float4*)&Bs[brow][bcol] = bv;
    __syncthreads();
#pragma unroll
    for (int k = 0; k < 16; ++k) {
      float4 a = *(const float4*)&As[k][tm * 4];
      float4 b = *(const float4*)&Bs[k][tn * 4];
      acc[0][0] += a.x * b.x; acc[0][1] += a.x * b.y; acc[0][2] += a.x * b.z; acc[0][3] += a.x * b.w;
      acc[1][0] += a.y * b.x; acc[1][1] += a.y * b.y; acc[1][2] += a.y * b.z; acc[1][3] += a.y * b.w;
      acc[2][0] += a.z * b.x; acc[2][1] += a.z * b.y; acc[2][2] += a.z * b.z; acc[2][3] += a.z * b.w;
      acc[3][0] += a.w * b.x; acc[3][1] += a.w * b.y; acc[3][2] += a.w * b.z; acc[3][3] += a.w * b.w;
    }
    __syncthreads();
  }

#pragma unroll
  for (int i = 0; i < 4; ++i) {
    int r = bm + tm * 4 + i;
    if (r >= M) continue;
    float4 v = make_float4(acc[i][0], acc[i][1], acc[i][2], acc[i][3]);
    if (bias) {
      const float* bp = bias + bn + tn * 4;
      v.x += bp[0]; v.y += bp[1]; v.z += bp[2]; v.w += bp[3];
    }
    *(float4*)(C + (size_t)r * N + bn + tn * 4) = v;
  }
}

// ------------- fold Wdst (768x512) against adst (4x128) -> wfold[768][8] ----
__global__ void fold_kernel(const float* __restrict__ Wdst0, const float* __restrict__ adst0,
                            const float* __restrict__ Wdst1, const float* __restrict__ adst1,
                            float* __restrict__ wfold)
{
  int idx = blockIdx.x * 256 + threadIdx.x;   // 768*8
  if (idx >= IN_DIM * 8) return;
  int k = idx >> 3, hh = idx & 7;
  const float* W   = (hh < 4) ? Wdst0 : Wdst1;
  const float* att = (hh < 4) ? adst0 : adst1;
  int h = hh & 3;
  float s = 0.f;
#pragma unroll 4
  for (int c = 0; c < HID; ++c)
    s += W[(size_t)k * SEM + h * HID + c] * att[h * HID + c];
  wfold[idx] = s;
}

// -------- a_d[p][n][4] = x_user[n,:] @ wfold[:, p*4+h]  (wave per node) -----
__global__ __launch_bounds__(256) void ad_kernel(
    const float* __restrict__ x, const float* __restrict__ wfold,
    float* __restrict__ a_d, int n)
{
  int wid = threadIdx.x >> 6, lane = threadIdx.x & 63;
  int node = blockIdx.x * 4 + wid;
  if (node >= n) return;
  float acc[8] = {};
  for (int kk = lane; kk < IN_DIM; kk += 64) {
    float xv = x[(size_t)node * IN_DIM + kk];
    const float* wf = wfold + kk * 8;
#pragma unroll
    for (int h = 0; h < 8; ++h) acc[h] += xv * wf[h];
  }
#pragma unroll
  for (int off = 32; off > 0; off >>= 1) {
#pragma unroll
    for (int h = 0; h < 8; ++h) acc[h] += __shfl_down(acc[h], off);
  }
  if (lane == 0) {
#pragma unroll
    for (int h = 0; h < 4; ++h) a_d[(size_t)node * 4 + h] = acc[h];
#pragma unroll
    for (int h = 0; h < 4; ++h) a_d[(size_t)N_USER * 4 + (size_t)node * 4 + h] = acc[4 + h];
  }
}

// -------- a_s[n][4] = sum_c hs[n, h*128+c] * att[h*128+c] ------------------
__global__ __launch_bounds__(256) void as_kernel(
    const float* __restrict__ hs, const float* __restrict__ att,
    float* __restrict__ a_s, int n)
{
  __shared__ float sm[512];
  int node = blockIdx.x;
  int t = threadIdx.x;
  const float* hr = hs + (size_t)node * SEM;
  sm[t]       = hr[t]       * att[t];
  sm[t + 256] = hr[t + 256] * att[t + 256];
  __syncthreads();
  int seg = t >> 7, lane = t & 127;   // seg 0..1
  for (int off = 64; off > 0; off >>= 1) {
    if (lane < off) {
      sm[seg * 128 + lane]       += sm[seg * 128 + lane + off];
      sm[(seg + 2) * 128 + lane] += sm[(seg + 2) * 128 + lane + off];
    }
    __syncthreads();
  }
  if (t < 4) a_s[(size_t)node * 4 + t] = sm[t * 128];
}

// -------- per-edge: ex = exp(leaky_relu(a_s[src]+a_d[dst])), denom, deg ----
__global__ void edge_kernel(const int* __restrict__ src, const int* __restrict__ dst,
                            const float* __restrict__ a_s, const float* __restrict__ a_d,
                            float* __restrict__ ex, float* __restrict__ denom,
                            int* __restrict__ deg, int E)
{
  int e = blockIdx.x * 256 + threadIdx.x;
  if (e >= E) return;
  int s = src[e], d = dst[e];
  float4 as4 = *(const float4*)(a_s + (size_t)s * 4);
  float4 ad4 = *(const float4*)(a_d + (size_t)d * 4);
  float v[4] = { as4.x + ad4.x, as4.y + ad4.y, as4.z + ad4.z, as4.w + ad4.w };
  float ev[4];
#pragma unroll
  for (int h = 0; h < 4; ++h) {
    float x = v[h];
    x = (x > 0.f) ? x : 0.2f * x;       // leaky_relu(0.2)
    ev[h] = expf(x);                    // no max-subtraction: shift-invariant
    atomicAdd(&denom[(size_t)d * 4 + h], ev[h]);
  }
  *(float4*)(ex + (size_t)e * 4) = make_float4(ev[0], ev[1], ev[2], ev[3]);
  atomicAdd(&deg[d], 1);
}

// -------- single-block exclusive scan: deg[n] -> row_ptr[n+1] --------------
__global__ __launch_bounds__(1024) void scan_kernel(
    const int* __restrict__ deg, int* __restrict__ row_ptr, int n)
{
  __shared__ int sm[1024];
  __shared__ int carry_s;
  int t = threadIdx.x;
  if (t == 0) carry_s = 0;
  __syncthreads();
  for (int base = 0; base < n; base += 1024) {
    int v = (base + t < n) ? deg[base + t] : 0;
    sm[t] = v;
    __syncthreads();
    for (int off = 1; off < 1024; off <<= 1) {
      int x = (t >= off) ? sm[t - off] : 0;
      __syncthreads();
      sm[t] += x;
      __syncthreads();
    }
    int incl = sm[t];
    int c = carry_s;
    if (base + t < n) row_ptr[base + t] = c + incl - v;
    __syncthreads();
    if (t == 1023) carry_s = c + sm[1023];
    __syncthreads();
  }
  if (t == 0) row_ptr[n] = carry_s;
}

// -------- scatter edges into CSR order -------------------------------------
__global__ void scatter_kernel(const int* __restrict__ dst, const int* __restrict__ row_ptr,
                               int* __restrict__ cursor, int* __restrict__ edge_idx, int E)
{
  int e = blockIdx.x * 256 + threadIdx.x;
  if (e >= E) return;
  int d = dst[e];
  int pos = row_ptr[d] + atomicAdd(&cursor[d], 1);
  edge_idx[pos] = e;
}

// -------- aggregation (block per dst node): z = elu(sum alpha*hs + bias) ---
__global__ __launch_bounds__(256) void agg_kernel(
    const float* __restrict__ hs, const float* __restrict__ ex,
    const float* __restrict__ denom, const int* __restrict__ row_ptr,
    const int* __restrict__ edge_idx, const int* __restrict__ src,
    const float* __restrict__ bias, float* __restrict__ Zout)
{
  int node = blockIdx.x;
  int t = threadIdx.x;
  int ch0 = t, ch1 = t + 256;
  int h0 = ch0 >> 7, h1 = ch1 >> 7;
  float invd0 = 1.f / (denom[(size_t)node * 4 + h0] + 1e-16f);
  float invd1 = 1.f / (denom[(size_t)node * 4 + h1] + 1e-16f);
  float acc0 = 0.f, acc1 = 0.f;
  int jb = row_ptr[node], je = row_ptr[node + 1];
  for (int j = jb; j < je; ++j) {
    int e = edge_idx[j];
    int s = src[e];
    float al0 = ex[(size_t)e * 4 + h0] * invd0;
    float al1 = ex[(size_t)e * 4 + h1] * invd1;
    const float* hr = hs + (size_t)s * SEM;
    acc0 += hr[ch0] * al0;
    acc1 += hr[ch1] * al1;
  }
  float z0 = acc0 + bias[ch0];
  float z1 = acc1 + bias[ch1];
  z0 = (z0 > 0.f) ? z0 : expm1f(z0);   // ELU
  z1 = (z1 > 0.f) ? z1 : expm1f(z1);
  Zout[(size_t)node * SEM + ch0] = z0;
  Zout[(size_t)node * SEM + ch1] = z1;
}

// -------- semantic attention combine: z_final overwrites Z[0:N_USER] -------
__global__ __launch_bounds__(256) void combine_kernel(
    const float* __restrict__ T, const float* __restrict__ b1,
    const float* __restrict__ W2, float* __restrict__ Z)
{
  __shared__ float red[256];
  __shared__ float beta[2];
  int node = blockIdx.x, t = threadIdx.x;
  int p = t >> 7, j = t & 127;
  float val = tanhf(T[(size_t)(p * N_USER + node) * HID + j] + b1[j]) * W2[j];
  red[t] = val;
  __syncthreads();
  for (int off = 64; off > 0; off >>= 1) {
    if (j < off) red[t] += red[t + off];
    __syncthreads();
  }
  if (t == 0) {
    float w0 = red[0], w1 = red[128];
    float mx = fmaxf(w0, w1);
    float e0 = expf(w0 - mx), e1 = expf(w1 - mx);
    float s = e0 + e1;
    beta[0] = e0 / s; beta[1] = e1 / s;
  }
  __syncthreads();
  float b0v = beta[0], b1v = beta[1];
  size_t i0 = (size_t)node * SEM;
  size_t i1 = (size_t)(N_USER + node) * SEM;
  float zf0 = b0v * Z[i0 + t]       + b1v * Z[i1 + t];
  float zf1 = b0v * Z[i0 + t + 256] + b1v * Z[i1 + t + 256];
  Z[i0 + t]       = zf0;
  Z[i0 + t + 256] = zf1;
}

extern "C" void kernel_launch(void* const* d_in, const int* in_sizes, int n_in,
                              void* d_out, int out_size, void* d_ws, size_t ws_size,
                              hipStream_t stream)
{
  const float* x_user = (const float*)d_in[0];
  const float* x_llm  = (const float*)d_in[1];
  const int* src0 = (const int*)d_in[2];
  const int* dst0 = (const int*)d_in[3];
  const int* src1 = (const int*)d_in[4];
  const int* dst1 = (const int*)d_in[5];
  const float* Wsrc0 = (const float*)d_in[6];
  const float* Wdst0 = (const float*)d_in[7];
  const float* asrc0 = (const float*)d_in[8];
  const float* adst0 = (const float*)d_in[9];
  const float* bias0 = (const float*)d_in[10];
  const float* Wsrc1 = (const float*)d_in[11];
  const float* Wdst1 = (const float*)d_in[12];
  const float* asrc1 = (const float*)d_in[13];
  const float* adst1 = (const float*)d_in[14];
  const float* bias1 = (const float*)d_in[15];
  const float* sem_W1 = (const float*)d_in[16];
  const float* sem_b1 = (const float*)d_in[17];
  const float* sem_W2 = (const float*)d_in[18];
  const float* out_W  = (const float*)d_in[19];
  const float* out_b  = (const float*)d_in[20];

  char* ws = (char*)d_ws;
  size_t off = 0;
  auto alloc = [&](size_t bytes) -> size_t {
    size_t o = off;
    off += (bytes + 255) & ~(size_t)255;
    return o;
  };

  size_t hs0_off   = alloc((size_t)N_LLM  * SEM * 4);       // 10.24 MB
  size_t hs1_off   = alloc((size_t)N_USER * SEM * 4);       // 102.4 MB
  size_t Z_off     = alloc((size_t)2 * N_USER * SEM * 4);   // 204.8 MB
  size_t ex0_off   = alloc((size_t)NE * 4 * 4);             // 6.4 MB
  size_t ex1_off   = alloc((size_t)NE * 4 * 4);             // 6.4 MB
  size_t as0_off   = alloc((size_t)N_LLM  * 4 * 4);
  size_t as1_off   = alloc((size_t)N_USER * 4 * 4);
  size_t ad_off    = alloc((size_t)2 * N_USER * 4 * 4);
  size_t wfold_off = alloc((size_t)IN_DIM * 8 * 4);
  size_t denom_off = alloc((size_t)2 * N_USER * 4 * 4);     // zeroed
  size_t deg_off   = alloc((size_t)2 * N_USER * 4);         // zeroed
  size_t cur_off   = alloc((size_t)2 * N_USER * 4);         // zeroed
  size_t zero_end  = off;
  size_t rp_off    = alloc((size_t)2 * (N_USER + 8) * 4);
  size_t ei_off    = alloc((size_t)2 * NE * 4);
  // T overlays the (dead by then) hs0+hs1 region: needs 51.2 MB <= 112.6 MB
  float* Tbuf = (float*)(ws + hs0_off);

  float* hs0   = (float*)(ws + hs0_off);
  float* hs1   = (float*)(ws + hs1_off);
  float* Z     = (float*)(ws + Z_off);
  float* ex0   = (float*)(ws + ex0_off);
  float* ex1   = (float*)(ws + ex1_off);
  float* a_s0  = (float*)(ws + as0_off);
  float* a_s1  = (float*)(ws + as1_off);
  float* a_d   = (float*)(ws + ad_off);     // [2][N_USER][4]
  float* wfold = (float*)(ws + wfold_off);
  float* denom = (float*)(ws + denom_off);  // [2][N_USER][4]
  int*   deg   = (int*)(ws + deg_off);      // [2][N_USER]
  int*   cur   = (int*)(ws + cur_off);
  int*   rp0   = (int*)(ws + rp_off);
  int*   rp1   = rp0 + (N_USER + 8);
  int*   ei0   = (int*)(ws + ei_off);
  int*   ei1   = ei0 + NE;

  // zero denom/deg/cursor in one memset
  hipMemsetAsync(ws + denom_off, 0, zero_end - denom_off, stream);

  // fold Wdst against adst -> wfold[768][8]
  fold_kernel<<<cdiv(IN_DIM * 8, 256), 256, 0, stream>>>(Wdst0, adst0, Wdst1, adst1, wfold);

  // a_d for both metapaths (x_dst is x_user for both)
  ad_kernel<<<cdiv(N_USER, 4), 256, 0, stream>>>(x_user, wfold, a_d, N_USER);

  // hs0 = x_llm @ Wsrc0 ; hs1 = x_user @ Wsrc1
  {
    dim3 g(SEM / 64, cdiv(N_LLM, 64));
    gemm_f32<<<g, 256, 0, stream>>>(x_llm, Wsrc0, hs0, nullptr, N_LLM, SEM, IN_DIM);
  }
  {
    dim3 g(SEM / 64, cdiv(N_USER, 64));
    gemm_f32<<<g, 256, 0, stream>>>(x_user, Wsrc1, hs1, nullptr, N_USER, SEM, IN_DIM);
  }

  // a_s from hs
  as_kernel<<<N_LLM,  256, 0, stream>>>(hs0, asrc0, a_s0, N_LLM);
  as_kernel<<<N_USER, 256, 0, stream>>>(hs1, asrc1, a_s1, N_USER);

  // per-edge exp + denominators + degree histogram
  edge_kernel<<<cdiv(NE, 256), 256, 0, stream>>>(src0, dst0, a_s0, a_d,            ex0, denom,              deg,          NE);
  edge_kernel<<<cdiv(NE, 256), 256, 0, stream>>>(src1, dst1, a_s1, a_d + (size_t)N_USER * 4, ex1, denom + (size_t)N_USER * 4, deg + N_USER, NE);

  // CSR build
  scan_kernel<<<1, 1024, 0, stream>>>(deg,          rp0, N_USER);
  scan_kernel<<<1, 1024, 0, stream>>>(deg + N_USER, rp1, N_USER);
  scatter_kernel<<<cdiv(NE, 256), 256, 0, stream>>>(dst0, rp0, cur,          ei0, NE);
  scatter_kernel<<<cdiv(NE, 256), 256, 0, stream>>>(dst1, rp1, cur + N_USER, ei1, NE);

  // aggregate + bias + ELU -> Z rows [0:N_USER) = z0, [N_USER:2N) = z1
  agg_kernel<<<N_USER, 256, 0, stream>>>(hs0, ex0, denom,                       rp0, ei0, src0, bias0, Z);
  agg_kernel<<<N_USER, 256, 0, stream>>>(hs1, ex1, denom + (size_t)N_USER * 4,  rp1, ei1, src1, bias1, Z + (size_t)N_USER * SEM);

  // T = Z @ sem_W1   [100000, 128]  (overlays dead hs region)
  {
    dim3 g(HID / 64, cdiv(2 * N_USER, 64));
    gemm_f32<<<g, 256, 0, stream>>>(Z, sem_W1, Tbuf, nullptr, 2 * N_USER, HID, SEM);
  }

  // semantic softmax + weighted sum (z_final overwrites Z[0:N_USER])
  combine_kernel<<<N_USER, 256, 0, stream>>>(Tbuf, sem_b1, sem_W2, Z);

  // out = z_final @ out_W + out_b
  {
    dim3 g(OUT_DIM / 64, cdiv(N_USER, 64));
    gemm_f32<<<g, 256, 0, stream>>>(Z, out_W, (float*)d_out, out_b, N_USER, OUT_DIM, SEM);
  }
}

// Round 2
// 971.707 us; speedup vs baseline: 2.1064x; 2.1064x over previous
//
#include <hip/hip_runtime.h>
#include <hip/hip_bf16.h>
#include <math.h>

constexpr int IN_DIM  = 768;
constexpr int HID     = 128;
constexpr int OUT_DIM = 256;
constexpr int SEM     = 512;     // HID*HEADS
constexpr int N_USER  = 50000;
constexpr int N_LLM   = 5000;
constexpr int NE      = 400000;

constexpr int MP_USER = 50048;   // 391*128
constexpr int MP_LLM  = 5120;    // 40*128
constexpr int MP_2U   = 100096;  // 782*128

typedef unsigned int uint;
typedef unsigned short ushort;
typedef __attribute__((ext_vector_type(8))) short bf16x8;
typedef __attribute__((ext_vector_type(4))) float f32x4;

static inline int cdiv(int a, int b) { return (a + b - 1) / b; }

__device__ __forceinline__ ushort f2b(float f) {
  uint u = __float_as_uint(f);
  u += 0x7FFFu + ((u >> 16) & 1u);       // RNE
  return (ushort)(u >> 16);
}
__device__ __forceinline__ float b2f(uint bits16) {
  return __uint_as_float(bits16 << 16);
}

#define GLOAD_LDS16(g, l) __builtin_amdgcn_global_load_lds( \
    (const __attribute__((address_space(1))) void*)(g), \
    (__attribute__((address_space(3))) void*)(l), 16, 0, 0)

// ---------------- bf16 MFMA GEMM: C[M,N] = A[Mpad,K] @ Bt[N,K]^T -----------
// 128x128 tile, BK=64, 256 threads (4 waves, 2x2 of 64x64 each).
// STORE_MODE 0: bf16 store, no guard (pad rows land in ws). 1: f32 +bias, row<Mreal guard.
template<int STORE_MODE>
__global__ __launch_bounds__(256) void gemm_bf16(
    const ushort* __restrict__ A, const ushort* __restrict__ Bt,
    void* __restrict__ Cout, const float* __restrict__ bias,
    int Mreal, int N, int K)
{
  __shared__ ushort As[128][64];   // 16 KB
  __shared__ ushort Bs[128][64];   // 16 KB
  const int t = threadIdx.x;
  const int wid = t >> 6, lane = t & 63;
  const int bm = blockIdx.y * 128, bn = blockIdx.x * 128;
  const int lr = lane & 15, kg = lane >> 4;
  const int mbase = (wid >> 1) * 64, nbase = (wid & 1) * 64;
  const int grow = lane >> 3;          // 0..7 within chunk
  const int gcol = (lane & 7) * 8;     // element col, 16B granules

  f32x4 acc[4][4] = {};

  for (int k0 = 0; k0 < K; k0 += 64) {
#pragma unroll
    for (int c = 0; c < 4; ++c) {
      int ch = wid * 4 + c;            // 0..15, rows ch*8..ch*8+7
      const ushort* ga = A  + (size_t)(bm + ch * 8 + grow) * K + k0 + gcol;
      const ushort* gb = Bt + (size_t)(bn + ch * 8 + grow) * K + k0 + gcol;
      GLOAD_LDS16(ga, &As[ch * 8][0]);
      GLOAD_LDS16(gb, &Bs[ch * 8][0]);
    }
    asm volatile("s_waitcnt vmcnt(0)" ::: "memory");
    __syncthreads();
#pragma unroll
    for (int kb = 0; kb < 2; ++kb) {
      bf16x8 av[4], bv[4];
#pragma unroll
      for (int m = 0; m < 4; ++m)
        av[m] = *(const bf16x8*)&As[mbase + m * 16 + lr][kb * 32 + kg * 8];
#pragma unroll
      for (int n = 0; n < 4; ++n)
        bv[n] = *(const bf16x8*)&Bs[nbase + n * 16 + lr][kb * 32 + kg * 8];
#pragma unroll
      for (int m = 0; m < 4; ++m)
#pragma unroll
        for (int n = 0; n < 4; ++n)
          acc[m][n] = __builtin_amdgcn_mfma_f32_16x16x32_bf16(av[m], bv[n], acc[m][n], 0, 0, 0);
    }
    __syncthreads();
  }

#pragma unroll
  for (int m = 0; m < 4; ++m) {
#pragma unroll
    for (int j = 0; j < 4; ++j) {
      int row = bm + mbase + m * 16 + kg * 4 + j;
      if (STORE_MODE == 1 && row >= Mreal) continue;
#pragma unroll
      for (int n = 0; n < 4; ++n) {
        int col = bn + nbase + n * 16 + lr;
        float v = acc[m][n][j];
        if (STORE_MODE == 1) {
          if (bias) v += bias[col];
          ((float*)Cout)[(size_t)row * N + col] = v;
        } else {
          ((ushort*)Cout)[(size_t)row * N + col] = f2b(v);
        }
      }
    }
  }
}

// -------- cast fp32 row-major -> bf16 row-major (8 elems/thread) -----------
__global__ __launch_bounds__(256) void cast_kernel(
    const float* __restrict__ x, ushort* __restrict__ out, int total8, int dummy)
{
  int i = blockIdx.x * 256 + threadIdx.x;
  if (i >= total8) return;
  const float4 a = *(const float4*)(x + (size_t)i * 8);
  const float4 b = *(const float4*)(x + (size_t)i * 8 + 4);
  uint4 o;
  o.x = (uint)f2b(a.x) | ((uint)f2b(a.y) << 16);
  o.y = (uint)f2b(a.z) | ((uint)f2b(a.w) << 16);
  o.z = (uint)f2b(b.x) | ((uint)f2b(b.y) << 16);
  o.w = (uint)f2b(b.z) | ((uint)f2b(b.w) << 16);
  *(uint4*)(out + (size_t)i * 8) = o;
}

// -------- transpose-cast: W fp32 [K][Nw] -> Bt bf16 [Nw][K] ----------------
__global__ __launch_bounds__(256) void tc_kernel(
    const float* __restrict__ W, ushort* __restrict__ Bt, int K, int Nw)
{
  int i = blockIdx.x * 256 + threadIdx.x;
  if (i >= K * Nw) return;
  int n = i / K, k = i - n * K;
  Bt[i] = f2b(W[(size_t)k * Nw + n]);
}

// ------------- fold Wdst (768x512) against adst (4x128) -> wfold[768][8] ---
__global__ void fold_kernel(const float* __restrict__ Wdst0, const float* __restrict__ adst0,
                            const float* __restrict__ Wdst1, const float* __restrict__ adst1,
                            float* __restrict__ wfold)
{
  int idx = blockIdx.x * 256 + threadIdx.x;
  if (idx >= IN_DIM * 8) return;
  int k = idx >> 3, hh = idx & 7;
  const float* W   = (hh < 4) ? Wdst0 : Wdst1;
  const float* att = (hh < 4) ? adst0 : adst1;
  int h = hh & 3;
  float s = 0.f;
#pragma unroll 4
  for (int c = 0; c < HID; ++c)
    s += W[(size_t)k * SEM + h * HID + c] * att[h * HID + c];
  wfold[idx] = s;
}

// -------- a_d[p][n][4] = x_user[n,:] @ wfold[:, p*4+h]  (wave per node) ----
__global__ __launch_bounds__(256) void ad_kernel(
    const float* __restrict__ x, const float* __restrict__ wfold,
    float* __restrict__ a_d, int n)
{
  int wid = threadIdx.x >> 6, lane = threadIdx.x & 63;
  int node = blockIdx.x * 4 + wid;
  if (node >= n) return;
  float acc[8] = {};
  for (int kk = lane; kk < IN_DIM; kk += 64) {
    float xv = x[(size_t)node * IN_DIM + kk];
    const float* wf = wfold + kk * 8;
#pragma unroll
    for (int h = 0; h < 8; ++h) acc[h] += xv * wf[h];
  }
#pragma unroll
  for (int off = 32; off > 0; off >>= 1) {
#pragma unroll
    for (int h = 0; h < 8; ++h) acc[h] += __shfl_down(acc[h], off);
  }
  if (lane == 0) {
#pragma unroll
    for (int h = 0; h < 4; ++h) a_d[(size_t)node * 4 + h] = acc[h];
#pragma unroll
    for (int h = 0; h < 4; ++h) a_d[(size_t)N_USER * 4 + (size_t)node * 4 + h] = acc[4 + h];
  }
}

// -------- a_s[n][4] from bf16 hs ------------------------------------------
__global__ __launch_bounds__(256) void as_kernel(
    const ushort* __restrict__ hs, const float* __restrict__ att,
    float* __restrict__ a_s)
{
  __shared__ float sm[256];
  int node = blockIdx.x, t = threadIdx.x;
  uint pv = *(const uint*)(hs + (size_t)node * SEM + 2 * t);
  float v = b2f(pv & 0xffffu) * att[2 * t] + b2f(pv >> 16) * att[2 * t + 1];
  sm[t] = v;
  __syncthreads();
  for (int off = 32; off > 0; off >>= 1) {
    if ((t & 63) < off) sm[t] += sm[t + off];
    __syncthreads();
  }
  if ((t & 63) == 0) a_s[(size_t)node * 4 + (t >> 6)] = sm[t];
}

// -------- per-edge exp + denom + degree ------------------------------------
__global__ void edge_kernel(const int* __restrict__ src, const int* __restrict__ dst,
                            const float* __restrict__ a_s, const float* __restrict__ a_d,
                            float* __restrict__ ex, float* __restrict__ denom,
                            int* __restrict__ deg, int E)
{
  int e = blockIdx.x * 256 + threadIdx.x;
  if (e >= E) return;
  int s = src[e], d = dst[e];
  float4 as4 = *(const float4*)(a_s + (size_t)s * 4);
  float4 ad4 = *(const float4*)(a_d + (size_t)d * 4);
  float v[4] = { as4.x + ad4.x, as4.y + ad4.y, as4.z + ad4.z, as4.w + ad4.w };
  float ev[4];
#pragma unroll
  for (int h = 0; h < 4; ++h) {
    float x = v[h];
    x = (x > 0.f) ? x : 0.2f * x;
    ev[h] = expf(x);
    atomicAdd(&denom[(size_t)d * 4 + h], ev[h]);
  }
  *(float4*)(ex + (size_t)e * 4) = make_float4(ev[0], ev[1], ev[2], ev[3]);
  atomicAdd(&deg[d], 1);
}

// -------- 3-phase scan over deg[0..n) --------------------------------------
__global__ __launch_bounds__(256) void scan1(const int* __restrict__ deg,
                                             int* __restrict__ bsum, int n)
{
  __shared__ int sm[256];
  int b = blockIdx.x, t = threadIdx.x;
  int base = b * 1024 + t * 4;
  int s = 0;
#pragma unroll
  for (int i = 0; i < 4; ++i) if (base + i < n) s += deg[base + i];
  sm[t] = s;
  __syncthreads();
  for (int off = 128; off > 0; off >>= 1) {
    if (t < off) sm[t] += sm[t + off];
    __syncthreads();
  }
  if (t == 0) bsum[b] = sm[0];
}

__global__ __launch_bounds__(128) void scan2(const int* __restrict__ bsum,
                                             int* __restrict__ boff, int nb,
                                             int* __restrict__ rp_tail, int tailval)
{
  __shared__ int sm[128];
  int t = threadIdx.x;
  int v = (t < nb) ? bsum[t] : 0;
  sm[t] = v;
  __syncthreads();
  for (int off = 1; off < 128; off <<= 1) {
    int x = (t >= off) ? sm[t - off] : 0;
    __syncthreads();
    sm[t] += x;
    __syncthreads();
  }
  if (t < nb) boff[t] = sm[t] - v;
  if (t == 0) *rp_tail = tailval;
}

__global__ __launch_bounds__(256) void scan3(const int* __restrict__ deg,
                                             const int* __restrict__ boff,
                                             int* __restrict__ rp, int n)
{
  __shared__ int sm[256];
  int b = blockIdx.x, t = threadIdx.x;
  int base = b * 1024 + t * 4;
  int v[4];
#pragma unroll
  for (int i = 0; i < 4; ++i) v[i] = (base + i < n) ? deg[base + i] : 0;
  int tsum = v[0] + v[1] + v[2] + v[3];
  sm[t] = tsum;
  __syncthreads();
  for (int off = 1; off < 256; off <<= 1) {
    int x = (t >= off) ? sm[t - off] : 0;
    __syncthreads();
    sm[t] += x;
    __syncthreads();
  }
  int run = sm[t] - tsum + boff[b];
#pragma unroll
  for (int i = 0; i < 4; ++i) {
    if (base + i < n) rp[base + i] = run;
    run += v[i];
  }
}

// -------- scatter edges into CSR order -------------------------------------
__global__ void scatter_kernel(const int* __restrict__ dst, const int* __restrict__ row_ptr,
                               int* __restrict__ cursor, int* __restrict__ edge_idx, int E)
{
  int e = blockIdx.x * 256 + threadIdx.x;
  if (e >= E) return;
  int d = dst[e];
  int pos = row_ptr[d] + atomicAdd(&cursor[d], 1);
  edge_idx[pos] = e;
}

// -------- aggregation: z = elu(sum alpha*hs + bias) -> bf16 Z --------------
__global__ __launch_bounds__(256) void agg_kernel(
    const ushort* __restrict__ hs, const float* __restrict__ ex,
    const float* __restrict__ denom, const int* __restrict__ row_ptr,
    const int* __restrict__ edge_idx, const int* __restrict__ src,
    const float* __restrict__ bias, ushort* __restrict__ Zout)
{
  int node = blockIdx.x, t = threadIdx.x;
  int ch = 2 * t;
  int h = ch >> 7;
  float invd = 1.f / (denom[(size_t)node * 4 + h] + 1e-16f);
  float acc0 = 0.f, acc1 = 0.f;
  int jb = row_ptr[node], je = row_ptr[node + 1];
  for (int j = jb; j < je; ++j) {
    int e = edge_idx[j];
    int s = src[e];
    float al = ex[(size_t)e * 4 + h] * invd;
    uint pv = *(const uint*)(hs + (size_t)s * SEM + ch);
    acc0 += b2f(pv & 0xffffu) * al;
    acc1 += b2f(pv >> 16) * al;
  }
  float z0 = acc0 + bias[ch];
  float z1 = acc1 + bias[ch + 1];
  z0 = (z0 > 0.f) ? z0 : expm1f(z0);
  z1 = (z1 > 0.f) ? z1 : expm1f(z1);
  uint o = (uint)f2b(z0) | ((uint)f2b(z1) << 16);
  *(uint*)(Zout + (size_t)node * SEM + ch) = o;
}

// -------- semantic attention combine: ZF = beta0*Z0 + beta1*Z1 (bf16) ------
__global__ __launch_bounds__(256) void combine_kernel(
    const float* __restrict__ T, const float* __restrict__ b1,
    const float* __restrict__ W2, const ushort* __restrict__ Z,
    ushort* __restrict__ ZF)
{
  __shared__ float red[256];
  __shared__ float beta[2];
  int node = blockIdx.x, t = threadIdx.x;
  int p = t >> 7, j = t & 127;
  float val = tanhf(T[(size_t)(p * N_USER + node) * HID + j] + b1[j]) * W2[j];
  red[t] = val;
  __syncthreads();
  for (int off = 64; off > 0; off >>= 1) {
    if (j < off) red[t] += red[t + off];
    __syncthreads();
  }
  if (t == 0) {
    float w0 = red[0], w1 = red[128];
    float mx = fmaxf(w0, w1);
    float e0 = expf(w0 - mx), e1 = expf(w1 - mx);
    float s = e0 + e1;
    beta[0] = e0 / s; beta[1] = e1 / s;
  }
  __syncthreads();
  float b0v = beta[0], b1v = beta[1];
  int ch = 2 * t;
  uint z0 = *(const uint*)(Z + (size_t)node * SEM + ch);
  uint z1 = *(const uint*)(Z + (size_t)(N_USER + node) * SEM + ch);
  float f0 = b0v * b2f(z0 & 0xffffu) + b1v * b2f(z1 & 0xffffu);
  float f1 = b0v * b2f(z0 >> 16)     + b1v * b2f(z1 >> 16);
  uint o = (uint)f2b(f0) | ((uint)f2b(f1) << 16);
  *(uint*)(ZF + (size_t)node * SEM + ch) = o;
}

extern "C" void kernel_launch(void* const* d_in, const int* in_sizes, int n_in,
                              void* d_out, int out_size, void* d_ws, size_t ws_size,
                              hipStream_t stream)
{
  const float* x_user = (const float*)d_in[0];
  const float* x_llm  = (const float*)d_in[1];
  const int* src0 = (const int*)d_in[2];
  const int* dst0 = (const int*)d_in[3];
  const int* src1 = (const int*)d_in[4];
  const int* dst1 = (const int*)d_in[5];
  const float* Wsrc0 = (const float*)d_in[6];
  const float* Wdst0 = (const float*)d_in[7];
  const float* asrc0 = (const float*)d_in[8];
  const float* adst0 = (const float*)d_in[9];
  const float* bias0 = (const float*)d_in[10];
  const float* Wsrc1 = (const float*)d_in[11];
  const float* Wdst1 = (const float*)d_in[12];
  const float* asrc1 = (const float*)d_in[13];
  const float* adst1 = (const float*)d_in[14];
  const float* bias1 = (const float*)d_in[15];
  const float* sem_W1 = (const float*)d_in[16];
  const float* sem_b1 = (const float*)d_in[17];
  const float* sem_W2 = (const float*)d_in[18];
  const float* out_W  = (const float*)d_in[19];
  const float* out_b  = (const float*)d_in[20];

  char* ws = (char*)d_ws;
  size_t off = 0;
  auto alloc = [&](size_t bytes) -> size_t {
    size_t o = off;
    off += (bytes + 255) & ~(size_t)255;
    return o;
  };

  size_t xbu_off  = alloc((size_t)MP_USER * IN_DIM * 2);   // 76.9 MB (later overlaid by T)
  size_t xbl_off  = alloc((size_t)MP_LLM  * IN_DIM * 2);   // 7.9 MB
  size_t wt0_off  = alloc((size_t)SEM * IN_DIM * 2);
  size_t wt1_off  = alloc((size_t)SEM * IN_DIM * 2);
  size_t wts_off  = alloc((size_t)HID * SEM * 2);
  size_t wto_off  = alloc((size_t)OUT_DIM * SEM * 2);
  size_t hs0_off  = alloc((size_t)MP_LLM  * SEM * 2);      // 5.2 MB
  size_t hs1_off  = alloc((size_t)MP_USER * SEM * 2);      // 51.2 MB (later overlaid by ZF)
  size_t Z_off    = alloc((size_t)MP_2U   * SEM * 2);      // 102.5 MB
  size_t ex0_off  = alloc((size_t)NE * 4 * 4);
  size_t ex1_off  = alloc((size_t)NE * 4 * 4);
  size_t as0_off  = alloc((size_t)N_LLM  * 4 * 4);
  size_t as1_off  = alloc((size_t)N_USER * 4 * 4);
  size_t ad_off   = alloc((size_t)2 * N_USER * 4 * 4);
  size_t wf_off   = alloc((size_t)IN_DIM * 8 * 4);
  size_t den_off  = alloc((size_t)2 * N_USER * 4 * 4);     // zeroed
  size_t deg_off  = alloc((size_t)2 * N_USER * 4);         // zeroed
  size_t cur_off  = alloc((size_t)2 * N_USER * 4);         // zeroed
  size_t zero_end = off;
  size_t rp_off   = alloc((size_t)(2 * N_USER + 1) * 4);
  size_t ei_off   = alloc((size_t)2 * NE * 4);
  size_t bs_off   = alloc((size_t)128 * 4);
  size_t bo_off   = alloc((size_t)128 * 4);

  ushort* xb_u  = (ushort*)(ws + xbu_off);
  ushort* xb_l  = (ushort*)(ws + xbl_off);
  ushort* Wt0   = (ushort*)(ws + wt0_off);
  ushort* Wt1   = (ushort*)(ws + wt1_off);
  ushort* WtS   = (ushort*)(ws + wts_off);
  ushort* WtO   = (ushort*)(ws + wto_off);
  ushort* hs0b  = (ushort*)(ws + hs0_off);
  ushort* hs1b  = (ushort*)(ws + hs1_off);
  ushort* Zsw   = (ushort*)(ws + Z_off);
  float*  Tbuf  = (float*)(ws + xbu_off);   // overlay: xb dead after hs GEMMs
  ushort* ZF    = (ushort*)(ws + hs1_off);  // overlay: hs1 dead after agg1
  float*  ex0   = (float*)(ws + ex0_off);
  float*  ex1   = (float*)(ws + ex1_off);
  float*  a_s0  = (float*)(ws + as0_off);
  float*  a_s1  = (float*)(ws + as1_off);
  float*  a_d   = (float*)(ws + ad_off);
  float*  wfold = (float*)(ws + wf_off);
  float*  denom = (float*)(ws + den_off);
  int*    deg   = (int*)(ws + deg_off);     // concatenated [2*N_USER]
  int*    cur   = (int*)(ws + cur_off);
  int*    rp    = (int*)(ws + rp_off);      // [2*N_USER+1]
  int*    ei    = (int*)(ws + ei_off);      // [2*NE]
  int*    bsum  = (int*)(ws + bs_off);
  int*    boff  = (int*)(ws + bo_off);

  hipMemsetAsync(ws + den_off, 0, zero_end - den_off, stream);

  // precompute: folds, casts, transposes
  fold_kernel<<<cdiv(IN_DIM * 8, 256), 256, 0, stream>>>(Wdst0, adst0, Wdst1, adst1, wfold);
  ad_kernel<<<cdiv(N_USER, 4), 256, 0, stream>>>(x_user, wfold, a_d, N_USER);
  cast_kernel<<<cdiv(N_USER * IN_DIM / 8, 256), 256, 0, stream>>>(x_user, xb_u, N_USER * IN_DIM / 8, 0);
  cast_kernel<<<cdiv(N_LLM * IN_DIM / 8, 256), 256, 0, stream>>>(x_llm, xb_l, N_LLM * IN_DIM / 8, 0);
  tc_kernel<<<cdiv(IN_DIM * SEM, 256), 256, 0, stream>>>(Wsrc0, Wt0, IN_DIM, SEM);
  tc_kernel<<<cdiv(IN_DIM * SEM, 256), 256, 0, stream>>>(Wsrc1, Wt1, IN_DIM, SEM);
  tc_kernel<<<cdiv(SEM * HID, 256), 256, 0, stream>>>(sem_W1, WtS, SEM, HID);
  tc_kernel<<<cdiv(SEM * OUT_DIM, 256), 256, 0, stream>>>(out_W, WtO, SEM, OUT_DIM);

  // hs GEMMs (bf16 out)
  {
    dim3 g(SEM / 128, MP_LLM / 128);
    gemm_bf16<0><<<g, 256, 0, stream>>>(xb_l, Wt0, hs0b, nullptr, MP_LLM, SEM, IN_DIM);
  }
  {
    dim3 g(SEM / 128, MP_USER / 128);
    gemm_bf16<0><<<g, 256, 0, stream>>>(xb_u, Wt1, hs1b, nullptr, MP_USER, SEM, IN_DIM);
  }

  // attention logits
  as_kernel<<<N_LLM,  256, 0, stream>>>(hs0b, asrc0, a_s0);
  as_kernel<<<N_USER, 256, 0, stream>>>(hs1b, asrc1, a_s1);
  edge_kernel<<<cdiv(NE, 256), 256, 0, stream>>>(src0, dst0, a_s0, a_d, ex0, denom, deg, NE);
  edge_kernel<<<cdiv(NE, 256), 256, 0, stream>>>(src1, dst1, a_s1, a_d + (size_t)N_USER * 4,
                                                 ex1, denom + (size_t)N_USER * 4, deg + N_USER, NE);

  // CSR build over concatenated degrees
  const int NTOT = 2 * N_USER;
  const int NB = cdiv(NTOT, 1024);   // 98
  scan1<<<NB, 256, 0, stream>>>(deg, bsum, NTOT);
  scan2<<<1, 128, 0, stream>>>(bsum, boff, NB, rp + NTOT, 2 * NE);
  scan3<<<NB, 256, 0, stream>>>(deg, boff, rp, NTOT);
  scatter_kernel<<<cdiv(NE, 256), 256, 0, stream>>>(dst0, rp, cur, ei, NE);
  scatter_kernel<<<cdiv(NE, 256), 256, 0, stream>>>(dst1, rp + N_USER, cur + N_USER, ei, NE);

  // aggregate -> bf16 Z rows [0:N) path0, [N:2N) path1
  agg_kernel<<<N_USER, 256, 0, stream>>>(hs0b, ex0, denom, rp, ei, src0, bias0, Zsw);
  agg_kernel<<<N_USER, 256, 0, stream>>>(hs1b, ex1, denom + (size_t)N_USER * 4,
                                         rp + N_USER, ei, src1, bias1, Zsw + (size_t)N_USER * SEM);

  // T = Z @ sem_W1 (fp32 out, overlays dead xb_u)
  {
    dim3 g(HID / 128, MP_2U / 128);
    gemm_bf16<1><<<g, 256, 0, stream>>>(Zsw, WtS, Tbuf, nullptr, MP_2U, HID, SEM);
  }

  // semantic combine -> bf16 ZF (overlays dead hs1b)
  combine_kernel<<<N_USER, 256, 0, stream>>>(Tbuf, sem_b1, sem_W2, Zsw, ZF);

  // out = ZF @ out_W + out_b (fp32, guarded)
  {
    dim3 g(OUT_DIM / 128, MP_USER / 128);
    gemm_bf16<1><<<g, 256, 0, stream>>>(ZF, WtO, (float*)d_out, out_b, N_USER, OUT_DIM, SEM);
  }
}

// Round 3
// 810.053 us; speedup vs baseline: 2.5268x; 1.1996x over previous
//
#include <hip/hip_runtime.h>
#include <hip/hip_bf16.h>
#include <math.h>

constexpr int IN_DIM  = 768;
constexpr int HID     = 128;
constexpr int OUT_DIM = 256;
constexpr int SEM     = 512;     // HID*HEADS
constexpr int N_USER  = 50000;
constexpr int N_LLM   = 5000;
constexpr int NE      = 400000;

constexpr int MP_USER = 50048;   // 391*128
constexpr int MP_LLM  = 5120;    // 40*128
constexpr int MP_2U   = 100096;  // 782*128

typedef unsigned int uint;
typedef unsigned short ushort;
typedef __attribute__((ext_vector_type(8))) short bf16x8;
typedef __attribute__((ext_vector_type(4))) float f32x4;

static inline int cdiv(int a, int b) { return (a + b - 1) / b; }

__device__ __forceinline__ ushort f2b(float f) {
  uint u = __float_as_uint(f);
  u += 0x7FFFu + ((u >> 16) & 1u);       // RNE
  return (ushort)(u >> 16);
}
__device__ __forceinline__ float b2f(uint bits16) {
  return __uint_as_float(bits16 << 16);
}

#define GLOAD_LDS16(g, l) __builtin_amdgcn_global_load_lds( \
    (const __attribute__((address_space(1))) void*)(g), \
    (__attribute__((address_space(3))) void*)(l), 16, 0, 0)

// ---------------- bf16 MFMA GEMM: C[M,N] = A[Mpad,K] @ Bt[N,K]^T -----------
// 128x128 tile, BK=64, 256 threads (4 waves, 2x2 of 64x64 each).
// STORE_MODE 0: bf16 store, no guard (pad rows land in ws). 1: f32 +bias, row<Mreal guard.
template<int STORE_MODE>
__global__ __launch_bounds__(256) void gemm_bf16(
    const ushort* __restrict__ A, const ushort* __restrict__ Bt,
    void* __restrict__ Cout, const float* __restrict__ bias,
    int Mreal, int N, int K)
{
  __shared__ ushort As[128][64];   // 16 KB
  __shared__ ushort Bs[128][64];   // 16 KB
  const int t = threadIdx.x;
  const int wid = t >> 6, lane = t & 63;

  // bijective XCD-aware swizzle (m204): each XCD gets a contiguous chunk of
  // logical tiles; row-major flatten so same-row (shared A panel) tiles stay
  // on one XCD's L2.
  const int nwg  = gridDim.x * gridDim.y;
  const int orig = blockIdx.y * gridDim.x + blockIdx.x;
  const int q = nwg >> 3, r = nwg & 7;
  const int xcd = orig & 7, idx = orig >> 3;
  const int swz = (xcd < r ? xcd * (q + 1) : r * (q + 1) + (xcd - r) * q) + idx;
  const int bxi = swz % gridDim.x, byi = swz / gridDim.x;

  const int bm = byi * 128, bn = bxi * 128;
  const int lr = lane & 15, kg = lane >> 4;
  const int mbase = (wid >> 1) * 64, nbase = (wid & 1) * 64;
  const int grow = lane >> 3;          // 0..7 within chunk
  const int gcol = (lane & 7) * 8;     // element col, 16B granules

  f32x4 acc[4][4] = {};

  for (int k0 = 0; k0 < K; k0 += 64) {
#pragma unroll
    for (int c = 0; c < 4; ++c) {
      int ch = wid * 4 + c;            // 0..15, rows ch*8..ch*8+7
      const ushort* ga = A  + (size_t)(bm + ch * 8 + grow) * K + k0 + gcol;
      const ushort* gb = Bt + (size_t)(bn + ch * 8 + grow) * K + k0 + gcol;
      GLOAD_LDS16(ga, &As[ch * 8][0]);
      GLOAD_LDS16(gb, &Bs[ch * 8][0]);
    }
    asm volatile("s_waitcnt vmcnt(0)" ::: "memory");
    __syncthreads();
#pragma unroll
    for (int kb = 0; kb < 2; ++kb) {
      bf16x8 av[4], bv[4];
#pragma unroll
      for (int m = 0; m < 4; ++m)
        av[m] = *(const bf16x8*)&As[mbase + m * 16 + lr][kb * 32 + kg * 8];
#pragma unroll
      for (int n = 0; n < 4; ++n)
        bv[n] = *(const bf16x8*)&Bs[nbase + n * 16 + lr][kb * 32 + kg * 8];
#pragma unroll
      for (int m = 0; m < 4; ++m)
#pragma unroll
        for (int n = 0; n < 4; ++n)
          acc[m][n] = __builtin_amdgcn_mfma_f32_16x16x32_bf16(av[m], bv[n], acc[m][n], 0, 0, 0);
    }
    __syncthreads();
  }

#pragma unroll
  for (int m = 0; m < 4; ++m) {
#pragma unroll
    for (int j = 0; j < 4; ++j) {
      int row = bm + mbase + m * 16 + kg * 4 + j;
      if (STORE_MODE == 1 && row >= Mreal) continue;
#pragma unroll
      for (int n = 0; n < 4; ++n) {
        int col = bn + nbase + n * 16 + lr;
        float v = acc[m][n][j];
        if (STORE_MODE == 1) {
          if (bias) v += bias[col];
          ((float*)Cout)[(size_t)row * N + col] = v;
        } else {
          ((ushort*)Cout)[(size_t)row * N + col] = f2b(v);
        }
      }
    }
  }
}

// -------- cast fp32 row-major -> bf16 row-major (8 elems/thread) -----------
__global__ __launch_bounds__(256) void cast_kernel(
    const float* __restrict__ x, ushort* __restrict__ out, int total8, int dummy)
{
  int i = blockIdx.x * 256 + threadIdx.x;
  if (i >= total8) return;
  const float4 a = *(const float4*)(x + (size_t)i * 8);
  const float4 b = *(const float4*)(x + (size_t)i * 8 + 4);
  uint4 o;
  o.x = (uint)f2b(a.x) | ((uint)f2b(a.y) << 16);
  o.y = (uint)f2b(a.z) | ((uint)f2b(a.w) << 16);
  o.z = (uint)f2b(b.x) | ((uint)f2b(b.y) << 16);
  o.w = (uint)f2b(b.z) | ((uint)f2b(b.w) << 16);
  *(uint4*)(out + (size_t)i * 8) = o;
}

// -------- transpose-cast: W fp32 [K][Nw] -> Bt bf16 [Nw][K] ----------------
__global__ __launch_bounds__(256) void tc_kernel(
    const float* __restrict__ W, ushort* __restrict__ Bt, int K, int Nw)
{
  int i = blockIdx.x * 256 + threadIdx.x;
  if (i >= K * Nw) return;
  int n = i / K, k = i - n * K;
  Bt[i] = f2b(W[(size_t)k * Nw + n]);
}

// ------------- fold Wdst (768x512) against adst (4x128) -> wfold[768][8] ---
__global__ void fold_kernel(const float* __restrict__ Wdst0, const float* __restrict__ adst0,
                            const float* __restrict__ Wdst1, const float* __restrict__ adst1,
                            float* __restrict__ wfold)
{
  int idx = blockIdx.x * 256 + threadIdx.x;
  if (idx >= IN_DIM * 8) return;
  int k = idx >> 3, hh = idx & 7;
  const float* W   = (hh < 4) ? Wdst0 : Wdst1;
  const float* att = (hh < 4) ? adst0 : adst1;
  int h = hh & 3;
  float s = 0.f;
#pragma unroll 4
  for (int c = 0; c < HID; ++c)
    s += W[(size_t)k * SEM + h * HID + c] * att[h * HID + c];
  wfold[idx] = s;
}

// -------- a_d[p][n][4] = x_user[n,:] @ wfold[:, p*4+h]  (wave per node) ----
__global__ __launch_bounds__(256) void ad_kernel(
    const float* __restrict__ x, const float* __restrict__ wfold,
    float* __restrict__ a_d, int n)
{
  int wid = threadIdx.x >> 6, lane = threadIdx.x & 63;
  int node = blockIdx.x * 4 + wid;
  if (node >= n) return;
  float acc[8] = {};
  for (int kk = lane; kk < IN_DIM; kk += 64) {
    float xv = x[(size_t)node * IN_DIM + kk];
    const float* wf = wfold + kk * 8;
#pragma unroll
    for (int h = 0; h < 8; ++h) acc[h] += xv * wf[h];
  }
#pragma unroll
  for (int off = 32; off > 0; off >>= 1) {
#pragma unroll
    for (int h = 0; h < 8; ++h) acc[h] += __shfl_down(acc[h], off);
  }
  if (lane == 0) {
#pragma unroll
    for (int h = 0; h < 4; ++h) a_d[(size_t)node * 4 + h] = acc[h];
#pragma unroll
    for (int h = 0; h < 4; ++h) a_d[(size_t)N_USER * 4 + (size_t)node * 4 + h] = acc[4 + h];
  }
}

// -------- a_s[n][4] from bf16 hs ------------------------------------------
__global__ __launch_bounds__(256) void as_kernel(
    const ushort* __restrict__ hs, const float* __restrict__ att,
    float* __restrict__ a_s)
{
  __shared__ float sm[256];
  int node = blockIdx.x, t = threadIdx.x;
  uint pv = *(const uint*)(hs + (size_t)node * SEM + 2 * t);
  float v = b2f(pv & 0xffffu) * att[2 * t] + b2f(pv >> 16) * att[2 * t + 1];
  sm[t] = v;
  __syncthreads();
  for (int off = 32; off > 0; off >>= 1) {
    if ((t & 63) < off) sm[t] += sm[t + off];
    __syncthreads();
  }
  if ((t & 63) == 0) a_s[(size_t)node * 4 + (t >> 6)] = sm[t];
}

// -------- pass 1: degree histogram over unified node space -----------------
__global__ void edge1_kernel(const int* __restrict__ dst0, const int* __restrict__ dst1,
                             int* __restrict__ deg)
{
  int e = blockIdx.x * 256 + threadIdx.x;
  if (e >= 2 * NE) return;
  int d = (e < NE) ? dst0[e] : (dst1[e - NE] + N_USER);
  atomicAdd(&deg[d], 1);
}

// -------- pass 2: exp + denom + write (src, ev4) into CSR slots ------------
__global__ void edge2_kernel(const int* __restrict__ src0, const int* __restrict__ dst0,
                             const int* __restrict__ src1, const int* __restrict__ dst1,
                             const float* __restrict__ a_s0, const float* __restrict__ a_s1,
                             const float* __restrict__ a_d,
                             const int* __restrict__ rp, int* __restrict__ cur,
                             int* __restrict__ srcs_csr, float4* __restrict__ exs_csr,
                             float* __restrict__ denom)
{
  int e = blockIdx.x * 256 + threadIdx.x;
  if (e >= 2 * NE) return;
  bool p1 = (e >= NE);
  int ee = p1 ? e - NE : e;
  int s = p1 ? src1[ee] : src0[ee];
  int d = p1 ? (dst1[ee] + N_USER) : dst0[ee];
  const float* as = p1 ? a_s1 : a_s0;
  float4 as4 = *(const float4*)(as + (size_t)s * 4);
  float4 ad4 = *(const float4*)(a_d + (size_t)d * 4);
  float v[4] = { as4.x + ad4.x, as4.y + ad4.y, as4.z + ad4.z, as4.w + ad4.w };
  float ev[4];
#pragma unroll
  for (int h = 0; h < 4; ++h) {
    float x = v[h];
    x = (x > 0.f) ? x : 0.2f * x;       // leaky_relu(0.2)
    ev[h] = expf(x);                    // shift-invariant: skip segment_max
    atomicAdd(&denom[(size_t)d * 4 + h], ev[h]);
  }
  int pos = rp[d] + atomicAdd(&cur[d], 1);
  srcs_csr[pos] = s;
  exs_csr[pos] = make_float4(ev[0], ev[1], ev[2], ev[3]);
}

// -------- 3-phase scan over deg[0..n) --------------------------------------
__global__ __launch_bounds__(256) void scan1(const int* __restrict__ deg,
                                             int* __restrict__ bsum, int n)
{
  __shared__ int sm[256];
  int b = blockIdx.x, t = threadIdx.x;
  int base = b * 1024 + t * 4;
  int s = 0;
#pragma unroll
  for (int i = 0; i < 4; ++i) if (base + i < n) s += deg[base + i];
  sm[t] = s;
  __syncthreads();
  for (int off = 128; off > 0; off >>= 1) {
    if (t < off) sm[t] += sm[t + off];
    __syncthreads();
  }
  if (t == 0) bsum[b] = sm[0];
}

__global__ __launch_bounds__(128) void scan2(const int* __restrict__ bsum,
                                             int* __restrict__ boff, int nb,
                                             int* __restrict__ rp_tail, int tailval)
{
  __shared__ int sm[128];
  int t = threadIdx.x;
  int v = (t < nb) ? bsum[t] : 0;
  sm[t] = v;
  __syncthreads();
  for (int off = 1; off < 128; off <<= 1) {
    int x = (t >= off) ? sm[t - off] : 0;
    __syncthreads();
    sm[t] += x;
    __syncthreads();
  }
  if (t < nb) boff[t] = sm[t] - v;
  if (t == 0) *rp_tail = tailval;
}

__global__ __launch_bounds__(256) void scan3(const int* __restrict__ deg,
                                             const int* __restrict__ boff,
                                             int* __restrict__ rp, int n)
{
  __shared__ int sm[256];
  int b = blockIdx.x, t = threadIdx.x;
  int base = b * 1024 + t * 4;
  int v[4];
#pragma unroll
  for (int i = 0; i < 4; ++i) v[i] = (base + i < n) ? deg[base + i] : 0;
  int tsum = v[0] + v[1] + v[2] + v[3];
  sm[t] = tsum;
  __syncthreads();
  for (int off = 1; off < 256; off <<= 1) {
    int x = (t >= off) ? sm[t - off] : 0;
    __syncthreads();
    sm[t] += x;
    __syncthreads();
  }
  int run = sm[t] - tsum + boff[b];
#pragma unroll
  for (int i = 0; i < 4; ++i) {
    if (base + i < n) rp[base + i] = run;
    run += v[i];
  }
}

// -------- unified aggregation over 2*N_USER nodes --------------------------
// Block = one dst node. Edge records LDS-staged (coalesced), then each edge is
// a single independent gather (dep-chain depth 1, unrolled x4 for MLP).
__global__ __launch_bounds__(256) void agg_kernel(
    const ushort* __restrict__ hs0, const ushort* __restrict__ hs1,
    const int* __restrict__ srcs, const float4* __restrict__ exs,
    const float* __restrict__ denom, const int* __restrict__ rp,
    const float* __restrict__ bias0, const float* __restrict__ bias1,
    ushort* __restrict__ Zout)
{
  __shared__ int   s_src[64];
  __shared__ float s_ex[64][4];
  int node = blockIdx.x, t = threadIdx.x;
  bool p1 = (node >= N_USER);
  const ushort* hs   = p1 ? hs1 : hs0;
  const float*  bias = p1 ? bias1 : bias0;
  int ch = 2 * t;
  int h = ch >> 7;
  float invd = 1.f / (denom[(size_t)node * 4 + h] + 1e-16f);
  float acc0 = 0.f, acc1 = 0.f;
  int jb = rp[node], je = rp[node + 1];
  for (int j0 = jb; j0 < je; j0 += 64) {
    int n = min(64, je - j0);
    __syncthreads();
    if (t < n) {
      s_src[t] = srcs[j0 + t];
      *(float4*)&s_ex[t][0] = exs[j0 + t];
    }
    __syncthreads();
#pragma unroll 4
    for (int j = 0; j < n; ++j) {
      int s = s_src[j];
      float al = s_ex[j][h] * invd;
      uint pv = *(const uint*)(hs + (size_t)s * SEM + ch);
      acc0 += b2f(pv & 0xffffu) * al;
      acc1 += b2f(pv >> 16) * al;
    }
  }
  float z0 = acc0 + bias[ch];
  float z1 = acc1 + bias[ch + 1];
  z0 = (z0 > 0.f) ? z0 : expm1f(z0);   // ELU
  z1 = (z1 > 0.f) ? z1 : expm1f(z1);
  uint o = (uint)f2b(z0) | ((uint)f2b(z1) << 16);
  *(uint*)(Zout + (size_t)node * SEM + ch) = o;
}

// -------- semantic attention combine: ZF = beta0*Z0 + beta1*Z1 (bf16) ------
__global__ __launch_bounds__(256) void combine_kernel(
    const float* __restrict__ T, const float* __restrict__ b1,
    const float* __restrict__ W2, const ushort* __restrict__ Z,
    ushort* __restrict__ ZF)
{
  __shared__ float red[256];
  __shared__ float beta[2];
  int node = blockIdx.x, t = threadIdx.x;
  int p = t >> 7, j = t & 127;
  float val = tanhf(T[(size_t)(p * N_USER + node) * HID + j] + b1[j]) * W2[j];
  red[t] = val;
  __syncthreads();
  for (int off = 64; off > 0; off >>= 1) {
    if (j < off) red[t] += red[t + off];
    __syncthreads();
  }
  if (t == 0) {
    float w0 = red[0], w1 = red[128];
    float mx = fmaxf(w0, w1);
    float e0 = expf(w0 - mx), e1 = expf(w1 - mx);
    float s = e0 + e1;
    beta[0] = e0 / s; beta[1] = e1 / s;
  }
  __syncthreads();
  float b0v = beta[0], b1v = beta[1];
  int ch = 2 * t;
  uint z0 = *(const uint*)(Z + (size_t)node * SEM + ch);
  uint z1 = *(const uint*)(Z + (size_t)(N_USER + node) * SEM + ch);
  float f0 = b0v * b2f(z0 & 0xffffu) + b1v * b2f(z1 & 0xffffu);
  float f1 = b0v * b2f(z0 >> 16)     + b1v * b2f(z1 >> 16);
  uint o = (uint)f2b(f0) | ((uint)f2b(f1) << 16);
  *(uint*)(ZF + (size_t)node * SEM + ch) = o;
}

extern "C" void kernel_launch(void* const* d_in, const int* in_sizes, int n_in,
                              void* d_out, int out_size, void* d_ws, size_t ws_size,
                              hipStream_t stream)
{
  const float* x_user = (const float*)d_in[0];
  const float* x_llm  = (const float*)d_in[1];
  const int* src0 = (const int*)d_in[2];
  const int* dst0 = (const int*)d_in[3];
  const int* src1 = (const int*)d_in[4];
  const int* dst1 = (const int*)d_in[5];
  const float* Wsrc0 = (const float*)d_in[6];
  const float* Wdst0 = (const float*)d_in[7];
  const float* asrc0 = (const float*)d_in[8];
  const float* adst0 = (const float*)d_in[9];
  const float* bias0 = (const float*)d_in[10];
  const float* Wsrc1 = (const float*)d_in[11];
  const float* Wdst1 = (const float*)d_in[12];
  const float* asrc1 = (const float*)d_in[13];
  const float* adst1 = (const float*)d_in[14];
  const float* bias1 = (const float*)d_in[15];
  const float* sem_W1 = (const float*)d_in[16];
  const float* sem_b1 = (const float*)d_in[17];
  const float* sem_W2 = (const float*)d_in[18];
  const float* out_W  = (const float*)d_in[19];
  const float* out_b  = (const float*)d_in[20];

  char* ws = (char*)d_ws;
  size_t off = 0;
  auto alloc = [&](size_t bytes) -> size_t {
    size_t o = off;
    off += (bytes + 255) & ~(size_t)255;
    return o;
  };

  size_t xbu_off  = alloc((size_t)MP_USER * IN_DIM * 2);   // 76.9 MB (later overlaid by T)
  size_t xbl_off  = alloc((size_t)MP_LLM  * IN_DIM * 2);   // 7.9 MB
  size_t wt0_off  = alloc((size_t)SEM * IN_DIM * 2);
  size_t wt1_off  = alloc((size_t)SEM * IN_DIM * 2);
  size_t wts_off  = alloc((size_t)HID * SEM * 2);
  size_t wto_off  = alloc((size_t)OUT_DIM * SEM * 2);
  size_t hs0_off  = alloc((size_t)MP_LLM  * SEM * 2);      // 5.2 MB
  size_t hs1_off  = alloc((size_t)MP_USER * SEM * 2);      // 51.2 MB (later overlaid by ZF)
  size_t Z_off    = alloc((size_t)MP_2U   * SEM * 2);      // 102.5 MB
  size_t sc_off   = alloc((size_t)2 * NE * 4);             // src in CSR order, 3.2 MB
  size_t xc_off   = alloc((size_t)2 * NE * 16);            // ev4 in CSR order, 12.8 MB
  size_t as0_off  = alloc((size_t)N_LLM  * 4 * 4);
  size_t as1_off  = alloc((size_t)N_USER * 4 * 4);
  size_t ad_off   = alloc((size_t)2 * N_USER * 4 * 4);
  size_t wf_off   = alloc((size_t)IN_DIM * 8 * 4);
  size_t den_off  = alloc((size_t)2 * N_USER * 4 * 4);     // zeroed
  size_t deg_off  = alloc((size_t)2 * N_USER * 4);         // zeroed
  size_t cur_off  = alloc((size_t)2 * N_USER * 4);         // zeroed
  size_t zero_end = off;
  size_t rp_off   = alloc((size_t)(2 * N_USER + 1) * 4);
  size_t bs_off   = alloc((size_t)128 * 4);
  size_t bo_off   = alloc((size_t)128 * 4);

  ushort* xb_u  = (ushort*)(ws + xbu_off);
  ushort* xb_l  = (ushort*)(ws + xbl_off);
  ushort* Wt0   = (ushort*)(ws + wt0_off);
  ushort* Wt1   = (ushort*)(ws + wt1_off);
  ushort* WtS   = (ushort*)(ws + wts_off);
  ushort* WtO   = (ushort*)(ws + wto_off);
  ushort* hs0b  = (ushort*)(ws + hs0_off);
  ushort* hs1b  = (ushort*)(ws + hs1_off);
  ushort* Zsw   = (ushort*)(ws + Z_off);
  float*  Tbuf  = (float*)(ws + xbu_off);   // overlay: xb dead after hs GEMMs
  ushort* ZF    = (ushort*)(ws + hs1_off);  // overlay: hs1 dead after agg
  int*    scsr  = (int*)(ws + sc_off);
  float4* xcsr  = (float4*)(ws + xc_off);
  float*  a_s0  = (float*)(ws + as0_off);
  float*  a_s1  = (float*)(ws + as1_off);
  float*  a_d   = (float*)(ws + ad_off);
  float*  wfold = (float*)(ws + wf_off);
  float*  denom = (float*)(ws + den_off);
  int*    deg   = (int*)(ws + deg_off);     // concatenated [2*N_USER]
  int*    cur   = (int*)(ws + cur_off);
  int*    rp    = (int*)(ws + rp_off);      // [2*N_USER+1]
  int*    bsum  = (int*)(ws + bs_off);
  int*    boff  = (int*)(ws + bo_off);

  hipMemsetAsync(ws + den_off, 0, zero_end - den_off, stream);

  // precompute: folds, casts, transposes
  fold_kernel<<<cdiv(IN_DIM * 8, 256), 256, 0, stream>>>(Wdst0, adst0, Wdst1, adst1, wfold);
  ad_kernel<<<cdiv(N_USER, 4), 256, 0, stream>>>(x_user, wfold, a_d, N_USER);
  cast_kernel<<<cdiv(N_USER * IN_DIM / 8, 256), 256, 0, stream>>>(x_user, xb_u, N_USER * IN_DIM / 8, 0);
  cast_kernel<<<cdiv(N_LLM * IN_DIM / 8, 256), 256, 0, stream>>>(x_llm, xb_l, N_LLM * IN_DIM / 8, 0);
  tc_kernel<<<cdiv(IN_DIM * SEM, 256), 256, 0, stream>>>(Wsrc0, Wt0, IN_DIM, SEM);
  tc_kernel<<<cdiv(IN_DIM * SEM, 256), 256, 0, stream>>>(Wsrc1, Wt1, IN_DIM, SEM);
  tc_kernel<<<cdiv(SEM * HID, 256), 256, 0, stream>>>(sem_W1, WtS, SEM, HID);
  tc_kernel<<<cdiv(SEM * OUT_DIM, 256), 256, 0, stream>>>(out_W, WtO, SEM, OUT_DIM);

  // degree histogram + CSR row pointers (independent of GEMMs)
  const int NTOT = 2 * N_USER;
  const int NB = cdiv(NTOT, 1024);   // 98
  edge1_kernel<<<cdiv(2 * NE, 256), 256, 0, stream>>>(dst0, dst1, deg);
  scan1<<<NB, 256, 0, stream>>>(deg, bsum, NTOT);
  scan2<<<1, 128, 0, stream>>>(bsum, boff, NB, rp + NTOT, 2 * NE);
  scan3<<<NB, 256, 0, stream>>>(deg, boff, rp, NTOT);

  // hs GEMMs (bf16 out)
  {
    dim3 g(SEM / 128, MP_LLM / 128);
    gemm_bf16<0><<<g, 256, 0, stream>>>(xb_l, Wt0, hs0b, nullptr, MP_LLM, SEM, IN_DIM);
  }
  {
    dim3 g(SEM / 128, MP_USER / 128);
    gemm_bf16<0><<<g, 256, 0, stream>>>(xb_u, Wt1, hs1b, nullptr, MP_USER, SEM, IN_DIM);
  }

  // attention logits
  as_kernel<<<N_LLM,  256, 0, stream>>>(hs0b, asrc0, a_s0);
  as_kernel<<<N_USER, 256, 0, stream>>>(hs1b, asrc1, a_s1);

  // per-edge exp + denom + direct CSR scatter of (src, ev4)
  edge2_kernel<<<cdiv(2 * NE, 256), 256, 0, stream>>>(src0, dst0, src1, dst1,
                                                      a_s0, a_s1, a_d,
                                                      rp, cur, scsr, xcsr, denom);

  // unified aggregation -> bf16 Z rows [0:N) path0, [N:2N) path1
  agg_kernel<<<NTOT, 256, 0, stream>>>(hs0b, hs1b, scsr, xcsr, denom, rp,
                                       bias0, bias1, Zsw);

  // T = Z @ sem_W1 (fp32 out, overlays dead xb_u)
  {
    dim3 g(HID / 128, MP_2U / 128);
    gemm_bf16<1><<<g, 256, 0, stream>>>(Zsw, WtS, Tbuf, nullptr, MP_2U, HID, SEM);
  }

  // semantic combine -> bf16 ZF (overlays dead hs1b)
  combine_kernel<<<N_USER, 256, 0, stream>>>(Tbuf, sem_b1, sem_W2, Zsw, ZF);

  // out = ZF @ out_W + out_b (fp32, guarded)
  {
    dim3 g(OUT_DIM / 128, MP_USER / 128);
    gemm_bf16<1><<<g, 256, 0, stream>>>(ZF, WtO, (float*)d_out, out_b, N_USER, OUT_DIM, SEM);
  }
}

// Round 4
// 665.036 us; speedup vs baseline: 3.0778x; 1.2181x over previous
//
#include <hip/hip_runtime.h>
#include <hip/hip_bf16.h>
#include <math.h>

constexpr int IN_DIM  = 768;
constexpr int HID     = 128;
constexpr int OUT_DIM = 256;
constexpr int SEM     = 512;     // HID*HEADS
constexpr int N_USER  = 50000;
constexpr int N_LLM   = 5000;
constexpr int NE      = 400000;

constexpr int MP_USER = 50048;   // 391*128
constexpr int MP_LLM  = 5120;    // 40*128
constexpr int MP_2U   = 100096;  // 782*128

typedef unsigned int uint;
typedef unsigned short ushort;
typedef __attribute__((ext_vector_type(8))) short bf16x8;
typedef __attribute__((ext_vector_type(4))) float f32x4;

static inline int cdiv(int a, int b) { return (a + b - 1) / b; }

__device__ __forceinline__ ushort f2b(float f) {
  uint u = __float_as_uint(f);
  u += 0x7FFFu + ((u >> 16) & 1u);       // RNE
  return (ushort)(u >> 16);
}
__device__ __forceinline__ float b2f(uint bits16) {
  return __uint_as_float(bits16 << 16);
}

#define GLOAD_LDS16(g, l) __builtin_amdgcn_global_load_lds( \
    (const __attribute__((address_space(1))) void*)(g), \
    (__attribute__((address_space(3))) void*)(l), 16, 0, 0)

// ---------------- bf16 MFMA GEMM: C[M,N] = A[Mpad,K] @ Bt[N,K]^T -----------
// 128x128 tile, BK=64, 256 threads (4 waves, 2x2 of 64x64 each).
// STORE_MODE 0: bf16 store, no guard (pad rows land in ws). 1: f32 +bias, row<Mreal guard.
template<int STORE_MODE>
__global__ __launch_bounds__(256) void gemm_bf16(
    const ushort* __restrict__ A, const ushort* __restrict__ Bt,
    void* __restrict__ Cout, const float* __restrict__ bias,
    int Mreal, int N, int K)
{
  __shared__ ushort As[128][64];   // 16 KB
  __shared__ ushort Bs[128][64];   // 16 KB
  const int t = threadIdx.x;
  const int wid = t >> 6, lane = t & 63;

  // bijective XCD-aware swizzle (m204)
  const int nwg  = gridDim.x * gridDim.y;
  const int orig = blockIdx.y * gridDim.x + blockIdx.x;
  const int q = nwg >> 3, r = nwg & 7;
  const int xcd = orig & 7, idx = orig >> 3;
  const int swz = (xcd < r ? xcd * (q + 1) : r * (q + 1) + (xcd - r) * q) + idx;
  const int bxi = swz % gridDim.x, byi = swz / gridDim.x;

  const int bm = byi * 128, bn = bxi * 128;
  const int lr = lane & 15, kg = lane >> 4;
  const int mbase = (wid >> 1) * 64, nbase = (wid & 1) * 64;
  const int grow = lane >> 3;          // 0..7 within chunk
  const int gcol = (lane & 7) * 8;     // element col, 16B granules

  f32x4 acc[4][4] = {};

  for (int k0 = 0; k0 < K; k0 += 64) {
#pragma unroll
    for (int c = 0; c < 4; ++c) {
      int ch = wid * 4 + c;            // 0..15, rows ch*8..ch*8+7
      const ushort* ga = A  + (size_t)(bm + ch * 8 + grow) * K + k0 + gcol;
      const ushort* gb = Bt + (size_t)(bn + ch * 8 + grow) * K + k0 + gcol;
      GLOAD_LDS16(ga, &As[ch * 8][0]);
      GLOAD_LDS16(gb, &Bs[ch * 8][0]);
    }
    asm volatile("s_waitcnt vmcnt(0)" ::: "memory");
    __syncthreads();
#pragma unroll
    for (int kb = 0; kb < 2; ++kb) {
      bf16x8 av[4], bv[4];
#pragma unroll
      for (int m = 0; m < 4; ++m)
        av[m] = *(const bf16x8*)&As[mbase + m * 16 + lr][kb * 32 + kg * 8];
#pragma unroll
      for (int n = 0; n < 4; ++n)
        bv[n] = *(const bf16x8*)&Bs[nbase + n * 16 + lr][kb * 32 + kg * 8];
#pragma unroll
      for (int m = 0; m < 4; ++m)
#pragma unroll
        for (int n = 0; n < 4; ++n)
          acc[m][n] = __builtin_amdgcn_mfma_f32_16x16x32_bf16(av[m], bv[n], acc[m][n], 0, 0, 0);
    }
    __syncthreads();
  }

#pragma unroll
  for (int m = 0; m < 4; ++m) {
#pragma unroll
    for (int j = 0; j < 4; ++j) {
      int row = bm + mbase + m * 16 + kg * 4 + j;
      if (STORE_MODE == 1 && row >= Mreal) continue;
#pragma unroll
      for (int n = 0; n < 4; ++n) {
        int col = bn + nbase + n * 16 + lr;
        float v = acc[m][n][j];
        if (STORE_MODE == 1) {
          if (bias) v += bias[col];
          ((float*)Cout)[(size_t)row * N + col] = v;
        } else {
          ((ushort*)Cout)[(size_t)row * N + col] = f2b(v);
        }
      }
    }
  }
}

// -------- cast fp32 row-major -> bf16 row-major (8 elems/thread) -----------
__global__ __launch_bounds__(256) void cast_kernel(
    const float* __restrict__ x, ushort* __restrict__ out, int total8)
{
  int i = blockIdx.x * 256 + threadIdx.x;
  if (i >= total8) return;
  const float4 a = *(const float4*)(x + (size_t)i * 8);
  const float4 b = *(const float4*)(x + (size_t)i * 8 + 4);
  uint4 o;
  o.x = (uint)f2b(a.x) | ((uint)f2b(a.y) << 16);
  o.y = (uint)f2b(a.z) | ((uint)f2b(a.w) << 16);
  o.z = (uint)f2b(b.x) | ((uint)f2b(b.y) << 16);
  o.w = (uint)f2b(b.z) | ((uint)f2b(b.w) << 16);
  *(uint4*)(out + (size_t)i * 8) = o;
}

// -------- transpose-cast: W fp32 [K][Nw] -> Bt bf16 [Nw][K] ----------------
__global__ __launch_bounds__(256) void tc_kernel(
    const float* __restrict__ W, ushort* __restrict__ Bt, int K, int Nw)
{
  int i = blockIdx.x * 256 + threadIdx.x;
  if (i >= K * Nw) return;
  int n = i / K, k = i - n * K;
  Bt[i] = f2b(W[(size_t)k * Nw + n]);
}

// ------------- fold W (768x512) against att (4x128) ------------------------
// wfold_u[768][12]: {Wdst0·adst0, Wdst1·adst1, Wsrc1·asrc1}
// wfold_l[768][4]:  {Wsrc0·asrc0}
__global__ void fold_kernel(const float* __restrict__ Wdst0, const float* __restrict__ adst0,
                            const float* __restrict__ Wdst1, const float* __restrict__ adst1,
                            const float* __restrict__ Wsrc1, const float* __restrict__ asrc1,
                            const float* __restrict__ Wsrc0, const float* __restrict__ asrc0,
                            float* __restrict__ wfold_u, float* __restrict__ wfold_l)
{
  int idx = blockIdx.x * 256 + threadIdx.x;   // 768*16
  if (idx >= IN_DIM * 16) return;
  int k = idx >> 4, hh = idx & 15;
  const float* W;
  const float* att;
  if (hh < 4)       { W = Wdst0; att = adst0; }
  else if (hh < 8)  { W = Wdst1; att = adst1; }
  else if (hh < 12) { W = Wsrc1; att = asrc1; }
  else              { W = Wsrc0; att = asrc0; }
  int h = hh & 3;
  float s = 0.f;
#pragma unroll 4
  for (int c = 0; c < HID; ++c)
    s += W[(size_t)k * SEM + h * HID + c] * att[h * HID + c];
  if (hh < 12) wfold_u[k * 12 + hh] = s;
  else         wfold_l[k * 4 + h]  = s;
}

// -------- user projections: a_d (both paths) + a_s1  (wave per node) -------
__global__ __launch_bounds__(256) void proj_user_kernel(
    const float* __restrict__ x, const float* __restrict__ wfold_u,
    float* __restrict__ a_d, float* __restrict__ a_s1, int n)
{
  int wid = threadIdx.x >> 6, lane = threadIdx.x & 63;
  int node = blockIdx.x * 4 + wid;
  if (node >= n) return;
  float acc[12] = {};
  for (int kk = lane; kk < IN_DIM; kk += 64) {
    float xv = x[(size_t)node * IN_DIM + kk];
    const float* wf = wfold_u + kk * 12;
#pragma unroll
    for (int h = 0; h < 12; ++h) acc[h] += xv * wf[h];
  }
#pragma unroll
  for (int off = 32; off > 0; off >>= 1) {
#pragma unroll
    for (int h = 0; h < 12; ++h) acc[h] += __shfl_down(acc[h], off);
  }
  if (lane == 0) {
#pragma unroll
    for (int h = 0; h < 4; ++h) a_d[(size_t)node * 4 + h] = acc[h];
#pragma unroll
    for (int h = 0; h < 4; ++h) a_d[(size_t)(N_USER + node) * 4 + h] = acc[4 + h];
#pragma unroll
    for (int h = 0; h < 4; ++h) a_s1[(size_t)node * 4 + h] = acc[8 + h];
  }
}

// -------- llm projection: a_s0 (wave per node) -----------------------------
__global__ __launch_bounds__(256) void proj_llm_kernel(
    const float* __restrict__ x, const float* __restrict__ wfold_l,
    float* __restrict__ a_s0, int n)
{
  int wid = threadIdx.x >> 6, lane = threadIdx.x & 63;
  int node = blockIdx.x * 4 + wid;
  if (node >= n) return;
  float acc[4] = {};
  for (int kk = lane; kk < IN_DIM; kk += 64) {
    float xv = x[(size_t)node * IN_DIM + kk];
    const float* wf = wfold_l + kk * 4;
#pragma unroll
    for (int h = 0; h < 4; ++h) acc[h] += xv * wf[h];
  }
#pragma unroll
  for (int off = 32; off > 0; off >>= 1) {
#pragma unroll
    for (int h = 0; h < 4; ++h) acc[h] += __shfl_down(acc[h], off);
  }
  if (lane == 0) {
#pragma unroll
    for (int h = 0; h < 4; ++h) a_s0[(size_t)node * 4 + h] = acc[h];
  }
}

// -------- pass 1: degree histogram over unified node space -----------------
__global__ void edge1_kernel(const int* __restrict__ dst0, const int* __restrict__ dst1,
                             int* __restrict__ deg)
{
  int e = blockIdx.x * 256 + threadIdx.x;
  if (e >= 2 * NE) return;
  int d = (e < NE) ? dst0[e] : (dst1[e - NE] + N_USER);
  atomicAdd(&deg[d], 1);
}

// -------- pass 2: scatter src (ushort) into CSR slots ----------------------
__global__ void scatter_kernel(const int* __restrict__ src0, const int* __restrict__ dst0,
                               const int* __restrict__ src1, const int* __restrict__ dst1,
                               const int* __restrict__ rp, int* __restrict__ cur,
                               ushort* __restrict__ scsr)
{
  int e = blockIdx.x * 256 + threadIdx.x;
  if (e >= 2 * NE) return;
  bool p1 = (e >= NE);
  int ee = p1 ? e - NE : e;
  int s = p1 ? src1[ee] : src0[ee];
  int d = p1 ? (dst1[ee] + N_USER) : dst0[ee];
  int pos = rp[d] + atomicAdd(&cur[d], 1);
  scsr[pos] = (ushort)s;
}

// -------- 3-phase scan over deg[0..n) --------------------------------------
__global__ __launch_bounds__(256) void scan1(const int* __restrict__ deg,
                                             int* __restrict__ bsum, int n)
{
  __shared__ int sm[256];
  int b = blockIdx.x, t = threadIdx.x;
  int base = b * 1024 + t * 4;
  int s = 0;
#pragma unroll
  for (int i = 0; i < 4; ++i) if (base + i < n) s += deg[base + i];
  sm[t] = s;
  __syncthreads();
  for (int off = 128; off > 0; off >>= 1) {
    if (t < off) sm[t] += sm[t + off];
    __syncthreads();
  }
  if (t == 0) bsum[b] = sm[0];
}

__global__ __launch_bounds__(128) void scan2(const int* __restrict__ bsum,
                                             int* __restrict__ boff, int nb,
                                             int* __restrict__ rp_tail, int tailval)
{
  __shared__ int sm[128];
  int t = threadIdx.x;
  int v = (t < nb) ? bsum[t] : 0;
  sm[t] = v;
  __syncthreads();
  for (int off = 1; off < 128; off <<= 1) {
    int x = (t >= off) ? sm[t - off] : 0;
    __syncthreads();
    sm[t] += x;
    __syncthreads();
  }
  if (t < nb) boff[t] = sm[t] - v;
  if (t == 0) *rp_tail = tailval;
}

__global__ __launch_bounds__(256) void scan3(const int* __restrict__ deg,
                                             const int* __restrict__ boff,
                                             int* __restrict__ rp, int n)
{
  __shared__ int sm[256];
  int b = blockIdx.x, t = threadIdx.x;
  int base = b * 1024 + t * 4;
  int v[4];
#pragma unroll
  for (int i = 0; i < 4; ++i) v[i] = (base + i < n) ? deg[base + i] : 0;
  int tsum = v[0] + v[1] + v[2] + v[3];
  sm[t] = tsum;
  __syncthreads();
  for (int off = 1; off < 256; off <<= 1) {
    int x = (t >= off) ? sm[t - off] : 0;
    __syncthreads();
    sm[t] += x;
    __syncthreads();
  }
  int run = sm[t] - tsum + boff[b];
#pragma unroll
  for (int i = 0; i < 4; ++i) {
    if (base + i < n) rp[base + i] = run;
    run += v[i];
  }
}

// -------- unified aggregation over 2*N_USER nodes --------------------------
// Block = one dst node. z = (sum ev*hs)/(sum ev) + bias, ev computed on the
// fly from folded logits (no per-edge materialization, no denom atomics).
__global__ __launch_bounds__(256) void agg_kernel(
    const ushort* __restrict__ hs0, const ushort* __restrict__ hs1,
    const ushort* __restrict__ srcs,
    const float* __restrict__ a_s0, const float* __restrict__ a_s1,
    const float* __restrict__ a_d, const int* __restrict__ rp,
    const float* __restrict__ bias0, const float* __restrict__ bias1,
    ushort* __restrict__ Zout)
{
  __shared__ ushort s_src[64];
  __shared__ float  s_ex[64][4];
  int node = blockIdx.x, t = threadIdx.x;
  bool p1 = (node >= N_USER);
  const ushort* hs   = p1 ? hs1 : hs0;
  const float*  as   = p1 ? a_s1 : a_s0;
  const float*  bias = p1 ? bias1 : bias0;
  float4 ad4 = *(const float4*)(a_d + (size_t)node * 4);
  int ch = 2 * t;
  int h = ch >> 7;
  float acc0 = 0.f, acc1 = 0.f, dsum = 0.f;
  int jb = rp[node], je = rp[node + 1];
  for (int j0 = jb; j0 < je; j0 += 64) {
    int n = min(64, je - j0);
    __syncthreads();
    if (t < n) {
      ushort s = srcs[j0 + t];
      s_src[t] = s;
      float4 as4 = *(const float4*)(as + (size_t)s * 4);
      float v0 = as4.x + ad4.x, v1 = as4.y + ad4.y;
      float v2 = as4.z + ad4.z, v3 = as4.w + ad4.w;
      v0 = (v0 > 0.f) ? v0 : 0.2f * v0;   // leaky_relu(0.2)
      v1 = (v1 > 0.f) ? v1 : 0.2f * v1;
      v2 = (v2 > 0.f) ? v2 : 0.2f * v2;
      v3 = (v3 > 0.f) ? v3 : 0.2f * v3;
      s_ex[t][0] = __expf(v0) == 0.f ? expf(v0) : expf(v0);  // keep precise expf
      s_ex[t][1] = expf(v1);
      s_ex[t][2] = expf(v2);
      s_ex[t][3] = expf(v3);
    }
    __syncthreads();
#pragma unroll 4
    for (int j = 0; j < n; ++j) {
      int s = s_src[j];
      float e = s_ex[j][h];
      uint pv = *(const uint*)(hs + (size_t)s * SEM + ch);
      acc0 += b2f(pv & 0xffffu) * e;
      acc1 += b2f(pv >> 16) * e;
      dsum += e;
    }
  }
  float inv = 1.f / (dsum + 1e-16f);
  float z0 = acc0 * inv + bias[ch];
  float z1 = acc1 * inv + bias[ch + 1];
  z0 = (z0 > 0.f) ? z0 : expm1f(z0);   // ELU
  z1 = (z1 > 0.f) ? z1 : expm1f(z1);
  uint o = (uint)f2b(z0) | ((uint)f2b(z1) << 16);
  *(uint*)(Zout + (size_t)node * SEM + ch) = o;
}

// -------- semantic attention combine: ZF = beta0*Z0 + beta1*Z1 (bf16) ------
__global__ __launch_bounds__(256) void combine_kernel(
    const float* __restrict__ T, const float* __restrict__ b1,
    const float* __restrict__ W2, const ushort* __restrict__ Z,
    ushort* __restrict__ ZF)
{
  __shared__ float red[256];
  __shared__ float beta[2];
  int node = blockIdx.x, t = threadIdx.x;
  int p = t >> 7, j = t & 127;
  float val = tanhf(T[(size_t)(p * N_USER + node) * HID + j] + b1[j]) * W2[j];
  red[t] = val;
  __syncthreads();
  for (int off = 64; off > 0; off >>= 1) {
    if (j < off) red[t] += red[t + off];
    __syncthreads();
  }
  if (t == 0) {
    float w0 = red[0], w1 = red[128];
    float mx = fmaxf(w0, w1);
    float e0 = expf(w0 - mx), e1 = expf(w1 - mx);
    float s = e0 + e1;
    beta[0] = e0 / s; beta[1] = e1 / s;
  }
  __syncthreads();
  float b0v = beta[0], b1v = beta[1];
  int ch = 2 * t;
  uint z0 = *(const uint*)(Z + (size_t)node * SEM + ch);
  uint z1 = *(const uint*)(Z + (size_t)(N_USER + node) * SEM + ch);
  float f0 = b0v * b2f(z0 & 0xffffu) + b1v * b2f(z1 & 0xffffu);
  float f1 = b0v * b2f(z0 >> 16)     + b1v * b2f(z1 >> 16);
  uint o = (uint)f2b(f0) | ((uint)f2b(f1) << 16);
  *(uint*)(ZF + (size_t)node * SEM + ch) = o;
}

extern "C" void kernel_launch(void* const* d_in, const int* in_sizes, int n_in,
                              void* d_out, int out_size, void* d_ws, size_t ws_size,
                              hipStream_t stream)
{
  const float* x_user = (const float*)d_in[0];
  const float* x_llm  = (const float*)d_in[1];
  const int* src0 = (const int*)d_in[2];
  const int* dst0 = (const int*)d_in[3];
  const int* src1 = (const int*)d_in[4];
  const int* dst1 = (const int*)d_in[5];
  const float* Wsrc0 = (const float*)d_in[6];
  const float* Wdst0 = (const float*)d_in[7];
  const float* asrc0 = (const float*)d_in[8];
  const float* adst0 = (const float*)d_in[9];
  const float* bias0 = (const float*)d_in[10];
  const float* Wsrc1 = (const float*)d_in[11];
  const float* Wdst1 = (const float*)d_in[12];
  const float* asrc1 = (const float*)d_in[13];
  const float* adst1 = (const float*)d_in[14];
  const float* bias1 = (const float*)d_in[15];
  const float* sem_W1 = (const float*)d_in[16];
  const float* sem_b1 = (const float*)d_in[17];
  const float* sem_W2 = (const float*)d_in[18];
  const float* out_W  = (const float*)d_in[19];
  const float* out_b  = (const float*)d_in[20];

  char* ws = (char*)d_ws;
  size_t off = 0;
  auto alloc = [&](size_t bytes) -> size_t {
    size_t o = off;
    off += (bytes + 255) & ~(size_t)255;
    return o;
  };

  size_t xbu_off  = alloc((size_t)MP_USER * IN_DIM * 2);   // 76.9 MB (later overlaid by T)
  size_t xbl_off  = alloc((size_t)MP_LLM  * IN_DIM * 2);   // 7.9 MB
  size_t wt0_off  = alloc((size_t)SEM * IN_DIM * 2);
  size_t wt1_off  = alloc((size_t)SEM * IN_DIM * 2);
  size_t wts_off  = alloc((size_t)HID * SEM * 2);
  size_t wto_off  = alloc((size_t)OUT_DIM * SEM * 2);
  size_t hs0_off  = alloc((size_t)MP_LLM  * SEM * 2);      // 5.2 MB
  size_t hs1_off  = alloc((size_t)MP_USER * SEM * 2);      // 51.2 MB (later overlaid by ZF)
  size_t Z_off    = alloc((size_t)MP_2U   * SEM * 2);      // 102.5 MB
  size_t sc_off   = alloc((size_t)2 * NE * 2);             // src ushort, CSR order, 1.6 MB
  size_t as0_off  = alloc((size_t)N_LLM  * 4 * 4);
  size_t as1_off  = alloc((size_t)N_USER * 4 * 4);
  size_t ad_off   = alloc((size_t)2 * N_USER * 4 * 4);
  size_t wfu_off  = alloc((size_t)IN_DIM * 12 * 4);
  size_t wfl_off  = alloc((size_t)IN_DIM * 4 * 4);
  size_t deg_off  = alloc((size_t)2 * N_USER * 4);         // zeroed
  size_t cur_off  = alloc((size_t)2 * N_USER * 4);         // zeroed
  size_t zero_end = off;
  size_t rp_off   = alloc((size_t)(2 * N_USER + 1) * 4);
  size_t bs_off   = alloc((size_t)128 * 4);
  size_t bo_off   = alloc((size_t)128 * 4);

  ushort* xb_u  = (ushort*)(ws + xbu_off);
  ushort* xb_l  = (ushort*)(ws + xbl_off);
  ushort* Wt0   = (ushort*)(ws + wt0_off);
  ushort* Wt1   = (ushort*)(ws + wt1_off);
  ushort* WtS   = (ushort*)(ws + wts_off);
  ushort* WtO   = (ushort*)(ws + wto_off);
  ushort* hs0b  = (ushort*)(ws + hs0_off);
  ushort* hs1b  = (ushort*)(ws + hs1_off);
  ushort* Zsw   = (ushort*)(ws + Z_off);
  float*  Tbuf  = (float*)(ws + xbu_off);   // overlay: xb dead after hs GEMMs
  ushort* ZF    = (ushort*)(ws + hs1_off);  // overlay: hs1 dead after agg
  ushort* scsr  = (ushort*)(ws + sc_off);
  float*  a_s0  = (float*)(ws + as0_off);
  float*  a_s1  = (float*)(ws + as1_off);
  float*  a_d   = (float*)(ws + ad_off);
  float*  wfu   = (float*)(ws + wfu_off);
  float*  wfl   = (float*)(ws + wfl_off);
  int*    deg   = (int*)(ws + deg_off);     // concatenated [2*N_USER]
  int*    cur   = (int*)(ws + cur_off);
  int*    rp    = (int*)(ws + rp_off);      // [2*N_USER+1]
  int*    bsum  = (int*)(ws + bs_off);
  int*    boff  = (int*)(ws + bo_off);

  hipMemsetAsync(ws + deg_off, 0, zero_end - deg_off, stream);

  // folds + fp32 logit projections
  fold_kernel<<<cdiv(IN_DIM * 16, 256), 256, 0, stream>>>(
      Wdst0, adst0, Wdst1, adst1, Wsrc1, asrc1, Wsrc0, asrc0, wfu, wfl);
  proj_user_kernel<<<cdiv(N_USER, 4), 256, 0, stream>>>(x_user, wfu, a_d, a_s1, N_USER);
  proj_llm_kernel<<<cdiv(N_LLM, 4), 256, 0, stream>>>(x_llm, wfl, a_s0, N_LLM);

  // casts + weight transposes
  cast_kernel<<<cdiv(N_USER * IN_DIM / 8, 256), 256, 0, stream>>>(x_user, xb_u, N_USER * IN_DIM / 8);
  cast_kernel<<<cdiv(N_LLM * IN_DIM / 8, 256), 256, 0, stream>>>(x_llm, xb_l, N_LLM * IN_DIM / 8);
  tc_kernel<<<cdiv(IN_DIM * SEM, 256), 256, 0, stream>>>(Wsrc0, Wt0, IN_DIM, SEM);
  tc_kernel<<<cdiv(IN_DIM * SEM, 256), 256, 0, stream>>>(Wsrc1, Wt1, IN_DIM, SEM);
  tc_kernel<<<cdiv(SEM * HID, 256), 256, 0, stream>>>(sem_W1, WtS, SEM, HID);
  tc_kernel<<<cdiv(SEM * OUT_DIM, 256), 256, 0, stream>>>(out_W, WtO, SEM, OUT_DIM);

  // CSR build over unified node space
  const int NTOT = 2 * N_USER;
  const int NB = cdiv(NTOT, 1024);   // 98
  edge1_kernel<<<cdiv(2 * NE, 256), 256, 0, stream>>>(dst0, dst1, deg);
  scan1<<<NB, 256, 0, stream>>>(deg, bsum, NTOT);
  scan2<<<1, 128, 0, stream>>>(bsum, boff, NB, rp + NTOT, 2 * NE);
  scan3<<<NB, 256, 0, stream>>>(deg, boff, rp, NTOT);
  scatter_kernel<<<cdiv(2 * NE, 256), 256, 0, stream>>>(src0, dst0, src1, dst1, rp, cur, scsr);

  // hs GEMMs (bf16 out)
  {
    dim3 g(SEM / 128, MP_LLM / 128);
    gemm_bf16<0><<<g, 256, 0, stream>>>(xb_l, Wt0, hs0b, nullptr, MP_LLM, SEM, IN_DIM);
  }
  {
    dim3 g(SEM / 128, MP_USER / 128);
    gemm_bf16<0><<<g, 256, 0, stream>>>(xb_u, Wt1, hs1b, nullptr, MP_USER, SEM, IN_DIM);
  }

  // unified aggregation -> bf16 Z rows [0:N) path0, [N:2N) path1
  agg_kernel<<<NTOT, 256, 0, stream>>>(hs0b, hs1b, scsr, a_s0, a_s1, a_d, rp,
                                       bias0, bias1, Zsw);

  // T = Z @ sem_W1 (fp32 out, overlays dead xb_u)
  {
    dim3 g(HID / 128, MP_2U / 128);
    gemm_bf16<1><<<g, 256, 0, stream>>>(Zsw, WtS, Tbuf, nullptr, MP_2U, HID, SEM);
  }

  // semantic combine -> bf16 ZF (overlays dead hs1b)
  combine_kernel<<<N_USER, 256, 0, stream>>>(Tbuf, sem_b1, sem_W2, Zsw, ZF);

  // out = ZF @ out_W + out_b (fp32, guarded)
  {
    dim3 g(OUT_DIM / 128, MP_USER / 128);
    gemm_bf16<1><<<g, 256, 0, stream>>>(ZF, WtO, (float*)d_out, out_b, N_USER, OUT_DIM, SEM);
  }
}

// Round 5
// 618.465 us; speedup vs baseline: 3.3096x; 1.0753x over previous
//
#include <hip/hip_runtime.h>
#include <hip/hip_bf16.h>
#include <math.h>

constexpr int IN_DIM  = 768;
constexpr int HID     = 128;
constexpr int OUT_DIM = 256;
constexpr int SEM     = 512;     // HID*HEADS
constexpr int N_USER  = 50000;
constexpr int N_LLM   = 5000;
constexpr int NE      = 400000;

constexpr int MP_USER = 50048;   // 391*128
constexpr int MP_LLM  = 5120;    // 40*128
constexpr int MP_2U   = 100096;  // 782*128

typedef unsigned int uint;
typedef unsigned short ushort;
typedef __attribute__((ext_vector_type(8))) short bf16x8;
typedef __attribute__((ext_vector_type(4))) float f32x4;

static inline int cdiv(int a, int b) { return (a + b - 1) / b; }

__device__ __forceinline__ ushort f2b(float f) {
  uint u = __float_as_uint(f);
  u += 0x7FFFu + ((u >> 16) & 1u);       // RNE
  return (ushort)(u >> 16);
}
__device__ __forceinline__ float b2f(uint bits16) {
  return __uint_as_float(bits16 << 16);
}

#define GLOAD_LDS16(g, l) __builtin_amdgcn_global_load_lds( \
    (const __attribute__((address_space(1))) void*)(g), \
    (__attribute__((address_space(3))) void*)(l), 16, 0, 0)

// ---------------- bf16 MFMA GEMM: C[M,N] = A[Mpad,K] @ Bt[N,K]^T -----------
// 128x128 tile, BK=64, 256 threads (4 waves, 2x2 of 64x64 each).
// STORE_MODE 0: bf16 store, no guard (pad rows land in ws). 1: f32 +bias, row<Mreal guard.
template<int STORE_MODE>
__global__ __launch_bounds__(256) void gemm_bf16(
    const ushort* __restrict__ A, const ushort* __restrict__ Bt,
    void* __restrict__ Cout, const float* __restrict__ bias,
    int Mreal, int N, int K)
{
  __shared__ ushort As[128][64];   // 16 KB
  __shared__ ushort Bs[128][64];   // 16 KB
  const int t = threadIdx.x;
  const int wid = t >> 6, lane = t & 63;

  // bijective XCD-aware swizzle (m204)
  const int nwg  = gridDim.x * gridDim.y;
  const int orig = blockIdx.y * gridDim.x + blockIdx.x;
  const int q = nwg >> 3, r = nwg & 7;
  const int xcd = orig & 7, idx = orig >> 3;
  const int swz = (xcd < r ? xcd * (q + 1) : r * (q + 1) + (xcd - r) * q) + idx;
  const int bxi = swz % gridDim.x, byi = swz / gridDim.x;

  const int bm = byi * 128, bn = bxi * 128;
  const int lr = lane & 15, kg = lane >> 4;
  const int mbase = (wid >> 1) * 64, nbase = (wid & 1) * 64;
  const int grow = lane >> 3;          // 0..7 within chunk
  const int gcol = (lane & 7) * 8;     // element col, 16B granules

  f32x4 acc[4][4] = {};

  for (int k0 = 0; k0 < K; k0 += 64) {
#pragma unroll
    for (int c = 0; c < 4; ++c) {
      int ch = wid * 4 + c;            // 0..15, rows ch*8..ch*8+7
      const ushort* ga = A  + (size_t)(bm + ch * 8 + grow) * K + k0 + gcol;
      const ushort* gb = Bt + (size_t)(bn + ch * 8 + grow) * K + k0 + gcol;
      GLOAD_LDS16(ga, &As[ch * 8][0]);
      GLOAD_LDS16(gb, &Bs[ch * 8][0]);
    }
    asm volatile("s_waitcnt vmcnt(0)" ::: "memory");
    __syncthreads();
#pragma unroll
    for (int kb = 0; kb < 2; ++kb) {
      bf16x8 av[4], bv[4];
#pragma unroll
      for (int m = 0; m < 4; ++m)
        av[m] = *(const bf16x8*)&As[mbase + m * 16 + lr][kb * 32 + kg * 8];
#pragma unroll
      for (int n = 0; n < 4; ++n)
        bv[n] = *(const bf16x8*)&Bs[nbase + n * 16 + lr][kb * 32 + kg * 8];
#pragma unroll
      for (int m = 0; m < 4; ++m)
#pragma unroll
        for (int n = 0; n < 4; ++n)
          acc[m][n] = __builtin_amdgcn_mfma_f32_16x16x32_bf16(av[m], bv[n], acc[m][n], 0, 0, 0);
    }
    __syncthreads();
  }

#pragma unroll
  for (int m = 0; m < 4; ++m) {
#pragma unroll
    for (int j = 0; j < 4; ++j) {
      int row = bm + mbase + m * 16 + kg * 4 + j;
      if (STORE_MODE == 1 && row >= Mreal) continue;
#pragma unroll
      for (int n = 0; n < 4; ++n) {
        int col = bn + nbase + n * 16 + lr;
        float v = acc[m][n][j];
        if (STORE_MODE == 1) {
          if (bias) v += bias[col];
          ((float*)Cout)[(size_t)row * N + col] = v;
        } else {
          ((ushort*)Cout)[(size_t)row * N + col] = f2b(v);
        }
      }
    }
  }
}

// -------- transpose-cast: W fp32 [K][Nw] -> Bt bf16 [Nw][K] ----------------
__global__ __launch_bounds__(256) void tc_kernel(
    const float* __restrict__ W, ushort* __restrict__ Bt, int K, int Nw)
{
  int i = blockIdx.x * 256 + threadIdx.x;
  if (i >= K * Nw) return;
  int n = i / K, k = i - n * K;
  Bt[i] = f2b(W[(size_t)k * Nw + n]);
}

// ------------- fold W (768x512) against att (4x128) ------------------------
// wfold_u[768][12]: {Wdst0·adst0, Wdst1·adst1, Wsrc1·asrc1}
// wfold_l[768][4]:  {Wsrc0·asrc0}
__global__ void fold_kernel(const float* __restrict__ Wdst0, const float* __restrict__ adst0,
                            const float* __restrict__ Wdst1, const float* __restrict__ adst1,
                            const float* __restrict__ Wsrc1, const float* __restrict__ asrc1,
                            const float* __restrict__ Wsrc0, const float* __restrict__ asrc0,
                            float* __restrict__ wfold_u, float* __restrict__ wfold_l)
{
  int idx = blockIdx.x * 256 + threadIdx.x;   // 768*16
  if (idx >= IN_DIM * 16) return;
  int k = idx >> 4, hh = idx & 15;
  const float* W;
  const float* att;
  if (hh < 4)       { W = Wdst0; att = adst0; }
  else if (hh < 8)  { W = Wdst1; att = adst1; }
  else if (hh < 12) { W = Wsrc1; att = asrc1; }
  else              { W = Wsrc0; att = asrc0; }
  int h = hh & 3;
  float s = 0.f;
#pragma unroll 4
  for (int c = 0; c < HID; ++c)
    s += W[(size_t)k * SEM + h * HID + c] * att[h * HID + c];
  if (hh < 12) wfold_u[k * 12 + hh] = s;
  else         wfold_l[k * 4 + h]  = s;
}

// -------- fused cast(x->bf16) + folded logit projections (wave per node) ---
// NH=12 (user): outA=a_d[p0], outB=a_d[p1], outC=a_s1. NH=4 (llm): outA=a_s0.
template<int NH>
__global__ __launch_bounds__(256) void proj_cast_kernel(
    const float* __restrict__ x, const float* __restrict__ wfold,
    ushort* __restrict__ xb, float* __restrict__ outA,
    float* __restrict__ outB, float* __restrict__ outC, int n)
{
  int wid = threadIdx.x >> 6, lane = threadIdx.x & 63;
  int node = blockIdx.x * 4 + wid;
  if (node >= n) return;
  float acc[NH];
#pragma unroll
  for (int hh = 0; hh < NH; ++hh) acc[hh] = 0.f;
  const float* xr = x + (size_t)node * IN_DIM;
  uint* xbo = (uint*)(xb + (size_t)node * IN_DIM);
#pragma unroll
  for (int i = 0; i < IN_DIM / 128; ++i) {   // 6 iters, float2 per lane
    int p = i * 64 + lane;                   // pair index 0..383
    float2 xv = *(const float2*)(xr + 2 * p);
    const float* wf = wfold + (size_t)(2 * p) * NH;
#pragma unroll
    for (int hh = 0; hh < NH; ++hh) acc[hh] += xv.x * wf[hh] + xv.y * wf[NH + hh];
    xbo[p] = (uint)f2b(xv.x) | ((uint)f2b(xv.y) << 16);
  }
#pragma unroll
  for (int off2 = 32; off2 > 0; off2 >>= 1) {
#pragma unroll
    for (int hh = 0; hh < NH; ++hh) acc[hh] += __shfl_down(acc[hh], off2);
  }
  if (lane == 0) {
#pragma unroll
    for (int h = 0; h < 4; ++h) outA[(size_t)node * 4 + h] = acc[h];
    if (NH == 12) {
#pragma unroll
      for (int h = 0; h < 4; ++h) outB[(size_t)node * 4 + h] = acc[4 + h];
#pragma unroll
      for (int h = 0; h < 4; ++h) outC[(size_t)node * 4 + h] = acc[8 + h];
    }
  }
}

// -------- pass 1: degree histogram over unified node space -----------------
__global__ void edge1_kernel(const int* __restrict__ dst0, const int* __restrict__ dst1,
                             int* __restrict__ deg)
{
  int e = blockIdx.x * 256 + threadIdx.x;
  if (e >= 2 * NE) return;
  int d = (e < NE) ? dst0[e] : (dst1[e - NE] + N_USER);
  atomicAdd(&deg[d], 1);
}

// -------- pass 2: scatter src (ushort) into CSR slots ----------------------
__global__ void scatter_kernel(const int* __restrict__ src0, const int* __restrict__ dst0,
                               const int* __restrict__ src1, const int* __restrict__ dst1,
                               const int* __restrict__ rp, int* __restrict__ cur,
                               ushort* __restrict__ scsr)
{
  int e = blockIdx.x * 256 + threadIdx.x;
  if (e >= 2 * NE) return;
  bool p1 = (e >= NE);
  int ee = p1 ? e - NE : e;
  int s = p1 ? src1[ee] : src0[ee];
  int d = p1 ? (dst1[ee] + N_USER) : dst0[ee];
  int pos = rp[d] + atomicAdd(&cur[d], 1);
  scsr[pos] = (ushort)s;
}

// -------- 3-phase scan over deg[0..n) --------------------------------------
__global__ __launch_bounds__(256) void scan1(const int* __restrict__ deg,
                                             int* __restrict__ bsum, int n)
{
  __shared__ int sm[256];
  int b = blockIdx.x, t = threadIdx.x;
  int base = b * 1024 + t * 4;
  int s = 0;
#pragma unroll
  for (int i = 0; i < 4; ++i) if (base + i < n) s += deg[base + i];
  sm[t] = s;
  __syncthreads();
  for (int off = 128; off > 0; off >>= 1) {
    if (t < off) sm[t] += sm[t + off];
    __syncthreads();
  }
  if (t == 0) bsum[b] = sm[0];
}

__global__ __launch_bounds__(128) void scan2(const int* __restrict__ bsum,
                                             int* __restrict__ boff, int nb,
                                             int* __restrict__ rp_tail, int tailval)
{
  __shared__ int sm[128];
  int t = threadIdx.x;
  int v = (t < nb) ? bsum[t] : 0;
  sm[t] = v;
  __syncthreads();
  for (int off = 1; off < 128; off <<= 1) {
    int x = (t >= off) ? sm[t - off] : 0;
    __syncthreads();
    sm[t] += x;
    __syncthreads();
  }
  if (t < nb) boff[t] = sm[t] - v;
  if (t == 0) *rp_tail = tailval;
}

__global__ __launch_bounds__(256) void scan3(const int* __restrict__ deg,
                                             const int* __restrict__ boff,
                                             int* __restrict__ rp, int n)
{
  __shared__ int sm[256];
  int b = blockIdx.x, t = threadIdx.x;
  int base = b * 1024 + t * 4;
  int v[4];
#pragma unroll
  for (int i = 0; i < 4; ++i) v[i] = (base + i < n) ? deg[base + i] : 0;
  int tsum = v[0] + v[1] + v[2] + v[3];
  sm[t] = tsum;
  __syncthreads();
  for (int off = 1; off < 256; off <<= 1) {
    int x = (t >= off) ? sm[t - off] : 0;
    __syncthreads();
    sm[t] += x;
    __syncthreads();
  }
  int run = sm[t] - tsum + boff[b];
#pragma unroll
  for (int i = 0; i < 4; ++i) {
    if (base + i < n) rp[base + i] = run;
    run += v[i];
  }
}

// -------- unified aggregation: ONE WAVE per dst node -----------------------
// Lane owns 8 channels (16B). Per edge: one dwordx4 gather (wave covers the
// full 1KB hs row) + 8 unpack-fma. ev computed on the fly during staging.
__global__ __launch_bounds__(64) void agg_kernel(
    const ushort* __restrict__ hs0, const ushort* __restrict__ hs1,
    const ushort* __restrict__ srcs,
    const float* __restrict__ a_s0, const float* __restrict__ a_s1,
    const float* __restrict__ a_d, const int* __restrict__ rp,
    const float* __restrict__ bias0, const float* __restrict__ bias1,
    ushort* __restrict__ Zout)
{
  __shared__ ushort s_src[64];
  __shared__ float  s_ev[64][4];
  int node = blockIdx.x, lane = threadIdx.x;
  bool p1 = (node >= N_USER);
  const ushort* hs   = p1 ? hs1 : hs0;
  const float*  as   = p1 ? a_s1 : a_s0;
  const float*  bias = p1 ? bias1 : bias0;
  float4 ad4 = *(const float4*)(a_d + (size_t)node * 4);
  int h  = lane >> 4;          // head for this lane's channels
  int cb = lane * 8;           // channel base
  float acc[8] = {};
  float dsum = 0.f;
  int jb = rp[node], je = rp[node + 1];
  for (int j0 = jb; j0 < je; j0 += 64) {
    int n = min(64, je - j0);
    __syncthreads();
    if (lane < n) {
      int s = srcs[j0 + lane];
      s_src[lane] = (ushort)s;
      float4 as4 = *(const float4*)(as + (size_t)s * 4);
      float v0 = as4.x + ad4.x, v1 = as4.y + ad4.y;
      float v2 = as4.z + ad4.z, v3 = as4.w + ad4.w;
      v0 = (v0 > 0.f) ? v0 : 0.2f * v0;   // leaky_relu(0.2)
      v1 = (v1 > 0.f) ? v1 : 0.2f * v1;
      v2 = (v2 > 0.f) ? v2 : 0.2f * v2;
      v3 = (v3 > 0.f) ? v3 : 0.2f * v3;
      s_ev[lane][0] = expf(v0);
      s_ev[lane][1] = expf(v1);
      s_ev[lane][2] = expf(v2);
      s_ev[lane][3] = expf(v3);
    }
    __syncthreads();
#pragma unroll 2
    for (int j = 0; j < n; ++j) {
      int s = s_src[j];
      float e = s_ev[j][h];
      uint4 pv = *(const uint4*)(hs + (size_t)s * SEM + cb);
      acc[0] += b2f(pv.x & 0xffffu) * e;  acc[1] += b2f(pv.x >> 16) * e;
      acc[2] += b2f(pv.y & 0xffffu) * e;  acc[3] += b2f(pv.y >> 16) * e;
      acc[4] += b2f(pv.z & 0xffffu) * e;  acc[5] += b2f(pv.z >> 16) * e;
      acc[6] += b2f(pv.w & 0xffffu) * e;  acc[7] += b2f(pv.w >> 16) * e;
      dsum += e;
    }
  }
  float inv = 1.f / (dsum + 1e-16f);
  uint4 o;
  uint* op = (uint*)&o;
#pragma unroll
  for (int i = 0; i < 4; ++i) {
    float z0 = acc[2 * i]     * inv + bias[cb + 2 * i];
    float z1 = acc[2 * i + 1] * inv + bias[cb + 2 * i + 1];
    z0 = (z0 > 0.f) ? z0 : expm1f(z0);   // ELU
    z1 = (z1 > 0.f) ? z1 : expm1f(z1);
    op[i] = (uint)f2b(z0) | ((uint)f2b(z1) << 16);
  }
  *(uint4*)(Zout + (size_t)node * SEM + cb) = o;
}

// -------- semantic attention combine (T in bf16): ZF = b0*Z0 + b1*Z1 -------
__global__ __launch_bounds__(256) void combine_kernel(
    const ushort* __restrict__ T, const float* __restrict__ b1,
    const float* __restrict__ W2, const ushort* __restrict__ Z,
    ushort* __restrict__ ZF)
{
  __shared__ float red[256];
  __shared__ float beta[2];
  int node = blockIdx.x, t = threadIdx.x;
  int p = t >> 7, j = t & 127;
  float tv = b2f(T[(size_t)(p * N_USER + node) * HID + j]);
  float val = tanhf(tv + b1[j]) * W2[j];
  red[t] = val;
  __syncthreads();
  for (int off = 64; off > 0; off >>= 1) {
    if (j < off) red[t] += red[t + off];
    __syncthreads();
  }
  if (t == 0) {
    float w0 = red[0], w1 = red[128];
    float mx = fmaxf(w0, w1);
    float e0 = expf(w0 - mx), e1 = expf(w1 - mx);
    float s = e0 + e1;
    beta[0] = e0 / s; beta[1] = e1 / s;
  }
  __syncthreads();
  float b0v = beta[0], b1v = beta[1];
  int ch = 2 * t;
  uint z0 = *(const uint*)(Z + (size_t)node * SEM + ch);
  uint z1 = *(const uint*)(Z + (size_t)(N_USER + node) * SEM + ch);
  float f0 = b0v * b2f(z0 & 0xffffu) + b1v * b2f(z1 & 0xffffu);
  float f1 = b0v * b2f(z0 >> 16)     + b1v * b2f(z1 >> 16);
  uint o = (uint)f2b(f0) | ((uint)f2b(f1) << 16);
  *(uint*)(ZF + (size_t)node * SEM + ch) = o;
}

extern "C" void kernel_launch(void* const* d_in, const int* in_sizes, int n_in,
                              void* d_out, int out_size, void* d_ws, size_t ws_size,
                              hipStream_t stream)
{
  const float* x_user = (const float*)d_in[0];
  const float* x_llm  = (const float*)d_in[1];
  const int* src0 = (const int*)d_in[2];
  const int* dst0 = (const int*)d_in[3];
  const int* src1 = (const int*)d_in[4];
  const int* dst1 = (const int*)d_in[5];
  const float* Wsrc0 = (const float*)d_in[6];
  const float* Wdst0 = (const float*)d_in[7];
  const float* asrc0 = (const float*)d_in[8];
  const float* adst0 = (const float*)d_in[9];
  const float* bias0 = (const float*)d_in[10];
  const float* Wsrc1 = (const float*)d_in[11];
  const float* Wdst1 = (const float*)d_in[12];
  const float* asrc1 = (const float*)d_in[13];
  const float* adst1 = (const float*)d_in[14];
  const float* bias1 = (const float*)d_in[15];
  const float* sem_W1 = (const float*)d_in[16];
  const float* sem_b1 = (const float*)d_in[17];
  const float* sem_W2 = (const float*)d_in[18];
  const float* out_W  = (const float*)d_in[19];
  const float* out_b  = (const float*)d_in[20];

  char* ws = (char*)d_ws;
  size_t off = 0;
  auto alloc = [&](size_t bytes) -> size_t {
    size_t o = off;
    off += (bytes + 255) & ~(size_t)255;
    return o;
  };

  size_t xbu_off  = alloc((size_t)MP_USER * IN_DIM * 2);   // 76.9 MB (later overlaid by T bf16)
  size_t xbl_off  = alloc((size_t)MP_LLM  * IN_DIM * 2);   // 7.9 MB
  size_t wt0_off  = alloc((size_t)SEM * IN_DIM * 2);
  size_t wt1_off  = alloc((size_t)SEM * IN_DIM * 2);
  size_t wts_off  = alloc((size_t)HID * SEM * 2);
  size_t wto_off  = alloc((size_t)OUT_DIM * SEM * 2);
  size_t hs0_off  = alloc((size_t)MP_LLM  * SEM * 2);      // 5.2 MB
  size_t hs1_off  = alloc((size_t)MP_USER * SEM * 2);      // 51.2 MB (later overlaid by ZF)
  size_t Z_off    = alloc((size_t)MP_2U   * SEM * 2);      // 102.5 MB
  size_t sc_off   = alloc((size_t)2 * NE * 2);             // src ushort, CSR order, 1.6 MB
  size_t as0_off  = alloc((size_t)N_LLM  * 4 * 4);
  size_t as1_off  = alloc((size_t)N_USER * 4 * 4);
  size_t ad_off   = alloc((size_t)2 * N_USER * 4 * 4);
  size_t wfu_off  = alloc((size_t)IN_DIM * 12 * 4);
  size_t wfl_off  = alloc((size_t)IN_DIM * 4 * 4);
  size_t deg_off  = alloc((size_t)2 * N_USER * 4);         // zeroed
  size_t cur_off  = alloc((size_t)2 * N_USER * 4);         // zeroed
  size_t zero_end = off;
  size_t rp_off   = alloc((size_t)(2 * N_USER + 1) * 4);
  size_t bs_off   = alloc((size_t)128 * 4);
  size_t bo_off   = alloc((size_t)128 * 4);

  ushort* xb_u  = (ushort*)(ws + xbu_off);
  ushort* xb_l  = (ushort*)(ws + xbl_off);
  ushort* Wt0   = (ushort*)(ws + wt0_off);
  ushort* Wt1   = (ushort*)(ws + wt1_off);
  ushort* WtS   = (ushort*)(ws + wts_off);
  ushort* WtO   = (ushort*)(ws + wto_off);
  ushort* hs0b  = (ushort*)(ws + hs0_off);
  ushort* hs1b  = (ushort*)(ws + hs1_off);
  ushort* Zsw   = (ushort*)(ws + Z_off);
  ushort* Tbuf  = (ushort*)(ws + xbu_off);  // overlay: xb dead after hs GEMMs (bf16 T)
  ushort* ZF    = (ushort*)(ws + hs1_off);  // overlay: hs1 dead after agg
  ushort* scsr  = (ushort*)(ws + sc_off);
  float*  a_s0  = (float*)(ws + as0_off);
  float*  a_s1  = (float*)(ws + as1_off);
  float*  a_d   = (float*)(ws + ad_off);
  float*  wfu   = (float*)(ws + wfu_off);
  float*  wfl   = (float*)(ws + wfl_off);
  int*    deg   = (int*)(ws + deg_off);     // concatenated [2*N_USER]
  int*    cur   = (int*)(ws + cur_off);
  int*    rp    = (int*)(ws + rp_off);      // [2*N_USER+1]
  int*    bsum  = (int*)(ws + bs_off);
  int*    boff  = (int*)(ws + bo_off);

  hipMemsetAsync(ws + deg_off, 0, zero_end - deg_off, stream);

  // folds + fused cast/projection passes (x read once each)
  fold_kernel<<<cdiv(IN_DIM * 16, 256), 256, 0, stream>>>(
      Wdst0, adst0, Wdst1, adst1, Wsrc1, asrc1, Wsrc0, asrc0, wfu, wfl);
  proj_cast_kernel<12><<<cdiv(N_USER, 4), 256, 0, stream>>>(
      x_user, wfu, xb_u, a_d, a_d + (size_t)N_USER * 4, a_s1, N_USER);
  proj_cast_kernel<4><<<cdiv(N_LLM, 4), 256, 0, stream>>>(
      x_llm, wfl, xb_l, a_s0, nullptr, nullptr, N_LLM);

  // weight transposes
  tc_kernel<<<cdiv(IN_DIM * SEM, 256), 256, 0, stream>>>(Wsrc0, Wt0, IN_DIM, SEM);
  tc_kernel<<<cdiv(IN_DIM * SEM, 256), 256, 0, stream>>>(Wsrc1, Wt1, IN_DIM, SEM);
  tc_kernel<<<cdiv(SEM * HID, 256), 256, 0, stream>>>(sem_W1, WtS, SEM, HID);
  tc_kernel<<<cdiv(SEM * OUT_DIM, 256), 256, 0, stream>>>(out_W, WtO, SEM, OUT_DIM);

  // CSR build over unified node space
  const int NTOT = 2 * N_USER;
  const int NB = cdiv(NTOT, 1024);   // 98
  edge1_kernel<<<cdiv(2 * NE, 256), 256, 0, stream>>>(dst0, dst1, deg);
  scan1<<<NB, 256, 0, stream>>>(deg, bsum, NTOT);
  scan2<<<1, 128, 0, stream>>>(bsum, boff, NB, rp + NTOT, 2 * NE);
  scan3<<<NB, 256, 0, stream>>>(deg, boff, rp, NTOT);
  scatter_kernel<<<cdiv(2 * NE, 256), 256, 0, stream>>>(src0, dst0, src1, dst1, rp, cur, scsr);

  // hs GEMMs (bf16 out)
  {
    dim3 g(SEM / 128, MP_LLM / 128);
    gemm_bf16<0><<<g, 256, 0, stream>>>(xb_l, Wt0, hs0b, nullptr, MP_LLM, SEM, IN_DIM);
  }
  {
    dim3 g(SEM / 128, MP_USER / 128);
    gemm_bf16<0><<<g, 256, 0, stream>>>(xb_u, Wt1, hs1b, nullptr, MP_USER, SEM, IN_DIM);
  }

  // unified aggregation (wave per node) -> bf16 Z
  agg_kernel<<<NTOT, 64, 0, stream>>>(hs0b, hs1b, scsr, a_s0, a_s1, a_d, rp,
                                      bias0, bias1, Zsw);

  // T = Z @ sem_W1 (bf16 out, overlays dead xb_u)
  {
    dim3 g(HID / 128, MP_2U / 128);
    gemm_bf16<0><<<g, 256, 0, stream>>>(Zsw, WtS, Tbuf, nullptr, MP_2U, HID, SEM);
  }

  // semantic combine -> bf16 ZF (overlays dead hs1b)
  combine_kernel<<<N_USER, 256, 0, stream>>>(Tbuf, sem_b1, sem_W2, Zsw, ZF);

  // out = ZF @ out_W + out_b (fp32, guarded)
  {
    dim3 g(OUT_DIM / 128, MP_USER / 128);
    gemm_bf16<1><<<g, 256, 0, stream>>>(ZF, WtO, (float*)d_out, out_b, N_USER, OUT_DIM, SEM);
  }
}

// Round 6
// 572.848 us; speedup vs baseline: 3.5731x; 1.0796x over previous
//
#include <hip/hip_runtime.h>
#include <hip/hip_bf16.h>
#include <math.h>

constexpr int IN_DIM  = 768;
constexpr int HID     = 128;
constexpr int OUT_DIM = 256;
constexpr int SEM     = 512;     // HID*HEADS
constexpr int N_USER  = 50000;
constexpr int N_LLM   = 5000;
constexpr int NE      = 400000;

constexpr int MP_USER = 50048;   // 391*128
constexpr int MP_LLM  = 5120;    // 40*128
constexpr int MP_2U   = 100096;  // 782*128

typedef unsigned int uint;
typedef unsigned short ushort;
typedef __attribute__((ext_vector_type(8))) short bf16x8;
typedef __attribute__((ext_vector_type(4))) float f32x4;

static inline int cdiv(int a, int b) { return (a + b - 1) / b; }

__device__ __forceinline__ ushort f2b(float f) {
  uint u = __float_as_uint(f);
  u += 0x7FFFu + ((u >> 16) & 1u);       // RNE
  return (ushort)(u >> 16);
}
__device__ __forceinline__ float b2f(uint bits16) {
  return __uint_as_float(bits16 << 16);
}

#define GLOAD_LDS16(g, l) __builtin_amdgcn_global_load_lds( \
    (const __attribute__((address_space(1))) void*)(g), \
    (__attribute__((address_space(3))) void*)(l), 16, 0, 0)

// ---------------- bf16 MFMA GEMM: C[M,N] = A[Mpad,K] @ Bt[N,K]^T -----------
// 128x128 tile, BK=64, 256 threads (4 waves, 2x2 of 64x64 each).
// STORE_MODE 0: bf16 store, no guard (pad rows land in ws). 1: f32 +bias, row<Mreal guard.
template<int STORE_MODE>
__global__ __launch_bounds__(256) void gemm_bf16(
    const ushort* __restrict__ A, const ushort* __restrict__ Bt,
    void* __restrict__ Cout, const float* __restrict__ bias,
    int Mreal, int N, int K)
{
  __shared__ ushort As[128][64];   // 16 KB
  __shared__ ushort Bs[128][64];   // 16 KB
  const int t = threadIdx.x;
  const int wid = t >> 6, lane = t & 63;

  // bijective XCD-aware swizzle (m204)
  const int nwg  = gridDim.x * gridDim.y;
  const int orig = blockIdx.y * gridDim.x + blockIdx.x;
  const int q = nwg >> 3, r = nwg & 7;
  const int xcd = orig & 7, idx = orig >> 3;
  const int swz = (xcd < r ? xcd * (q + 1) : r * (q + 1) + (xcd - r) * q) + idx;
  const int bxi = swz % gridDim.x, byi = swz / gridDim.x;

  const int bm = byi * 128, bn = bxi * 128;
  const int lr = lane & 15, kg = lane >> 4;
  const int mbase = (wid >> 1) * 64, nbase = (wid & 1) * 64;
  const int grow = lane >> 3;          // 0..7 within chunk
  const int gcol = (lane & 7) * 8;     // element col, 16B granules

  f32x4 acc[4][4] = {};

  for (int k0 = 0; k0 < K; k0 += 64) {
#pragma unroll
    for (int c = 0; c < 4; ++c) {
      int ch = wid * 4 + c;            // 0..15, rows ch*8..ch*8+7
      const ushort* ga = A  + (size_t)(bm + ch * 8 + grow) * K + k0 + gcol;
      const ushort* gb = Bt + (size_t)(bn + ch * 8 + grow) * K + k0 + gcol;
      GLOAD_LDS16(ga, &As[ch * 8][0]);
      GLOAD_LDS16(gb, &Bs[ch * 8][0]);
    }
    asm volatile("s_waitcnt vmcnt(0)" ::: "memory");
    __syncthreads();
#pragma unroll
    for (int kb = 0; kb < 2; ++kb) {
      bf16x8 av[4], bv[4];
#pragma unroll
      for (int m = 0; m < 4; ++m)
        av[m] = *(const bf16x8*)&As[mbase + m * 16 + lr][kb * 32 + kg * 8];
#pragma unroll
      for (int n = 0; n < 4; ++n)
        bv[n] = *(const bf16x8*)&Bs[nbase + n * 16 + lr][kb * 32 + kg * 8];
#pragma unroll
      for (int m = 0; m < 4; ++m)
#pragma unroll
        for (int n = 0; n < 4; ++n)
          acc[m][n] = __builtin_amdgcn_mfma_f32_16x16x32_bf16(av[m], bv[n], acc[m][n], 0, 0, 0);
    }
    __syncthreads();
  }

#pragma unroll
  for (int m = 0; m < 4; ++m) {
#pragma unroll
    for (int j = 0; j < 4; ++j) {
      int row = bm + mbase + m * 16 + kg * 4 + j;
      if (STORE_MODE == 1 && row >= Mreal) continue;
#pragma unroll
      for (int n = 0; n < 4; ++n) {
        int col = bn + nbase + n * 16 + lr;
        float v = acc[m][n][j];
        if (STORE_MODE == 1) {
          if (bias) v += bias[col];
          ((float*)Cout)[(size_t)row * N + col] = v;
        } else {
          ((ushort*)Cout)[(size_t)row * N + col] = f2b(v);
        }
      }
    }
  }
}

// -------- transpose-cast: W fp32 [K][Nw] -> Bt bf16 [Nw][K] ----------------
__global__ __launch_bounds__(256) void tc_kernel(
    const float* __restrict__ W, ushort* __restrict__ Bt, int K, int Nw)
{
  int i = blockIdx.x * 256 + threadIdx.x;
  if (i >= K * Nw) return;
  int n = i / K, k = i - n * K;
  Bt[i] = f2b(W[(size_t)k * Nw + n]);
}

// ------------- fold W (768x512) against att (4x128), TRANSPOSED out --------
// wfu_T[12][768]: {Wdst0·adst0, Wdst1·adst1, Wsrc1·asrc1}
// wfl_T[4][768]:  {Wsrc0·asrc0}
__global__ void fold_kernel(const float* __restrict__ Wdst0, const float* __restrict__ adst0,
                            const float* __restrict__ Wdst1, const float* __restrict__ adst1,
                            const float* __restrict__ Wsrc1, const float* __restrict__ asrc1,
                            const float* __restrict__ Wsrc0, const float* __restrict__ asrc0,
                            float* __restrict__ wfu_T, float* __restrict__ wfl_T)
{
  int idx = blockIdx.x * 256 + threadIdx.x;   // 768*16
  if (idx >= IN_DIM * 16) return;
  int k = idx >> 4, hh = idx & 15;
  const float* W;
  const float* att;
  if (hh < 4)       { W = Wdst0; att = adst0; }
  else if (hh < 8)  { W = Wdst1; att = adst1; }
  else if (hh < 12) { W = Wsrc1; att = asrc1; }
  else              { W = Wsrc0; att = asrc0; }
  int h = hh & 3;
  float s = 0.f;
#pragma unroll 4
  for (int c = 0; c < HID; ++c)
    s += W[(size_t)k * SEM + h * HID + c] * att[h * HID + c];
  if (hh < 12) wfu_T[hh * IN_DIM + k] = s;
  else         wfl_T[h * IN_DIM + k] = s;
}

// -------- fused cast(x->bf16) + folded logit projections -------------------
// Block = 256 threads, 16 nodes (4 waves x 4 nodes). wfoldT staged in LDS.
// NH=12 (user): outA=a_d[p0], outB=a_d[p1], outC=a_s1. NH=4 (llm): outA=a_s0.
template<int NH>
__global__ __launch_bounds__(256) void proj_cast_kernel(
    const float* __restrict__ x, const float* __restrict__ wfoldT,
    ushort* __restrict__ xb, float* __restrict__ outA,
    float* __restrict__ outB, float* __restrict__ outC, int n)
{
  __shared__ float wT[NH * IN_DIM];   // 36 KB (NH=12) / 12 KB (NH=4)
  for (int i = threadIdx.x; i < NH * IN_DIM; i += 256)
    wT[i] = wfoldT[i];
  __syncthreads();
  int wid = threadIdx.x >> 6, lane = threadIdx.x & 63;
  for (int sub = 0; sub < 4; ++sub) {
    int node = blockIdx.x * 16 + wid * 4 + sub;
    if (node >= n) return;
    float acc[NH];
#pragma unroll
    for (int hh = 0; hh < NH; ++hh) acc[hh] = 0.f;
    const float* xr = x + (size_t)node * IN_DIM;
    uint* xbo = (uint*)(xb + (size_t)node * IN_DIM);
#pragma unroll
    for (int i = 0; i < IN_DIM / 128; ++i) {   // 6 iters, float2 per lane
      int p = i * 64 + lane;                   // pair index 0..383
      float2 xv = *(const float2*)(xr + 2 * p);
#pragma unroll
      for (int hh = 0; hh < NH; ++hh) {
        float2 wv = *(const float2*)&wT[hh * IN_DIM + 2 * p];
        acc[hh] += xv.x * wv.x + xv.y * wv.y;
      }
      xbo[p] = (uint)f2b(xv.x) | ((uint)f2b(xv.y) << 16);
    }
#pragma unroll
    for (int off2 = 32; off2 > 0; off2 >>= 1) {
#pragma unroll
      for (int hh = 0; hh < NH; ++hh) acc[hh] += __shfl_down(acc[hh], off2);
    }
    if (lane == 0) {
#pragma unroll
      for (int h = 0; h < 4; ++h) outA[(size_t)node * 4 + h] = acc[h];
      if (NH == 12) {
#pragma unroll
        for (int h = 0; h < 4; ++h) outB[(size_t)node * 4 + h] = acc[4 + h];
#pragma unroll
        for (int h = 0; h < 4; ++h) outC[(size_t)node * 4 + h] = acc[8 + h];
      }
    }
  }
}

// -------- pass 1: degree histogram over unified node space -----------------
__global__ void edge1_kernel(const int* __restrict__ dst0, const int* __restrict__ dst1,
                             int* __restrict__ deg)
{
  int e = blockIdx.x * 256 + threadIdx.x;
  if (e >= 2 * NE) return;
  int d = (e < NE) ? dst0[e] : (dst1[e - NE] + N_USER);
  atomicAdd(&deg[d], 1);
}

// -------- pass 2: scatter src (ushort) into CSR slots ----------------------
__global__ void scatter_kernel(const int* __restrict__ src0, const int* __restrict__ dst0,
                               const int* __restrict__ src1, const int* __restrict__ dst1,
                               const int* __restrict__ rp, int* __restrict__ cur,
                               ushort* __restrict__ scsr)
{
  int e = blockIdx.x * 256 + threadIdx.x;
  if (e >= 2 * NE) return;
  bool p1 = (e >= NE);
  int ee = p1 ? e - NE : e;
  int s = p1 ? src1[ee] : src0[ee];
  int d = p1 ? (dst1[ee] + N_USER) : dst0[ee];
  int pos = rp[d] + atomicAdd(&cur[d], 1);
  scsr[pos] = (ushort)s;
}

// -------- 3-phase scan over deg[0..n) --------------------------------------
__global__ __launch_bounds__(256) void scan1(const int* __restrict__ deg,
                                             int* __restrict__ bsum, int n)
{
  __shared__ int sm[256];
  int b = blockIdx.x, t = threadIdx.x;
  int base = b * 1024 + t * 4;
  int s = 0;
#pragma unroll
  for (int i = 0; i < 4; ++i) if (base + i < n) s += deg[base + i];
  sm[t] = s;
  __syncthreads();
  for (int off = 128; off > 0; off >>= 1) {
    if (t < off) sm[t] += sm[t + off];
    __syncthreads();
  }
  if (t == 0) bsum[b] = sm[0];
}

__global__ __launch_bounds__(128) void scan2(const int* __restrict__ bsum,
                                             int* __restrict__ boff, int nb,
                                             int* __restrict__ rp_tail, int tailval)
{
  __shared__ int sm[128];
  int t = threadIdx.x;
  int v = (t < nb) ? bsum[t] : 0;
  sm[t] = v;
  __syncthreads();
  for (int off = 1; off < 128; off <<= 1) {
    int x = (t >= off) ? sm[t - off] : 0;
    __syncthreads();
    sm[t] += x;
    __syncthreads();
  }
  if (t < nb) boff[t] = sm[t] - v;
  if (t == 0) *rp_tail = tailval;
}

__global__ __launch_bounds__(256) void scan3(const int* __restrict__ deg,
                                             const int* __restrict__ boff,
                                             int* __restrict__ rp, int n)
{
  __shared__ int sm[256];
  int b = blockIdx.x, t = threadIdx.x;
  int base = b * 1024 + t * 4;
  int v[4];
#pragma unroll
  for (int i = 0; i < 4; ++i) v[i] = (base + i < n) ? deg[base + i] : 0;
  int tsum = v[0] + v[1] + v[2] + v[3];
  sm[t] = tsum;
  __syncthreads();
  for (int off = 1; off < 256; off <<= 1) {
    int x = (t >= off) ? sm[t - off] : 0;
    __syncthreads();
    sm[t] += x;
    __syncthreads();
  }
  int run = sm[t] - tsum + boff[b];
#pragma unroll
  for (int i = 0; i < 4; ++i) {
    if (base + i < n) rp[base + i] = run;
    run += v[i];
  }
}

// -------- unified aggregation: ONE WAVE per dst node -----------------------
// Lane owns 8 channels (16B). Per edge: one dwordx4 gather (wave covers the
// full 1KB hs row) + 8 unpack-fma. ev computed on the fly during staging.
__global__ __launch_bounds__(64) void agg_kernel(
    const ushort* __restrict__ hs0, const ushort* __restrict__ hs1,
    const ushort* __restrict__ srcs,
    const float* __restrict__ a_s0, const float* __restrict__ a_s1,
    const float* __restrict__ a_d, const int* __restrict__ rp,
    const float* __restrict__ bias0, const float* __restrict__ bias1,
    ushort* __restrict__ Zout)
{
  __shared__ ushort s_src[64];
  __shared__ float  s_ev[64][4];
  int node = blockIdx.x, lane = threadIdx.x;
  bool p1 = (node >= N_USER);
  const ushort* hs   = p1 ? hs1 : hs0;
  const float*  as   = p1 ? a_s1 : a_s0;
  const float*  bias = p1 ? bias1 : bias0;
  float4 ad4 = *(const float4*)(a_d + (size_t)node * 4);
  int h  = lane >> 4;          // head for this lane's channels
  int cb = lane * 8;           // channel base
  float acc[8] = {};
  float dsum = 0.f;
  int jb = rp[node], je = rp[node + 1];
  for (int j0 = jb; j0 < je; j0 += 64) {
    int n = min(64, je - j0);
    __syncthreads();
    if (lane < n) {
      int s = srcs[j0 + lane];
      s_src[lane] = (ushort)s;
      float4 as4 = *(const float4*)(as + (size_t)s * 4);
      float v0 = as4.x + ad4.x, v1 = as4.y + ad4.y;
      float v2 = as4.z + ad4.z, v3 = as4.w + ad4.w;
      v0 = (v0 > 0.f) ? v0 : 0.2f * v0;   // leaky_relu(0.2)
      v1 = (v1 > 0.f) ? v1 : 0.2f * v1;
      v2 = (v2 > 0.f) ? v2 : 0.2f * v2;
      v3 = (v3 > 0.f) ? v3 : 0.2f * v3;
      s_ev[lane][0] = expf(v0);
      s_ev[lane][1] = expf(v1);
      s_ev[lane][2] = expf(v2);
      s_ev[lane][3] = expf(v3);
    }
    __syncthreads();
#pragma unroll 2
    for (int j = 0; j < n; ++j) {
      int s = s_src[j];
      float e = s_ev[j][h];
      uint4 pv = *(const uint4*)(hs + (size_t)s * SEM + cb);
      acc[0] += b2f(pv.x & 0xffffu) * e;  acc[1] += b2f(pv.x >> 16) * e;
      acc[2] += b2f(pv.y & 0xffffu) * e;  acc[3] += b2f(pv.y >> 16) * e;
      acc[4] += b2f(pv.z & 0xffffu) * e;  acc[5] += b2f(pv.z >> 16) * e;
      acc[6] += b2f(pv.w & 0xffffu) * e;  acc[7] += b2f(pv.w >> 16) * e;
      dsum += e;
    }
  }
  float inv = 1.f / (dsum + 1e-16f);
  uint4 o;
  uint* op = (uint*)&o;
#pragma unroll
  for (int i = 0; i < 4; ++i) {
    float z0 = acc[2 * i]     * inv + bias[cb + 2 * i];
    float z1 = acc[2 * i + 1] * inv + bias[cb + 2 * i + 1];
    z0 = (z0 > 0.f) ? z0 : expm1f(z0);   // ELU
    z1 = (z1 > 0.f) ? z1 : expm1f(z1);
    op[i] = (uint)f2b(z0) | ((uint)f2b(z1) << 16);
  }
  *(uint4*)(Zout + (size_t)node * SEM + cb) = o;
}

// -------- semantic attention combine (T in bf16): ZF = b0*Z0 + b1*Z1 -------
__global__ __launch_bounds__(256) void combine_kernel(
    const ushort* __restrict__ T, const float* __restrict__ b1,
    const float* __restrict__ W2, const ushort* __restrict__ Z,
    ushort* __restrict__ ZF)
{
  __shared__ float red[256];
  __shared__ float beta[2];
  int node = blockIdx.x, t = threadIdx.x;
  int p = t >> 7, j = t & 127;
  float tv = b2f(T[(size_t)(p * N_USER + node) * HID + j]);
  float val = tanhf(tv + b1[j]) * W2[j];
  red[t] = val;
  __syncthreads();
  for (int off = 64; off > 0; off >>= 1) {
    if (j < off) red[t] += red[t + off];
    __syncthreads();
  }
  if (t == 0) {
    float w0 = red[0], w1 = red[128];
    float mx = fmaxf(w0, w1);
    float e0 = expf(w0 - mx), e1 = expf(w1 - mx);
    float s = e0 + e1;
    beta[0] = e0 / s; beta[1] = e1 / s;
  }
  __syncthreads();
  float b0v = beta[0], b1v = beta[1];
  int ch = 2 * t;
  uint z0 = *(const uint*)(Z + (size_t)node * SEM + ch);
  uint z1 = *(const uint*)(Z + (size_t)(N_USER + node) * SEM + ch);
  float f0 = b0v * b2f(z0 & 0xffffu) + b1v * b2f(z1 & 0xffffu);
  float f1 = b0v * b2f(z0 >> 16)     + b1v * b2f(z1 >> 16);
  uint o = (uint)f2b(f0) | ((uint)f2b(f1) << 16);
  *(uint*)(ZF + (size_t)node * SEM + ch) = o;
}

extern "C" void kernel_launch(void* const* d_in, const int* in_sizes, int n_in,
                              void* d_out, int out_size, void* d_ws, size_t ws_size,
                              hipStream_t stream)
{
  const float* x_user = (const float*)d_in[0];
  const float* x_llm  = (const float*)d_in[1];
  const int* src0 = (const int*)d_in[2];
  const int* dst0 = (const int*)d_in[3];
  const int* src1 = (const int*)d_in[4];
  const int* dst1 = (const int*)d_in[5];
  const float* Wsrc0 = (const float*)d_in[6];
  const float* Wdst0 = (const float*)d_in[7];
  const float* asrc0 = (const float*)d_in[8];
  const float* adst0 = (const float*)d_in[9];
  const float* bias0 = (const float*)d_in[10];
  const float* Wsrc1 = (const float*)d_in[11];
  const float* Wdst1 = (const float*)d_in[12];
  const float* asrc1 = (const float*)d_in[13];
  const float* adst1 = (const float*)d_in[14];
  const float* bias1 = (const float*)d_in[15];
  const float* sem_W1 = (const float*)d_in[16];
  const float* sem_b1 = (const float*)d_in[17];
  const float* sem_W2 = (const float*)d_in[18];
  const float* out_W  = (const float*)d_in[19];
  const float* out_b  = (const float*)d_in[20];

  char* ws = (char*)d_ws;
  size_t off = 0;
  auto alloc = [&](size_t bytes) -> size_t {
    size_t o = off;
    off += (bytes + 255) & ~(size_t)255;
    return o;
  };

  size_t xbu_off  = alloc((size_t)MP_USER * IN_DIM * 2);   // 76.9 MB (later overlaid by T bf16)
  size_t xbl_off  = alloc((size_t)MP_LLM  * IN_DIM * 2);   // 7.9 MB
  size_t wt0_off  = alloc((size_t)SEM * IN_DIM * 2);
  size_t wt1_off  = alloc((size_t)SEM * IN_DIM * 2);
  size_t wts_off  = alloc((size_t)HID * SEM * 2);
  size_t wto_off  = alloc((size_t)OUT_DIM * SEM * 2);
  size_t hs0_off  = alloc((size_t)MP_LLM  * SEM * 2);      // 5.2 MB
  size_t hs1_off  = alloc((size_t)MP_USER * SEM * 2);      // 51.2 MB (later overlaid by ZF)
  size_t Z_off    = alloc((size_t)MP_2U   * SEM * 2);      // 102.5 MB
  size_t sc_off   = alloc((size_t)2 * NE * 2);             // src ushort, CSR order, 1.6 MB
  size_t as0_off  = alloc((size_t)N_LLM  * 4 * 4);
  size_t as1_off  = alloc((size_t)N_USER * 4 * 4);
  size_t ad_off   = alloc((size_t)2 * N_USER * 4 * 4);
  size_t wfu_off  = alloc((size_t)IN_DIM * 12 * 4);
  size_t wfl_off  = alloc((size_t)IN_DIM * 4 * 4);
  size_t deg_off  = alloc((size_t)2 * N_USER * 4);         // zeroed
  size_t cur_off  = alloc((size_t)2 * N_USER * 4);         // zeroed
  size_t zero_end = off;
  size_t rp_off   = alloc((size_t)(2 * N_USER + 1) * 4);
  size_t bs_off   = alloc((size_t)128 * 4);
  size_t bo_off   = alloc((size_t)128 * 4);

  ushort* xb_u  = (ushort*)(ws + xbu_off);
  ushort* xb_l  = (ushort*)(ws + xbl_off);
  ushort* Wt0   = (ushort*)(ws + wt0_off);
  ushort* Wt1   = (ushort*)(ws + wt1_off);
  ushort* WtS   = (ushort*)(ws + wts_off);
  ushort* WtO   = (ushort*)(ws + wto_off);
  ushort* hs0b  = (ushort*)(ws + hs0_off);
  ushort* hs1b  = (ushort*)(ws + hs1_off);
  ushort* Zsw   = (ushort*)(ws + Z_off);
  ushort* Tbuf  = (ushort*)(ws + xbu_off);  // overlay: xb dead after hs GEMMs (bf16 T)
  ushort* ZF    = (ushort*)(ws + hs1_off);  // overlay: hs1 dead after agg
  ushort* scsr  = (ushort*)(ws + sc_off);
  float*  a_s0  = (float*)(ws + as0_off);
  float*  a_s1  = (float*)(ws + as1_off);
  float*  a_d   = (float*)(ws + ad_off);
  float*  wfu   = (float*)(ws + wfu_off);
  float*  wfl   = (float*)(ws + wfl_off);
  int*    deg   = (int*)(ws + deg_off);     // concatenated [2*N_USER]
  int*    cur   = (int*)(ws + cur_off);
  int*    rp    = (int*)(ws + rp_off);      // [2*N_USER+1]
  int*    bsum  = (int*)(ws + bs_off);
  int*    boff  = (int*)(ws + bo_off);

  hipMemsetAsync(ws + deg_off, 0, zero_end - deg_off, stream);

  // folds (transposed out) + fused cast/projection passes (x read once each)
  fold_kernel<<<cdiv(IN_DIM * 16, 256), 256, 0, stream>>>(
      Wdst0, adst0, Wdst1, adst1, Wsrc1, asrc1, Wsrc0, asrc0, wfu, wfl);
  proj_cast_kernel<12><<<cdiv(N_USER, 16), 256, 0, stream>>>(
      x_user, wfu, xb_u, a_d, a_d + (size_t)N_USER * 4, a_s1, N_USER);
  proj_cast_kernel<4><<<cdiv(N_LLM, 16), 256, 0, stream>>>(
      x_llm, wfl, xb_l, a_s0, nullptr, nullptr, N_LLM);

  // weight transposes
  tc_kernel<<<cdiv(IN_DIM * SEM, 256), 256, 0, stream>>>(Wsrc0, Wt0, IN_DIM, SEM);
  tc_kernel<<<cdiv(IN_DIM * SEM, 256), 256, 0, stream>>>(Wsrc1, Wt1, IN_DIM, SEM);
  tc_kernel<<<cdiv(SEM * HID, 256), 256, 0, stream>>>(sem_W1, WtS, SEM, HID);
  tc_kernel<<<cdiv(SEM * OUT_DIM, 256), 256, 0, stream>>>(out_W, WtO, SEM, OUT_DIM);

  // CSR build over unified node space
  const int NTOT = 2 * N_USER;
  const int NB = cdiv(NTOT, 1024);   // 98
  edge1_kernel<<<cdiv(2 * NE, 256), 256, 0, stream>>>(dst0, dst1, deg);
  scan1<<<NB, 256, 0, stream>>>(deg, bsum, NTOT);
  scan2<<<1, 128, 0, stream>>>(bsum, boff, NB, rp + NTOT, 2 * NE);
  scan3<<<NB, 256, 0, stream>>>(deg, boff, rp, NTOT);
  scatter_kernel<<<cdiv(2 * NE, 256), 256, 0, stream>>>(src0, dst0, src1, dst1, rp, cur, scsr);

  // hs GEMMs (bf16 out)
  {
    dim3 g(SEM / 128, MP_LLM / 128);
    gemm_bf16<0><<<g, 256, 0, stream>>>(xb_l, Wt0, hs0b, nullptr, MP_LLM, SEM, IN_DIM);
  }
  {
    dim3 g(SEM / 128, MP_USER / 128);
    gemm_bf16<0><<<g, 256, 0, stream>>>(xb_u, Wt1, hs1b, nullptr, MP_USER, SEM, IN_DIM);
  }

  // unified aggregation (wave per node) -> bf16 Z
  agg_kernel<<<NTOT, 64, 0, stream>>>(hs0b, hs1b, scsr, a_s0, a_s1, a_d, rp,
                                      bias0, bias1, Zsw);

  // T = Z @ sem_W1 (bf16 out, overlays dead xb_u)
  {
    dim3 g(HID / 128, MP_2U / 128);
    gemm_bf16<0><<<g, 256, 0, stream>>>(Zsw, WtS, Tbuf, nullptr, MP_2U, HID, SEM);
  }

  // semantic combine -> bf16 ZF (overlays dead hs1b)
  combine_kernel<<<N_USER, 256, 0, stream>>>(Tbuf, sem_b1, sem_W2, Zsw, ZF);

  // out = ZF @ out_W + out_b (fp32, guarded)
  {
    dim3 g(OUT_DIM / 128, MP_USER / 128);
    gemm_bf16<1><<<g, 256, 0, stream>>>(ZF, WtO, (float*)d_out, out_b, N_USER, OUT_DIM, SEM);
  }
}

// Round 7
// 487.917 us; speedup vs baseline: 4.1951x; 1.1741x over previous
//
#include <hip/hip_runtime.h>
#include <hip/hip_bf16.h>
#include <math.h>

constexpr int IN_DIM  = 768;
constexpr int HID     = 128;
constexpr int OUT_DIM = 256;
constexpr int SEM     = 512;     // HID*HEADS
constexpr int N_USER  = 50000;
constexpr int N_LLM   = 5000;
constexpr int NE      = 400000;

constexpr int MP_USER = 50048;   // 391*128
constexpr int MP_LLM  = 5120;    // 40*128
constexpr int MP_2U   = 100096;  // 782*128

typedef unsigned int uint;
typedef unsigned short ushort;
typedef __attribute__((ext_vector_type(8))) short bf16x8;
typedef __attribute__((ext_vector_type(4))) float f32x4;

static inline int cdiv(int a, int b) { return (a + b - 1) / b; }

__device__ __forceinline__ ushort f2b(float f) {
  uint u = __float_as_uint(f);
  u += 0x7FFFu + ((u >> 16) & 1u);       // RNE
  return (ushort)(u >> 16);
}
__device__ __forceinline__ float b2f(uint bits16) {
  return __uint_as_float(bits16 << 16);
}

#define GLOAD_LDS16(g, l) __builtin_amdgcn_global_load_lds( \
    (const __attribute__((address_space(1))) void*)(g), \
    (__attribute__((address_space(3))) void*)(l), 16, 0, 0)

// ---------------- bf16 MFMA GEMM: C[M,N] = A[Mpad,K] @ Bt[N,K]^T -----------
// 128x128 tile, BK=64, 256 threads (4 waves, 2x2 of 64x64 each).
// MODE 0: bf16 store (stride N), no guard.
// MODE 1: f32 +bias store (stride N), row<Mreal guard.
// MODE 2: split — col-tiles 0..gx-2 store bf16 (stride N-128); last col-tile
//         stores cols 0..15 as f32 into logit[row][16]. (hs GEMM + logits)
// MODE 3: A synthesized as beta.x*Z[row] + beta.y*Z[row+N_USER] (reg-staged,
//         ds_write); f32 +bias store, guarded. (fused combine + out-GEMM)
template<int MODE>
__global__ __launch_bounds__(256) void gemm_bf16(
    const ushort* __restrict__ A, const ushort* __restrict__ Bt,
    void* __restrict__ Cout, const float* __restrict__ bias,
    const float2* __restrict__ beta, float* __restrict__ logit,
    int Mreal, int N, int K)
{
  __shared__ ushort As[128][64];   // 16 KB
  __shared__ ushort Bs[128][64];   // 16 KB
  const int t = threadIdx.x;
  const int wid = t >> 6, lane = t & 63;

  // bijective XCD-aware swizzle (m204)
  const int nwg  = gridDim.x * gridDim.y;
  const int orig = blockIdx.y * gridDim.x + blockIdx.x;
  const int q = nwg >> 3, r = nwg & 7;
  const int xcd = orig & 7, idx = orig >> 3;
  const int swz = (xcd < r ? xcd * (q + 1) : r * (q + 1) + (xcd - r) * q) + idx;
  const int bxi = swz % gridDim.x, byi = swz / gridDim.x;

  const int bm = byi * 128, bn = bxi * 128;
  const int lr = lane & 15, kg = lane >> 4;
  const int mbase = (wid >> 1) * 64, nbase = (wid & 1) * 64;
  const int grow = lane >> 3;          // 0..7 within chunk
  const int gcol = (lane & 7) * 8;     // element col, 16B granules

  f32x4 acc[4][4] = {};

  for (int k0 = 0; k0 < K; k0 += 64) {
#pragma unroll
    for (int c = 0; c < 4; ++c) {
      int ch = wid * 4 + c;            // 0..15, rows ch*8..ch*8+7
      const ushort* gb = Bt + (size_t)(bn + ch * 8 + grow) * K + k0 + gcol;
      GLOAD_LDS16(gb, &Bs[ch * 8][0]);
      if (MODE != 3) {
        const ushort* ga = A + (size_t)(bm + ch * 8 + grow) * K + k0 + gcol;
        GLOAD_LDS16(ga, &As[ch * 8][0]);
      }
    }
    if (MODE == 3) {
#pragma unroll
      for (int c = 0; c < 4; ++c) {
        int ch = wid * 4 + c;
        int rl = ch * 8 + grow;        // 0..127
        int row = bm + rl;
        const ushort* z0p = A + (size_t)row * SEM + k0 + gcol;
        const ushort* z1p = A + (size_t)(N_USER + row) * SEM + k0 + gcol;
        float2 bb = beta[row];
        uint4 a0 = *(const uint4*)z0p;
        uint4 a1 = *(const uint4*)z1p;
        uint rpk[4];
#pragma unroll
        for (int qq = 0; qq < 4; ++qq) {
          uint x0 = ((const uint*)&a0)[qq], x1 = ((const uint*)&a1)[qq];
          float lo = bb.x * b2f(x0 & 0xffffu) + bb.y * b2f(x1 & 0xffffu);
          float hi = bb.x * b2f(x0 >> 16)     + bb.y * b2f(x1 >> 16);
          rpk[qq] = (uint)f2b(lo) | ((uint)f2b(hi) << 16);
        }
        *(uint4*)&As[rl][gcol] = make_uint4(rpk[0], rpk[1], rpk[2], rpk[3]);
      }
    }
    asm volatile("s_waitcnt vmcnt(0)" ::: "memory");
    __syncthreads();
#pragma unroll
    for (int kb = 0; kb < 2; ++kb) {
      bf16x8 av[4], bv[4];
#pragma unroll
      for (int m = 0; m < 4; ++m)
        av[m] = *(const bf16x8*)&As[mbase + m * 16 + lr][kb * 32 + kg * 8];
#pragma unroll
      for (int n = 0; n < 4; ++n)
        bv[n] = *(const bf16x8*)&Bs[nbase + n * 16 + lr][kb * 32 + kg * 8];
#pragma unroll
      for (int m = 0; m < 4; ++m)
#pragma unroll
        for (int n = 0; n < 4; ++n)
          acc[m][n] = __builtin_amdgcn_mfma_f32_16x16x32_bf16(av[m], bv[n], acc[m][n], 0, 0, 0);
    }
    __syncthreads();
  }

  if (MODE == 2 && bxi == (int)gridDim.x - 1) {
    // logit tile: only cols 0..15 meaningful (B rows 524.. are zero)
    if (nbase == 0) {
#pragma unroll
      for (int m = 0; m < 4; ++m)
#pragma unroll
        for (int j = 0; j < 4; ++j) {
          int row = bm + mbase + m * 16 + kg * 4 + j;
          logit[(size_t)row * 16 + lr] = acc[m][0][j];
        }
    }
    return;
  }

  const int cstride = (MODE == 2) ? (N - 128) : N;
#pragma unroll
  for (int m = 0; m < 4; ++m) {
#pragma unroll
    for (int j = 0; j < 4; ++j) {
      int row = bm + mbase + m * 16 + kg * 4 + j;
      if ((MODE == 1 || MODE == 3) && row >= Mreal) continue;
#pragma unroll
      for (int n = 0; n < 4; ++n) {
        int col = bn + nbase + n * 16 + lr;
        float v = acc[m][n][j];
        if (MODE == 1 || MODE == 3) {
          if (bias) v += bias[col];
          ((float*)Cout)[(size_t)row * cstride + col] = v;
        } else {
          ((ushort*)Cout)[(size_t)row * cstride + col] = f2b(v);
        }
      }
    }
  }
}

// -------- cast fp32 row-major -> bf16 row-major (8 elems/thread) -----------
__global__ __launch_bounds__(256) void cast_kernel(
    const float* __restrict__ x, ushort* __restrict__ out, int total8)
{
  int i = blockIdx.x * 256 + threadIdx.x;
  if (i >= total8) return;
  const float4 a = *(const float4*)(x + (size_t)i * 8);
  const float4 b = *(const float4*)(x + (size_t)i * 8 + 4);
  uint4 o;
  o.x = (uint)f2b(a.x) | ((uint)f2b(a.y) << 16);
  o.y = (uint)f2b(a.z) | ((uint)f2b(a.w) << 16);
  o.z = (uint)f2b(b.x) | ((uint)f2b(b.y) << 16);
  o.w = (uint)f2b(b.z) | ((uint)f2b(b.w) << 16);
  *(uint4*)(out + (size_t)i * 8) = o;
}

// -------- transpose-cast: W fp32 [K][Nw] -> Bt bf16 [Nw][K] ----------------
__global__ __launch_bounds__(256) void tc_kernel(
    const float* __restrict__ W, ushort* __restrict__ Bt, int K, int Nw)
{
  int i = blockIdx.x * 256 + threadIdx.x;
  if (i >= K * Nw) return;
  int n = i / K, k = i - n * K;
  Bt[i] = f2b(W[(size_t)k * Nw + n]);
}

// ------------- fold W (768x512) against att (4x128) into B-matrix rows -----
// Wt1x rows 512+hh (hh<12): {Wdst0·adst0, Wdst1·adst1, Wsrc1·asrc1} (bf16)
// Wt0x rows 512+h  (h<4):   {Wsrc0·asrc0}
__global__ void fold_kernel(const float* __restrict__ Wdst0, const float* __restrict__ adst0,
                            const float* __restrict__ Wdst1, const float* __restrict__ adst1,
                            const float* __restrict__ Wsrc1, const float* __restrict__ asrc1,
                            const float* __restrict__ Wsrc0, const float* __restrict__ asrc0,
                            ushort* __restrict__ Wt1x, ushort* __restrict__ Wt0x)
{
  int idx = blockIdx.x * 256 + threadIdx.x;   // 768*16
  if (idx >= IN_DIM * 16) return;
  int k = idx >> 4, hh = idx & 15;
  const float* W;
  const float* att;
  if (hh < 4)       { W = Wdst0; att = adst0; }
  else if (hh < 8)  { W = Wdst1; att = adst1; }
  else if (hh < 12) { W = Wsrc1; att = asrc1; }
  else              { W = Wsrc0; att = asrc0; }
  int h = hh & 3;
  float s = 0.f;
#pragma unroll 4
  for (int c = 0; c < HID; ++c)
    s += W[(size_t)k * SEM + h * HID + c] * att[h * HID + c];
  if (hh < 12) Wt1x[(size_t)(512 + hh) * IN_DIM + k] = f2b(s);
  else         Wt0x[(size_t)(512 + h) * IN_DIM + k] = f2b(s);
}

// -------- pass 1: degree histogram over unified node space -----------------
__global__ void edge1_kernel(const int* __restrict__ dst0, const int* __restrict__ dst1,
                             int* __restrict__ deg)
{
  int e = blockIdx.x * 256 + threadIdx.x;
  if (e >= 2 * NE) return;
  int d = (e < NE) ? dst0[e] : (dst1[e - NE] + N_USER);
  atomicAdd(&deg[d], 1);
}

// -------- pass 2: scatter src (ushort) into CSR slots ----------------------
__global__ void scatter_kernel(const int* __restrict__ src0, const int* __restrict__ dst0,
                               const int* __restrict__ src1, const int* __restrict__ dst1,
                               const int* __restrict__ rp, int* __restrict__ cur,
                               ushort* __restrict__ scsr)
{
  int e = blockIdx.x * 256 + threadIdx.x;
  if (e >= 2 * NE) return;
  bool p1 = (e >= NE);
  int ee = p1 ? e - NE : e;
  int s = p1 ? src1[ee] : src0[ee];
  int d = p1 ? (dst1[ee] + N_USER) : dst0[ee];
  int pos = rp[d] + atomicAdd(&cur[d], 1);
  scsr[pos] = (ushort)s;
}

// -------- 3-phase scan over deg[0..n) --------------------------------------
__global__ __launch_bounds__(256) void scan1(const int* __restrict__ deg,
                                             int* __restrict__ bsum, int n)
{
  __shared__ int sm[256];
  int b = blockIdx.x, t = threadIdx.x;
  int base = b * 1024 + t * 4;
  int s = 0;
#pragma unroll
  for (int i = 0; i < 4; ++i) if (base + i < n) s += deg[base + i];
  sm[t] = s;
  __syncthreads();
  for (int off = 128; off > 0; off >>= 1) {
    if (t < off) sm[t] += sm[t + off];
    __syncthreads();
  }
  if (t == 0) bsum[b] = sm[0];
}

__global__ __launch_bounds__(128) void scan2(const int* __restrict__ bsum,
                                             int* __restrict__ boff, int nb,
                                             int* __restrict__ rp_tail, int tailval)
{
  __shared__ int sm[128];
  int t = threadIdx.x;
  int v = (t < nb) ? bsum[t] : 0;
  sm[t] = v;
  __syncthreads();
  for (int off = 1; off < 128; off <<= 1) {
    int x = (t >= off) ? sm[t - off] : 0;
    __syncthreads();
    sm[t] += x;
    __syncthreads();
  }
  if (t < nb) boff[t] = sm[t] - v;
  if (t == 0) *rp_tail = tailval;
}

__global__ __launch_bounds__(256) void scan3(const int* __restrict__ deg,
                                             const int* __restrict__ boff,
                                             int* __restrict__ rp, int n)
{
  __shared__ int sm[256];
  int b = blockIdx.x, t = threadIdx.x;
  int base = b * 1024 + t * 4;
  int v[4];
#pragma unroll
  for (int i = 0; i < 4; ++i) v[i] = (base + i < n) ? deg[base + i] : 0;
  int tsum = v[0] + v[1] + v[2] + v[3];
  sm[t] = tsum;
  __syncthreads();
  for (int off = 1; off < 256; off <<= 1) {
    int x = (t >= off) ? sm[t - off] : 0;
    __syncthreads();
    sm[t] += x;
    __syncthreads();
  }
  int run = sm[t] - tsum + boff[b];
#pragma unroll
  for (int i = 0; i < 4; ++i) {
    if (base + i < n) rp[base + i] = run;
    run += v[i];
  }
}

// -------- unified aggregation: ONE WAVE per dst node -----------------------
// Lane owns 8 channels (16B). Per edge: one dwordx4 gather (wave covers the
// full 1KB hs row) + 8 unpack-fma. ev computed on the fly during staging.
// Logits come from the GEMM-fused fp32 logit arrays:
//   logitU[node][16]: cols 0..3 = a_d path0, 4..7 = a_d path1, 8..11 = a_s1
//   logitL[node][16]: cols 0..3 = a_s0
__global__ __launch_bounds__(64) void agg_kernel(
    const ushort* __restrict__ hs0, const ushort* __restrict__ hs1,
    const ushort* __restrict__ srcs,
    const float* __restrict__ logitL, const float* __restrict__ logitU,
    const int* __restrict__ rp,
    const float* __restrict__ bias0, const float* __restrict__ bias1,
    ushort* __restrict__ Zout)
{
  __shared__ ushort s_src[64];
  __shared__ float  s_ev[64][4];
  int node = blockIdx.x, lane = threadIdx.x;
  bool p1 = (node >= N_USER);
  const ushort* hs   = p1 ? hs1 : hs0;
  const float*  bias = p1 ? bias1 : bias0;
  int nd = p1 ? node - N_USER : node;
  float4 ad4 = *(const float4*)(logitU + (size_t)nd * 16 + (p1 ? 4 : 0));
  const float* asbase = p1 ? (logitU + 8) : logitL;
  int h  = lane >> 4;          // head for this lane's channels
  int cb = lane * 8;           // channel base
  float acc[8] = {};
  float dsum = 0.f;
  int jb = rp[node], je = rp[node + 1];
  for (int j0 = jb; j0 < je; j0 += 64) {
    int n = min(64, je - j0);
    __syncthreads();
    if (lane < n) {
      int s = srcs[j0 + lane];
      s_src[lane] = (ushort)s;
      float4 as4 = *(const float4*)(asbase + (size_t)s * 16);
      float v0 = as4.x + ad4.x, v1 = as4.y + ad4.y;
      float v2 = as4.z + ad4.z, v3 = as4.w + ad4.w;
      v0 = (v0 > 0.f) ? v0 : 0.2f * v0;   // leaky_relu(0.2)
      v1 = (v1 > 0.f) ? v1 : 0.2f * v1;
      v2 = (v2 > 0.f) ? v2 : 0.2f * v2;
      v3 = (v3 > 0.f) ? v3 : 0.2f * v3;
      s_ev[lane][0] = expf(v0);
      s_ev[lane][1] = expf(v1);
      s_ev[lane][2] = expf(v2);
      s_ev[lane][3] = expf(v3);
    }
    __syncthreads();
#pragma unroll 2
    for (int j = 0; j < n; ++j) {
      int s = s_src[j];
      float e = s_ev[j][h];
      uint4 pv = *(const uint4*)(hs + (size_t)s * SEM + cb);
      acc[0] += b2f(pv.x & 0xffffu) * e;  acc[1] += b2f(pv.x >> 16) * e;
      acc[2] += b2f(pv.y & 0xffffu) * e;  acc[3] += b2f(pv.y >> 16) * e;
      acc[4] += b2f(pv.z & 0xffffu) * e;  acc[5] += b2f(pv.z >> 16) * e;
      acc[6] += b2f(pv.w & 0xffffu) * e;  acc[7] += b2f(pv.w >> 16) * e;
      dsum += e;
    }
  }
  float inv = 1.f / (dsum + 1e-16f);
  uint4 o;
  uint* op = (uint*)&o;
#pragma unroll
  for (int i = 0; i < 4; ++i) {
    float z0 = acc[2 * i]     * inv + bias[cb + 2 * i];
    float z1 = acc[2 * i + 1] * inv + bias[cb + 2 * i + 1];
    z0 = (z0 > 0.f) ? z0 : expm1f(z0);   // ELU
    z1 = (z1 > 0.f) ? z1 : expm1f(z1);
    op[i] = (uint)f2b(z0) | ((uint)f2b(z1) << 16);
  }
  *(uint4*)(Zout + (size_t)node * SEM + cb) = o;
}

// -------- beta: semantic softmax weights per node (wave per node) ----------
__global__ __launch_bounds__(256) void beta_kernel(
    const ushort* __restrict__ T, const float* __restrict__ b1,
    const float* __restrict__ W2, float2* __restrict__ beta, int n)
{
  int wid = threadIdx.x >> 6, lane = threadIdx.x & 63;
  int node = blockIdx.x * 4 + wid;
  if (node >= n) return;
  const ushort* t0 = T + (size_t)node * HID;
  const ushort* t1 = T + (size_t)(N_USER + node) * HID;
  int j = 2 * lane;
  uint u0 = *(const uint*)(t0 + j);
  uint u1 = *(const uint*)(t1 + j);
  float wa = W2[j], wb = W2[j + 1];
  float ba = b1[j], bb = b1[j + 1];
  float s0 = tanhf(b2f(u0 & 0xffffu) + ba) * wa + tanhf(b2f(u0 >> 16) + bb) * wb;
  float s1 = tanhf(b2f(u1 & 0xffffu) + ba) * wa + tanhf(b2f(u1 >> 16) + bb) * wb;
#pragma unroll
  for (int off = 32; off > 0; off >>= 1) {
    s0 += __shfl_down(s0, off);
    s1 += __shfl_down(s1, off);
  }
  if (lane == 0) {
    float mx = fmaxf(s0, s1);
    float e0 = expf(s0 - mx), e1 = expf(s1 - mx);
    float s = e0 + e1;
    beta[node] = make_float2(e0 / s, e1 / s);
  }
}

extern "C" void kernel_launch(void* const* d_in, const int* in_sizes, int n_in,
                              void* d_out, int out_size, void* d_ws, size_t ws_size,
                              hipStream_t stream)
{
  const float* x_user = (const float*)d_in[0];
  const float* x_llm  = (const float*)d_in[1];
  const int* src0 = (const int*)d_in[2];
  const int* dst0 = (const int*)d_in[3];
  const int* src1 = (const int*)d_in[4];
  const int* dst1 = (const int*)d_in[5];
  const float* Wsrc0 = (const float*)d_in[6];
  const float* Wdst0 = (const float*)d_in[7];
  const float* asrc0 = (const float*)d_in[8];
  const float* adst0 = (const float*)d_in[9];
  const float* bias0 = (const float*)d_in[10];
  const float* Wsrc1 = (const float*)d_in[11];
  const float* Wdst1 = (const float*)d_in[12];
  const float* asrc1 = (const float*)d_in[13];
  const float* adst1 = (const float*)d_in[14];
  const float* bias1 = (const float*)d_in[15];
  const float* sem_W1 = (const float*)d_in[16];
  const float* sem_b1 = (const float*)d_in[17];
  const float* sem_W2 = (const float*)d_in[18];
  const float* out_W  = (const float*)d_in[19];
  const float* out_b  = (const float*)d_in[20];

  char* ws = (char*)d_ws;
  size_t off = 0;
  auto alloc = [&](size_t bytes) -> size_t {
    size_t o = off;
    off += (bytes + 255) & ~(size_t)255;
    return o;
  };

  size_t xbu_off  = alloc((size_t)MP_USER * IN_DIM * 2);   // 76.9 MB (later overlaid by T bf16)
  size_t xbl_off  = alloc((size_t)MP_LLM  * IN_DIM * 2);   // 7.9 MB
  size_t wt0_off  = alloc((size_t)640 * IN_DIM * 2);       // Wt0x: 512 cols + 4 fold + pad
  size_t wt1_off  = alloc((size_t)640 * IN_DIM * 2);       // Wt1x: 512 cols + 12 fold + pad
  size_t wts_off  = alloc((size_t)HID * SEM * 2);
  size_t wto_off  = alloc((size_t)OUT_DIM * SEM * 2);
  size_t hs0_off  = alloc((size_t)MP_LLM  * SEM * 2);      // 5.2 MB
  size_t hs1_off  = alloc((size_t)MP_USER * SEM * 2);      // 51.2 MB
  size_t Z_off    = alloc((size_t)MP_2U   * SEM * 2);      // 102.5 MB
  size_t sc_off   = alloc((size_t)2 * NE * 2);             // src ushort, CSR order
  size_t lgu_off  = alloc((size_t)MP_USER * 16 * 4);       // logitU fp32
  size_t lgl_off  = alloc((size_t)MP_LLM  * 16 * 4);       // logitL fp32
  size_t beta_off = alloc((size_t)MP_USER * 8);            // float2 per node
  size_t deg_off  = alloc((size_t)2 * N_USER * 4);         // zeroed
  size_t cur_off  = alloc((size_t)2 * N_USER * 4);         // zeroed
  size_t zero_end = off;
  size_t rp_off   = alloc((size_t)(2 * N_USER + 1) * 4);
  size_t bs_off   = alloc((size_t)128 * 4);
  size_t bo_off   = alloc((size_t)128 * 4);

  ushort* xb_u  = (ushort*)(ws + xbu_off);
  ushort* xb_l  = (ushort*)(ws + xbl_off);
  ushort* Wt0x  = (ushort*)(ws + wt0_off);
  ushort* Wt1x  = (ushort*)(ws + wt1_off);
  ushort* WtS   = (ushort*)(ws + wts_off);
  ushort* WtO   = (ushort*)(ws + wto_off);
  ushort* hs0b  = (ushort*)(ws + hs0_off);
  ushort* hs1b  = (ushort*)(ws + hs1_off);
  ushort* Zsw   = (ushort*)(ws + Z_off);
  ushort* Tbuf  = (ushort*)(ws + xbu_off);  // overlay: xb dead after hs GEMMs (bf16 T)
  ushort* scsr  = (ushort*)(ws + sc_off);
  float*  logU  = (float*)(ws + lgu_off);
  float*  logL  = (float*)(ws + lgl_off);
  float2* beta  = (float2*)(ws + beta_off);
  int*    deg   = (int*)(ws + deg_off);     // concatenated [2*N_USER]
  int*    cur   = (int*)(ws + cur_off);
  int*    rp    = (int*)(ws + rp_off);      // [2*N_USER+1]
  int*    bsum  = (int*)(ws + bs_off);
  int*    boff  = (int*)(ws + bo_off);

  hipMemsetAsync(ws + deg_off, 0, zero_end - deg_off, stream);
  // zero padding rows 512..639 of the extended B matrices
  hipMemsetAsync(Wt0x + (size_t)512 * IN_DIM, 0, (size_t)128 * IN_DIM * 2, stream);
  hipMemsetAsync(Wt1x + (size_t)512 * IN_DIM, 0, (size_t)128 * IN_DIM * 2, stream);

  // folds (write bf16 rows 512.. of extended B) + casts + weight transposes
  fold_kernel<<<cdiv(IN_DIM * 16, 256), 256, 0, stream>>>(
      Wdst0, adst0, Wdst1, adst1, Wsrc1, asrc1, Wsrc0, asrc0, Wt1x, Wt0x);
  cast_kernel<<<cdiv(N_USER * IN_DIM / 8, 256), 256, 0, stream>>>(
      x_user, xb_u, N_USER * IN_DIM / 8);
  cast_kernel<<<cdiv(N_LLM * IN_DIM / 8, 256), 256, 0, stream>>>(
      x_llm, xb_l, N_LLM * IN_DIM / 8);
  tc_kernel<<<cdiv(IN_DIM * SEM, 256), 256, 0, stream>>>(Wsrc0, Wt0x, IN_DIM, SEM);
  tc_kernel<<<cdiv(IN_DIM * SEM, 256), 256, 0, stream>>>(Wsrc1, Wt1x, IN_DIM, SEM);
  tc_kernel<<<cdiv(SEM * HID, 256), 256, 0, stream>>>(sem_W1, WtS, SEM, HID);
  tc_kernel<<<cdiv(SEM * OUT_DIM, 256), 256, 0, stream>>>(out_W, WtO, SEM, OUT_DIM);

  // CSR build over unified node space
  const int NTOT = 2 * N_USER;
  const int NB = cdiv(NTOT, 1024);   // 98
  edge1_kernel<<<cdiv(2 * NE, 256), 256, 0, stream>>>(dst0, dst1, deg);
  scan1<<<NB, 256, 0, stream>>>(deg, bsum, NTOT);
  scan2<<<1, 128, 0, stream>>>(bsum, boff, NB, rp + NTOT, 2 * NE);
  scan3<<<NB, 256, 0, stream>>>(deg, boff, rp, NTOT);
  scatter_kernel<<<cdiv(2 * NE, 256), 256, 0, stream>>>(src0, dst0, src1, dst1, rp, cur, scsr);

  // hs GEMMs with fused logit columns (bf16 hs + fp32 logits)
  {
    dim3 g(640 / 128, MP_LLM / 128);
    gemm_bf16<2><<<g, 256, 0, stream>>>(xb_l, Wt0x, hs0b, nullptr, nullptr, logL,
                                        MP_LLM, 640, IN_DIM);
  }
  {
    dim3 g(640 / 128, MP_USER / 128);
    gemm_bf16<2><<<g, 256, 0, stream>>>(xb_u, Wt1x, hs1b, nullptr, nullptr, logU,
                                        MP_USER, 640, IN_DIM);
  }

  // unified aggregation (wave per node) -> bf16 Z
  agg_kernel<<<NTOT, 64, 0, stream>>>(hs0b, hs1b, scsr, logL, logU, rp,
                                      bias0, bias1, Zsw);

  // T = Z @ sem_W1 (bf16 out, overlays dead xb_u)
  {
    dim3 g(HID / 128, MP_2U / 128);
    gemm_bf16<0><<<g, 256, 0, stream>>>(Zsw, WtS, Tbuf, nullptr, nullptr, nullptr,
                                        MP_2U, HID, SEM);
  }

  // semantic softmax weights
  beta_kernel<<<cdiv(N_USER, 4), 256, 0, stream>>>(Tbuf, sem_b1, sem_W2, beta, N_USER);

  // out = (beta0*Z0 + beta1*Z1) @ out_W + out_b  (A fused in staging)
  {
    dim3 g(OUT_DIM / 128, MP_USER / 128);
    gemm_bf16<3><<<g, 256, 0, stream>>>(Zsw, WtO, (float*)d_out, out_b, beta, nullptr,
                                        N_USER, OUT_DIM, SEM);
  }
}

// Round 8
// 477.322 us; speedup vs baseline: 4.2882x; 1.0222x over previous
//
#include <hip/hip_runtime.h>
#include <hip/hip_bf16.h>
#include <math.h>

constexpr int IN_DIM  = 768;
constexpr int HID     = 128;
constexpr int OUT_DIM = 256;
constexpr int SEM     = 512;     // HID*HEADS
constexpr int N_USER  = 50000;
constexpr int N_LLM   = 5000;
constexpr int NE      = 400000;

constexpr int MP_USER = 50048;   // 391*128
constexpr int MP_LLM  = 5120;    // 40*128
constexpr int MP_2U   = 100096;  // 782*128

typedef unsigned int uint;
typedef unsigned short ushort;
typedef __attribute__((ext_vector_type(8))) short bf16x8;
typedef __attribute__((ext_vector_type(4))) float f32x4;

static inline int cdiv(int a, int b) { return (a + b - 1) / b; }

__device__ __forceinline__ ushort f2b(float f) {
  uint u = __float_as_uint(f);
  u += 0x7FFFu + ((u >> 16) & 1u);       // RNE
  return (ushort)(u >> 16);
}
__device__ __forceinline__ float b2f(uint bits16) {
  return __uint_as_float(bits16 << 16);
}

__device__ __forceinline__ float fexp2(float x) { return __builtin_amdgcn_exp2f(x); }
#define LOG2E 1.4426950408889634f

#define GLOAD_LDS16(g, l) __builtin_amdgcn_global_load_lds( \
    (const __attribute__((address_space(1))) void*)(g), \
    (__attribute__((address_space(3))) void*)(l), 16, 0, 0)

// ---------------- bf16 MFMA GEMM: C[M,N] = A[Mpad,K] @ Bt[N,K]^T -----------
// 128x128 tile, BK=64, 256 threads (4 waves, 2x2 of 64x64 each).
// MODE 0: bf16 store (stride N), no guard.
// MODE 1: f32 +bias store (stride N), row<Mreal guard.
// MODE 2: split — col-tiles 0..gx-2 store bf16 (stride N-128); last col-tile
//         stores cols 0..15 as f32 into logit[row][16]. (hs GEMM + logits)
// MODE 3: A synthesized as beta.x*Z[row] + beta.y*Z[row+N_USER] (reg-staged,
//         ds_write); f32 +bias store, guarded. (fused combine + out-GEMM)
template<int MODE>
__global__ __launch_bounds__(256) void gemm_bf16(
    const ushort* __restrict__ A, const ushort* __restrict__ Bt,
    void* __restrict__ Cout, const float* __restrict__ bias,
    const float2* __restrict__ beta, float* __restrict__ logit,
    int Mreal, int N, int K)
{
  __shared__ ushort As[128][64];   // 16 KB
  __shared__ ushort Bs[128][64];   // 16 KB
  const int t = threadIdx.x;
  const int wid = t >> 6, lane = t & 63;

  // bijective XCD-aware swizzle (m204)
  const int nwg  = gridDim.x * gridDim.y;
  const int orig = blockIdx.y * gridDim.x + blockIdx.x;
  const int q = nwg >> 3, r = nwg & 7;
  const int xcd = orig & 7, idx = orig >> 3;
  const int swz = (xcd < r ? xcd * (q + 1) : r * (q + 1) + (xcd - r) * q) + idx;
  const int bxi = swz % gridDim.x, byi = swz / gridDim.x;

  const int bm = byi * 128, bn = bxi * 128;
  const int lr = lane & 15, kg = lane >> 4;
  const int mbase = (wid >> 1) * 64, nbase = (wid & 1) * 64;
  const int grow = lane >> 3;          // 0..7 within chunk
  const int gcol = (lane & 7) * 8;     // element col, 16B granules

  f32x4 acc[4][4] = {};

  for (int k0 = 0; k0 < K; k0 += 64) {
#pragma unroll
    for (int c = 0; c < 4; ++c) {
      int ch = wid * 4 + c;            // 0..15, rows ch*8..ch*8+7
      const ushort* gb = Bt + (size_t)(bn + ch * 8 + grow) * K + k0 + gcol;
      GLOAD_LDS16(gb, &Bs[ch * 8][0]);
      if (MODE != 3) {
        const ushort* ga = A + (size_t)(bm + ch * 8 + grow) * K + k0 + gcol;
        GLOAD_LDS16(ga, &As[ch * 8][0]);
      }
    }
    if (MODE == 3) {
#pragma unroll
      for (int c = 0; c < 4; ++c) {
        int ch = wid * 4 + c;
        int rl = ch * 8 + grow;        // 0..127
        int row = bm + rl;
        const ushort* z0p = A + (size_t)row * SEM + k0 + gcol;
        const ushort* z1p = A + (size_t)(N_USER + row) * SEM + k0 + gcol;
        float2 bb = beta[row];
        uint4 a0 = *(const uint4*)z0p;
        uint4 a1 = *(const uint4*)z1p;
        uint rpk[4];
#pragma unroll
        for (int qq = 0; qq < 4; ++qq) {
          uint x0 = ((const uint*)&a0)[qq], x1 = ((const uint*)&a1)[qq];
          float lo = bb.x * b2f(x0 & 0xffffu) + bb.y * b2f(x1 & 0xffffu);
          float hi = bb.x * b2f(x0 >> 16)     + bb.y * b2f(x1 >> 16);
          rpk[qq] = (uint)f2b(lo) | ((uint)f2b(hi) << 16);
        }
        *(uint4*)&As[rl][gcol] = make_uint4(rpk[0], rpk[1], rpk[2], rpk[3]);
      }
    }
    asm volatile("s_waitcnt vmcnt(0)" ::: "memory");
    __syncthreads();
#pragma unroll
    for (int kb = 0; kb < 2; ++kb) {
      bf16x8 av[4], bv[4];
#pragma unroll
      for (int m = 0; m < 4; ++m)
        av[m] = *(const bf16x8*)&As[mbase + m * 16 + lr][kb * 32 + kg * 8];
#pragma unroll
      for (int n = 0; n < 4; ++n)
        bv[n] = *(const bf16x8*)&Bs[nbase + n * 16 + lr][kb * 32 + kg * 8];
#pragma unroll
      for (int m = 0; m < 4; ++m)
#pragma unroll
        for (int n = 0; n < 4; ++n)
          acc[m][n] = __builtin_amdgcn_mfma_f32_16x16x32_bf16(av[m], bv[n], acc[m][n], 0, 0, 0);
    }
    __syncthreads();
  }

  if (MODE == 2 && bxi == (int)gridDim.x - 1) {
    // logit tile: only cols 0..15 meaningful (B rows 524.. are zero)
    if (nbase == 0) {
#pragma unroll
      for (int m = 0; m < 4; ++m)
#pragma unroll
        for (int j = 0; j < 4; ++j) {
          int row = bm + mbase + m * 16 + kg * 4 + j;
          logit[(size_t)row * 16 + lr] = acc[m][0][j];
        }
    }
    return;
  }

  const int cstride = (MODE == 2) ? (N - 128) : N;
#pragma unroll
  for (int m = 0; m < 4; ++m) {
#pragma unroll
    for (int j = 0; j < 4; ++j) {
      int row = bm + mbase + m * 16 + kg * 4 + j;
      if ((MODE == 1 || MODE == 3) && row >= Mreal) continue;
#pragma unroll
      for (int n = 0; n < 4; ++n) {
        int col = bn + nbase + n * 16 + lr;
        float v = acc[m][n][j];
        if (MODE == 1 || MODE == 3) {
          if (bias) v += bias[col];
          ((float*)Cout)[(size_t)row * cstride + col] = v;
        } else {
          ((ushort*)Cout)[(size_t)row * cstride + col] = f2b(v);
        }
      }
    }
  }
}

// -------- cast fp32 row-major -> bf16 row-major (8 elems/thread) -----------
__global__ __launch_bounds__(256) void cast_kernel(
    const float* __restrict__ x, ushort* __restrict__ out, int total8)
{
  int i = blockIdx.x * 256 + threadIdx.x;
  if (i >= total8) return;
  const float4 a = *(const float4*)(x + (size_t)i * 8);
  const float4 b = *(const float4*)(x + (size_t)i * 8 + 4);
  uint4 o;
  o.x = (uint)f2b(a.x) | ((uint)f2b(a.y) << 16);
  o.y = (uint)f2b(a.z) | ((uint)f2b(a.w) << 16);
  o.z = (uint)f2b(b.x) | ((uint)f2b(b.y) << 16);
  o.w = (uint)f2b(b.z) | ((uint)f2b(b.w) << 16);
  *(uint4*)(out + (size_t)i * 8) = o;
}

// -------- transpose-cast: W fp32 [K][Nw] -> Bt bf16 [Nw][K] ----------------
__global__ __launch_bounds__(256) void tc_kernel(
    const float* __restrict__ W, ushort* __restrict__ Bt, int K, int Nw)
{
  int i = blockIdx.x * 256 + threadIdx.x;
  if (i >= K * Nw) return;
  int n = i / K, k = i - n * K;
  Bt[i] = f2b(W[(size_t)k * Nw + n]);
}

// ------------- fold W (768x512) against att (4x128) into B-matrix rows -----
// Wt1x rows 512+hh (hh<12): {Wdst0·adst0, Wdst1·adst1, Wsrc1·asrc1} (bf16)
// Wt0x rows 512+h  (h<4):   {Wsrc0·asrc0}
__global__ void fold_kernel(const float* __restrict__ Wdst0, const float* __restrict__ adst0,
                            const float* __restrict__ Wdst1, const float* __restrict__ adst1,
                            const float* __restrict__ Wsrc1, const float* __restrict__ asrc1,
                            const float* __restrict__ Wsrc0, const float* __restrict__ asrc0,
                            ushort* __restrict__ Wt1x, ushort* __restrict__ Wt0x)
{
  int idx = blockIdx.x * 256 + threadIdx.x;   // 768*16
  if (idx >= IN_DIM * 16) return;
  int k = idx >> 4, hh = idx & 15;
  const float* W;
  const float* att;
  if (hh < 4)       { W = Wdst0; att = adst0; }
  else if (hh < 8)  { W = Wdst1; att = adst1; }
  else if (hh < 12) { W = Wsrc1; att = asrc1; }
  else              { W = Wsrc0; att = asrc0; }
  int h = hh & 3;
  float s = 0.f;
#pragma unroll 4
  for (int c = 0; c < HID; ++c)
    s += W[(size_t)k * SEM + h * HID + c] * att[h * HID + c];
  if (hh < 12) Wt1x[(size_t)(512 + hh) * IN_DIM + k] = f2b(s);
  else         Wt0x[(size_t)(512 + h) * IN_DIM + k] = f2b(s);
}

// -------- pass 1: degree histogram over unified node space -----------------
__global__ void edge1_kernel(const int* __restrict__ dst0, const int* __restrict__ dst1,
                             int* __restrict__ deg)
{
  int e = blockIdx.x * 256 + threadIdx.x;
  if (e >= 2 * NE) return;
  int d = (e < NE) ? dst0[e] : (dst1[e - NE] + N_USER);
  atomicAdd(&deg[d], 1);
}

// -------- pass 2: scatter src (ushort) into CSR slots ----------------------
__global__ void scatter_kernel(const int* __restrict__ src0, const int* __restrict__ dst0,
                               const int* __restrict__ src1, const int* __restrict__ dst1,
                               const int* __restrict__ rp, int* __restrict__ cur,
                               ushort* __restrict__ scsr)
{
  int e = blockIdx.x * 256 + threadIdx.x;
  if (e >= 2 * NE) return;
  bool p1 = (e >= NE);
  int ee = p1 ? e - NE : e;
  int s = p1 ? src1[ee] : src0[ee];
  int d = p1 ? (dst1[ee] + N_USER) : dst0[ee];
  int pos = rp[d] + atomicAdd(&cur[d], 1);
  scsr[pos] = (ushort)s;
}

// -------- 3-phase scan over deg[0..n) --------------------------------------
__global__ __launch_bounds__(256) void scan1(const int* __restrict__ deg,
                                             int* __restrict__ bsum, int n)
{
  __shared__ int sm[256];
  int b = blockIdx.x, t = threadIdx.x;
  int base = b * 1024 + t * 4;
  int s = 0;
#pragma unroll
  for (int i = 0; i < 4; ++i) if (base + i < n) s += deg[base + i];
  sm[t] = s;
  __syncthreads();
  for (int off = 128; off > 0; off >>= 1) {
    if (t < off) sm[t] += sm[t + off];
    __syncthreads();
  }
  if (t == 0) bsum[b] = sm[0];
}

__global__ __launch_bounds__(128) void scan2(const int* __restrict__ bsum,
                                             int* __restrict__ boff, int nb,
                                             int* __restrict__ rp_tail, int tailval)
{
  __shared__ int sm[128];
  int t = threadIdx.x;
  int v = (t < nb) ? bsum[t] : 0;
  sm[t] = v;
  __syncthreads();
  for (int off = 1; off < 128; off <<= 1) {
    int x = (t >= off) ? sm[t - off] : 0;
    __syncthreads();
    sm[t] += x;
    __syncthreads();
  }
  if (t < nb) boff[t] = sm[t] - v;
  if (t == 0) *rp_tail = tailval;
}

__global__ __launch_bounds__(256) void scan3(const int* __restrict__ deg,
                                             const int* __restrict__ boff,
                                             int* __restrict__ rp, int n)
{
  __shared__ int sm[256];
  int b = blockIdx.x, t = threadIdx.x;
  int base = b * 1024 + t * 4;
  int v[4];
#pragma unroll
  for (int i = 0; i < 4; ++i) v[i] = (base + i < n) ? deg[base + i] : 0;
  int tsum = v[0] + v[1] + v[2] + v[3];
  sm[t] = tsum;
  __syncthreads();
  for (int off = 1; off < 256; off <<= 1) {
    int x = (t >= off) ? sm[t - off] : 0;
    __syncthreads();
    sm[t] += x;
    __syncthreads();
  }
  int run = sm[t] - tsum + boff[b];
#pragma unroll
  for (int i = 0; i < 4; ++i) {
    if (base + i < n) rp[base + i] = run;
    run += v[i];
  }
}

// -------- unified aggregation: ONE WAVE per dst node -----------------------
// Lane owns 8 channels (16B). Per edge: one saddr dwordx4 gather (wave covers
// the full 1KB hs row) + 8 unpack-fma. ev via raw v_exp_f32; gather base
// address on the SALU via readfirstlane (src is wave-uniform per edge).
__global__ __launch_bounds__(64) void agg_kernel(
    const ushort* __restrict__ hs0, const ushort* __restrict__ hs1,
    const ushort* __restrict__ srcs,
    const float* __restrict__ logitL, const float* __restrict__ logitU,
    const int* __restrict__ rp,
    const float* __restrict__ bias0, const float* __restrict__ bias1,
    ushort* __restrict__ Zout)
{
  __shared__ ushort s_src[64];
  __shared__ float  s_ev[64][4];
  int node = blockIdx.x, lane = threadIdx.x;
  bool p1 = (node >= N_USER);
  const ushort* hs   = p1 ? hs1 : hs0;
  const float*  bias = p1 ? bias1 : bias0;
  int nd = p1 ? node - N_USER : node;
  float4 ad4 = *(const float4*)(logitU + (size_t)nd * 16 + (p1 ? 4 : 0));
  // pre-scale by log2(e): exp(x) = exp2(x*LOG2E); leaky slope commutes.
  ad4.x *= LOG2E; ad4.y *= LOG2E; ad4.z *= LOG2E; ad4.w *= LOG2E;
  const float* asbase = p1 ? (logitU + 8) : logitL;
  int h  = lane >> 4;          // head for this lane's channels
  int cb = lane * 8;           // channel base
  float acc[8] = {};
  float dsum = 0.f;
  int jb = rp[node], je = rp[node + 1];
  for (int j0 = jb; j0 < je; j0 += 64) {
    int n = min(64, je - j0);
    __syncthreads();
    if (lane < n) {
      int s = srcs[j0 + lane];
      s_src[lane] = (ushort)s;
      float4 as4 = *(const float4*)(asbase + (size_t)s * 16);
      float v0 = as4.x * LOG2E + ad4.x, v1 = as4.y * LOG2E + ad4.y;
      float v2 = as4.z * LOG2E + ad4.z, v3 = as4.w * LOG2E + ad4.w;
      v0 = (v0 > 0.f) ? v0 : 0.2f * v0;   // leaky_relu(0.2), log2 domain
      v1 = (v1 > 0.f) ? v1 : 0.2f * v1;
      v2 = (v2 > 0.f) ? v2 : 0.2f * v2;
      v3 = (v3 > 0.f) ? v3 : 0.2f * v3;
      s_ev[lane][0] = fexp2(v0);
      s_ev[lane][1] = fexp2(v1);
      s_ev[lane][2] = fexp2(v2);
      s_ev[lane][3] = fexp2(v3);
    }
    __syncthreads();
#pragma unroll 4
    for (int j = 0; j < n; ++j) {
      int s = __builtin_amdgcn_readfirstlane((int)s_src[j]);
      float e = s_ev[j][h];
      const uint4 pv = *(const uint4*)(hs + ((size_t)s << 9) + cb);
      acc[0] += b2f(pv.x & 0xffffu) * e;  acc[1] += b2f(pv.x >> 16) * e;
      acc[2] += b2f(pv.y & 0xffffu) * e;  acc[3] += b2f(pv.y >> 16) * e;
      acc[4] += b2f(pv.z & 0xffffu) * e;  acc[5] += b2f(pv.z >> 16) * e;
      acc[6] += b2f(pv.w & 0xffffu) * e;  acc[7] += b2f(pv.w >> 16) * e;
      dsum += e;
    }
  }
  float inv = 1.f / (dsum + 1e-16f);
  float4 b4a = *(const float4*)(bias + cb);
  float4 b4b = *(const float4*)(bias + cb + 4);
  float bb[8] = { b4a.x, b4a.y, b4a.z, b4a.w, b4b.x, b4b.y, b4b.z, b4b.w };
  uint4 o;
  uint* op = (uint*)&o;
#pragma unroll
  for (int i = 0; i < 4; ++i) {
    float z0 = acc[2 * i]     * inv + bb[2 * i];
    float z1 = acc[2 * i + 1] * inv + bb[2 * i + 1];
    z0 = (z0 > 0.f) ? z0 : fexp2(z0 * LOG2E) - 1.f;   // ELU
    z1 = (z1 > 0.f) ? z1 : fexp2(z1 * LOG2E) - 1.f;
    op[i] = (uint)f2b(z0) | ((uint)f2b(z1) << 16);
  }
  *(uint4*)(Zout + (size_t)node * SEM + cb) = o;
}

// -------- beta: semantic softmax weights per node (wave per node) ----------
__global__ __launch_bounds__(256) void beta_kernel(
    const ushort* __restrict__ T, const float* __restrict__ b1,
    const float* __restrict__ W2, float2* __restrict__ beta, int n)
{
  int wid = threadIdx.x >> 6, lane = threadIdx.x & 63;
  int node = blockIdx.x * 4 + wid;
  if (node >= n) return;
  const ushort* t0 = T + (size_t)node * HID;
  const ushort* t1 = T + (size_t)(N_USER + node) * HID;
  int j = 2 * lane;
  uint u0 = *(const uint*)(t0 + j);
  uint u1 = *(const uint*)(t1 + j);
  float wa = W2[j], wb = W2[j + 1];
  float ba = b1[j], bb = b1[j + 1];
  auto ftanh = [](float x) {
    x = fminf(fmaxf(x, -20.f), 20.f);
    float e = fexp2(2.f * LOG2E * x);
    return (e - 1.f) / (e + 1.f);
  };
  float s0 = ftanh(b2f(u0 & 0xffffu) + ba) * wa + ftanh(b2f(u0 >> 16) + bb) * wb;
  float s1 = ftanh(b2f(u1 & 0xffffu) + ba) * wa + ftanh(b2f(u1 >> 16) + bb) * wb;
#pragma unroll
  for (int off = 32; off > 0; off >>= 1) {
    s0 += __shfl_down(s0, off);
    s1 += __shfl_down(s1, off);
  }
  if (lane == 0) {
    float mx = fmaxf(s0, s1);
    float e0 = fexp2((s0 - mx) * LOG2E), e1 = fexp2((s1 - mx) * LOG2E);
    float s = e0 + e1;
    beta[node] = make_float2(e0 / s, e1 / s);
  }
}

extern "C" void kernel_launch(void* const* d_in, const int* in_sizes, int n_in,
                              void* d_out, int out_size, void* d_ws, size_t ws_size,
                              hipStream_t stream)
{
  const float* x_user = (const float*)d_in[0];
  const float* x_llm  = (const float*)d_in[1];
  const int* src0 = (const int*)d_in[2];
  const int* dst0 = (const int*)d_in[3];
  const int* src1 = (const int*)d_in[4];
  const int* dst1 = (const int*)d_in[5];
  const float* Wsrc0 = (const float*)d_in[6];
  const float* Wdst0 = (const float*)d_in[7];
  const float* asrc0 = (const float*)d_in[8];
  const float* adst0 = (const float*)d_in[9];
  const float* bias0 = (const float*)d_in[10];
  const float* Wsrc1 = (const float*)d_in[11];
  const float* Wdst1 = (const float*)d_in[12];
  const float* asrc1 = (const float*)d_in[13];
  const float* adst1 = (const float*)d_in[14];
  const float* bias1 = (const float*)d_in[15];
  const float* sem_W1 = (const float*)d_in[16];
  const float* sem_b1 = (const float*)d_in[17];
  const float* sem_W2 = (const float*)d_in[18];
  const float* out_W  = (const float*)d_in[19];
  const float* out_b  = (const float*)d_in[20];

  char* ws = (char*)d_ws;
  size_t off = 0;
  auto alloc = [&](size_t bytes) -> size_t {
    size_t o = off;
    off += (bytes + 255) & ~(size_t)255;
    return o;
  };

  size_t xbu_off  = alloc((size_t)MP_USER * IN_DIM * 2);   // 76.9 MB (later overlaid by T bf16)
  size_t xbl_off  = alloc((size_t)MP_LLM  * IN_DIM * 2);   // 7.9 MB
  size_t wt0_off  = alloc((size_t)640 * IN_DIM * 2);       // Wt0x: 512 cols + 4 fold + pad
  size_t wt1_off  = alloc((size_t)640 * IN_DIM * 2);       // Wt1x: 512 cols + 12 fold + pad
  size_t wts_off  = alloc((size_t)HID * SEM * 2);
  size_t wto_off  = alloc((size_t)OUT_DIM * SEM * 2);
  size_t hs0_off  = alloc((size_t)MP_LLM  * SEM * 2);      // 5.2 MB
  size_t hs1_off  = alloc((size_t)MP_USER * SEM * 2);      // 51.2 MB
  size_t Z_off    = alloc((size_t)MP_2U   * SEM * 2);      // 102.5 MB
  size_t sc_off   = alloc((size_t)2 * NE * 2);             // src ushort, CSR order
  size_t lgu_off  = alloc((size_t)MP_USER * 16 * 4);       // logitU fp32
  size_t lgl_off  = alloc((size_t)MP_LLM  * 16 * 4);       // logitL fp32
  size_t beta_off = alloc((size_t)MP_USER * 8);            // float2 per node
  size_t deg_off  = alloc((size_t)2 * N_USER * 4);         // zeroed
  size_t cur_off  = alloc((size_t)2 * N_USER * 4);         // zeroed
  size_t zero_end = off;
  size_t rp_off   = alloc((size_t)(2 * N_USER + 1) * 4);
  size_t bs_off   = alloc((size_t)128 * 4);
  size_t bo_off   = alloc((size_t)128 * 4);

  ushort* xb_u  = (ushort*)(ws + xbu_off);
  ushort* xb_l  = (ushort*)(ws + xbl_off);
  ushort* Wt0x  = (ushort*)(ws + wt0_off);
  ushort* Wt1x  = (ushort*)(ws + wt1_off);
  ushort* WtS   = (ushort*)(ws + wts_off);
  ushort* WtO   = (ushort*)(ws + wto_off);
  ushort* hs0b  = (ushort*)(ws + hs0_off);
  ushort* hs1b  = (ushort*)(ws + hs1_off);
  ushort* Zsw   = (ushort*)(ws + Z_off);
  ushort* Tbuf  = (ushort*)(ws + xbu_off);  // overlay: xb dead after hs GEMMs (bf16 T)
  ushort* scsr  = (ushort*)(ws + sc_off);
  float*  logU  = (float*)(ws + lgu_off);
  float*  logL  = (float*)(ws + lgl_off);
  float2* beta  = (float2*)(ws + beta_off);
  int*    deg   = (int*)(ws + deg_off);     // concatenated [2*N_USER]
  int*    cur   = (int*)(ws + cur_off);
  int*    rp    = (int*)(ws + rp_off);      // [2*N_USER+1]
  int*    bsum  = (int*)(ws + bs_off);
  int*    boff  = (int*)(ws + bo_off);

  hipMemsetAsync(ws + deg_off, 0, zero_end - deg_off, stream);
  // zero padding rows 512..639 of the extended B matrices
  hipMemsetAsync(Wt0x + (size_t)512 * IN_DIM, 0, (size_t)128 * IN_DIM * 2, stream);
  hipMemsetAsync(Wt1x + (size_t)512 * IN_DIM, 0, (size_t)128 * IN_DIM * 2, stream);

  // folds (write bf16 rows 512.. of extended B) + casts + weight transposes
  fold_kernel<<<cdiv(IN_DIM * 16, 256), 256, 0, stream>>>(
      Wdst0, adst0, Wdst1, adst1, Wsrc1, asrc1, Wsrc0, asrc0, Wt1x, Wt0x);
  cast_kernel<<<cdiv(N_USER * IN_DIM / 8, 256), 256, 0, stream>>>(
      x_user, xb_u, N_USER * IN_DIM / 8);
  cast_kernel<<<cdiv(N_LLM * IN_DIM / 8, 256), 256, 0, stream>>>(
      x_llm, xb_l, N_LLM * IN_DIM / 8);
  tc_kernel<<<cdiv(IN_DIM * SEM, 256), 256, 0, stream>>>(Wsrc0, Wt0x, IN_DIM, SEM);
  tc_kernel<<<cdiv(IN_DIM * SEM, 256), 256, 0, stream>>>(Wsrc1, Wt1x, IN_DIM, SEM);
  tc_kernel<<<cdiv(SEM * HID, 256), 256, 0, stream>>>(sem_W1, WtS, SEM, HID);
  tc_kernel<<<cdiv(SEM * OUT_DIM, 256), 256, 0, stream>>>(out_W, WtO, SEM, OUT_DIM);

  // CSR build over unified node space
  const int NTOT = 2 * N_USER;
  const int NB = cdiv(NTOT, 1024);   // 98
  edge1_kernel<<<cdiv(2 * NE, 256), 256, 0, stream>>>(dst0, dst1, deg);
  scan1<<<NB, 256, 0, stream>>>(deg, bsum, NTOT);
  scan2<<<1, 128, 0, stream>>>(bsum, boff, NB, rp + NTOT, 2 * NE);
  scan3<<<NB, 256, 0, stream>>>(deg, boff, rp, NTOT);
  scatter_kernel<<<cdiv(2 * NE, 256), 256, 0, stream>>>(src0, dst0, src1, dst1, rp, cur, scsr);

  // hs GEMMs with fused logit columns (bf16 hs + fp32 logits)
  {
    dim3 g(640 / 128, MP_LLM / 128);
    gemm_bf16<2><<<g, 256, 0, stream>>>(xb_l, Wt0x, hs0b, nullptr, nullptr, logL,
                                        MP_LLM, 640, IN_DIM);
  }
  {
    dim3 g(640 / 128, MP_USER / 128);
    gemm_bf16<2><<<g, 256, 0, stream>>>(xb_u, Wt1x, hs1b, nullptr, nullptr, logU,
                                        MP_USER, 640, IN_DIM);
  }

  // unified aggregation (wave per node) -> bf16 Z
  agg_kernel<<<NTOT, 64, 0, stream>>>(hs0b, hs1b, scsr, logL, logU, rp,
                                      bias0, bias1, Zsw);

  // T = Z @ sem_W1 (bf16 out, overlays dead xb_u)
  {
    dim3 g(HID / 128, MP_2U / 128);
    gemm_bf16<0><<<g, 256, 0, stream>>>(Zsw, WtS, Tbuf, nullptr, nullptr, nullptr,
                                        MP_2U, HID, SEM);
  }

  // semantic softmax weights
  beta_kernel<<<cdiv(N_USER, 4), 256, 0, stream>>>(Tbuf, sem_b1, sem_W2, beta, N_USER);

  // out = (beta0*Z0 + beta1*Z1) @ out_W + out_b  (A fused in staging)
  {
    dim3 g(OUT_DIM / 128, MP_USER / 128);
    gemm_bf16<3><<<g, 256, 0, stream>>>(Zsw, WtO, (float*)d_out, out_b, beta, nullptr,
                                        N_USER, OUT_DIM, SEM);
  }
}

// Round 10
// 446.861 us; speedup vs baseline: 4.5805x; 1.0682x over previous
//
#include <hip/hip_runtime.h>
#include <hip/hip_bf16.h>
#include <math.h>

constexpr int IN_DIM  = 768;
constexpr int HID     = 128;
constexpr int OUT_DIM = 256;
constexpr int SEM     = 512;     // HID*HEADS
constexpr int N_USER  = 50000;
constexpr int N_LLM   = 5000;
constexpr int NE      = 400000;

constexpr int MP_USER = 50048;   // 391*128
constexpr int MP_LLM  = 5120;    // 40*128
constexpr int MP_2U   = 100096;  // 782*128
constexpr int GY_USER = MP_USER / 128;   // 391
constexpr int GY_LLM  = MP_LLM / 128;    // 40

typedef unsigned int uint;
typedef unsigned short ushort;
typedef __attribute__((ext_vector_type(8))) short bf16x8;
typedef __attribute__((ext_vector_type(4))) float f32x4;

constexpr int cdiv(int a, int b) { return (a + b - 1) / b; }

__device__ __forceinline__ ushort f2b(float f) {
  uint u = __float_as_uint(f);
  u += 0x7FFFu + ((u >> 16) & 1u);       // RNE
  return (ushort)(u >> 16);
}
__device__ __forceinline__ float b2f(uint bits16) {
  return __uint_as_float(bits16 << 16);
}

__device__ __forceinline__ float fexp2(float x) { return __builtin_amdgcn_exp2f(x); }
#define LOG2E 1.4426950408889634f

#define GLOAD_LDS16(g, l) __builtin_amdgcn_global_load_lds( \
    (const __attribute__((address_space(1))) void*)(g), \
    (__attribute__((address_space(3))) void*)(l), 16, 0, 0)

// ---------------- generic bf16 MFMA GEMM (bf16 store) ----------------------
// 128x128 tile, BK=64, 256 threads (4 waves, 2x2 of 64x64 each).
__global__ __launch_bounds__(256) void gemm_bf16_0(
    const ushort* __restrict__ A, const ushort* __restrict__ Bt,
    ushort* __restrict__ Cout, int N, int K)
{
  __shared__ ushort As[128][64];
  __shared__ ushort Bs[128][64];
  const int t = threadIdx.x;
  const int wid = t >> 6, lane = t & 63;

  const int nwg  = gridDim.x * gridDim.y;
  const int orig = blockIdx.y * gridDim.x + blockIdx.x;
  const int q = nwg >> 3, r = nwg & 7;
  const int xcd = orig & 7, idx = orig >> 3;
  const int swz = (xcd < r ? xcd * (q + 1) : r * (q + 1) + (xcd - r) * q) + idx;
  const int bxi = swz % gridDim.x, byi = swz / gridDim.x;

  const int bm = byi * 128, bn = bxi * 128;
  const int lr = lane & 15, kg = lane >> 4;
  const int mbase = (wid >> 1) * 64, nbase = (wid & 1) * 64;
  const int grow = lane >> 3;
  const int gcol = (lane & 7) * 8;

  f32x4 acc[4][4] = {};

  for (int k0 = 0; k0 < K; k0 += 64) {
#pragma unroll
    for (int c = 0; c < 4; ++c) {
      int ch = wid * 4 + c;
      GLOAD_LDS16(A  + (size_t)(bm + ch * 8 + grow) * K + k0 + gcol, &As[ch * 8][0]);
      GLOAD_LDS16(Bt + (size_t)(bn + ch * 8 + grow) * K + k0 + gcol, &Bs[ch * 8][0]);
    }
    asm volatile("s_waitcnt vmcnt(0)" ::: "memory");
    __syncthreads();
#pragma unroll
    for (int kb = 0; kb < 2; ++kb) {
      bf16x8 av[4], bv[4];
#pragma unroll
      for (int m = 0; m < 4; ++m)
        av[m] = *(const bf16x8*)&As[mbase + m * 16 + lr][kb * 32 + kg * 8];
#pragma unroll
      for (int n = 0; n < 4; ++n)
        bv[n] = *(const bf16x8*)&Bs[nbase + n * 16 + lr][kb * 32 + kg * 8];
#pragma unroll
      for (int m = 0; m < 4; ++m)
#pragma unroll
        for (int n = 0; n < 4; ++n)
          acc[m][n] = __builtin_amdgcn_mfma_f32_16x16x32_bf16(av[m], bv[n], acc[m][n], 0, 0, 0);
    }
    __syncthreads();
  }

#pragma unroll
  for (int m = 0; m < 4; ++m)
#pragma unroll
    for (int j = 0; j < 4; ++j) {
      int row = bm + mbase + m * 16 + kg * 4 + j;
#pragma unroll
      for (int n = 0; n < 4; ++n) {
        int col = bn + nbase + n * 16 + lr;
        Cout[(size_t)row * N + col] = f2b(acc[m][n][j]);
      }
    }
}

// ------------- merged hs GEMM (user + llm) with fused logit columns --------
// Grid (5, GY_USER+GY_LLM). N=640: col tiles 0..3 -> bf16 hs (stride 512),
// col tile 4 -> fp32 logit[row][16]. byi >= GY_USER selects the llm problem.
__global__ __launch_bounds__(256) void gemm_hs(
    const ushort* __restrict__ A_u, const ushort* __restrict__ A_l,
    const ushort* __restrict__ Bt_u, const ushort* __restrict__ Bt_l,
    ushort* __restrict__ hs_u, ushort* __restrict__ hs_l,
    float* __restrict__ logU, float* __restrict__ logL)
{
  __shared__ ushort As[128][64];
  __shared__ ushort Bs[128][64];
  const int t = threadIdx.x;
  const int wid = t >> 6, lane = t & 63;
  const int K = IN_DIM;

  const int nwg  = gridDim.x * gridDim.y;
  const int orig = blockIdx.y * gridDim.x + blockIdx.x;
  const int q = nwg >> 3, r = nwg & 7;
  const int xcd = orig & 7, idx = orig >> 3;
  const int swz = (xcd < r ? xcd * (q + 1) : r * (q + 1) + (xcd - r) * q) + idx;
  const int bxi = swz % gridDim.x, byi0 = swz / gridDim.x;

  const bool llm = (byi0 >= GY_USER);
  const int byi = llm ? byi0 - GY_USER : byi0;
  const ushort* A    = llm ? A_l : A_u;
  const ushort* Bt   = llm ? Bt_l : Bt_u;
  ushort* hs         = llm ? hs_l : hs_u;
  float* logit       = llm ? logL : logU;

  const int bm = byi * 128, bn = bxi * 128;
  const int lr = lane & 15, kg = lane >> 4;
  const int mbase = (wid >> 1) * 64, nbase = (wid & 1) * 64;
  const int grow = lane >> 3;
  const int gcol = (lane & 7) * 8;

  f32x4 acc[4][4] = {};

  for (int k0 = 0; k0 < K; k0 += 64) {
#pragma unroll
    for (int c = 0; c < 4; ++c) {
      int ch = wid * 4 + c;
      GLOAD_LDS16(A  + (size_t)(bm + ch * 8 + grow) * K + k0 + gcol, &As[ch * 8][0]);
      GLOAD_LDS16(Bt + (size_t)(bn + ch * 8 + grow) * K + k0 + gcol, &Bs[ch * 8][0]);
    }
    asm volatile("s_waitcnt vmcnt(0)" ::: "memory");
    __syncthreads();
#pragma unroll
    for (int kb = 0; kb < 2; ++kb) {
      bf16x8 av[4], bv[4];
#pragma unroll
      for (int m = 0; m < 4; ++m)
        av[m] = *(const bf16x8*)&As[mbase + m * 16 + lr][kb * 32 + kg * 8];
#pragma unroll
      for (int n = 0; n < 4; ++n)
        bv[n] = *(const bf16x8*)&Bs[nbase + n * 16 + lr][kb * 32 + kg * 8];
#pragma unroll
      for (int m = 0; m < 4; ++m)
#pragma unroll
        for (int n = 0; n < 4; ++n)
          acc[m][n] = __builtin_amdgcn_mfma_f32_16x16x32_bf16(av[m], bv[n], acc[m][n], 0, 0, 0);
    }
    __syncthreads();
  }

  if (bxi == (int)gridDim.x - 1) {
    if (nbase == 0) {
#pragma unroll
      for (int m = 0; m < 4; ++m)
#pragma unroll
        for (int j = 0; j < 4; ++j) {
          int row = bm + mbase + m * 16 + kg * 4 + j;
          logit[(size_t)row * 16 + lr] = acc[m][0][j];
        }
    }
    return;
  }

#pragma unroll
  for (int m = 0; m < 4; ++m)
#pragma unroll
    for (int j = 0; j < 4; ++j) {
      int row = bm + mbase + m * 16 + kg * 4 + j;
#pragma unroll
      for (int n = 0; n < 4; ++n) {
        int col = bn + nbase + n * 16 + lr;
        hs[(size_t)row * SEM + col] = f2b(acc[m][n][j]);
      }
    }
}

// ------------- fused combine + out GEMM: 128x256 tile, single N pass -------
// A synthesized as beta.x*Z[row] + beta.y*Z[row+N_USER]; out fp32 +bias.
__global__ __launch_bounds__(256) void gemm_out(
    const ushort* __restrict__ Z, const ushort* __restrict__ WtO,
    float* __restrict__ out, const float* __restrict__ out_b,
    const float2* __restrict__ beta)
{
  __shared__ ushort As[128][64];   // 16 KB
  __shared__ ushort Bs[256][64];   // 32 KB
  const int t = threadIdx.x;
  const int wid = t >> 6, lane = t & 63;
  const int K = SEM;

  const int nwg  = gridDim.x;
  const int orig = blockIdx.x;
  const int q = nwg >> 3, r = nwg & 7;
  const int xcd = orig & 7, idx = orig >> 3;
  const int swz = (xcd < r ? xcd * (q + 1) : r * (q + 1) + (xcd - r) * q) + idx;

  const int bm = swz * 128;
  const int lr = lane & 15, kg = lane >> 4;
  const int mbase = (wid >> 1) * 64, nbase = (wid & 1) * 128;
  const int grow = lane >> 3;
  const int gcol = (lane & 7) * 8;

  f32x4 acc[4][8] = {};

  for (int k0 = 0; k0 < K; k0 += 64) {
    // Bs: 32 chunks of 8 rows via gload_lds (8 per wave)
#pragma unroll
    for (int c = 0; c < 8; ++c) {
      int ch = wid * 8 + c;            // 0..31
      GLOAD_LDS16(WtO + (size_t)(ch * 8 + grow) * K + k0 + gcol, &Bs[ch * 8][0]);
    }
    // As: 16 chunks of 8 rows, beta-combined in registers (4 per wave)
#pragma unroll
    for (int c = 0; c < 4; ++c) {
      int ch = wid * 4 + c;
      int rl = ch * 8 + grow;          // 0..127
      int row = bm + rl;
      const ushort* z0p = Z + (size_t)row * SEM + k0 + gcol;
      const ushort* z1p = Z + (size_t)(N_USER + row) * SEM + k0 + gcol;
      float2 bb = beta[row];
      uint4 a0 = *(const uint4*)z0p;
      uint4 a1 = *(const uint4*)z1p;
      uint rpk[4];
#pragma unroll
      for (int qq = 0; qq < 4; ++qq) {
        uint x0 = ((const uint*)&a0)[qq], x1 = ((const uint*)&a1)[qq];
        float lo = bb.x * b2f(x0 & 0xffffu) + bb.y * b2f(x1 & 0xffffu);
        float hi = bb.x * b2f(x0 >> 16)     + bb.y * b2f(x1 >> 16);
        rpk[qq] = (uint)f2b(lo) | ((uint)f2b(hi) << 16);
      }
      *(uint4*)&As[rl][gcol] = make_uint4(rpk[0], rpk[1], rpk[2], rpk[3]);
    }
    asm volatile("s_waitcnt vmcnt(0)" ::: "memory");
    __syncthreads();
#pragma unroll
    for (int kb = 0; kb < 2; ++kb) {
      bf16x8 av[4], bv[8];
#pragma unroll
      for (int m = 0; m < 4; ++m)
        av[m] = *(const bf16x8*)&As[mbase + m * 16 + lr][kb * 32 + kg * 8];
#pragma unroll
      for (int n = 0; n < 8; ++n)
        bv[n] = *(const bf16x8*)&Bs[nbase + n * 16 + lr][kb * 32 + kg * 8];
#pragma unroll
      for (int m = 0; m < 4; ++m)
#pragma unroll
        for (int n = 0; n < 8; ++n)
          acc[m][n] = __builtin_amdgcn_mfma_f32_16x16x32_bf16(av[m], bv[n], acc[m][n], 0, 0, 0);
    }
    __syncthreads();
  }

#pragma unroll
  for (int m = 0; m < 4; ++m)
#pragma unroll
    for (int j = 0; j < 4; ++j) {
      int row = bm + mbase + m * 16 + kg * 4 + j;
      if (row >= N_USER) continue;
#pragma unroll
      for (int n = 0; n < 8; ++n) {
        int col = nbase + n * 16 + lr;
        out[(size_t)row * OUT_DIM + col] = acc[m][n][j] + out_b[col];
      }
    }
}

// ---------------- mega prep kernel: fold | casts | transposes | edge1 ------
constexpr int NB_FOLD  = cdiv(IN_DIM * 16, 256);          // 48
constexpr int NB_CASTU = N_USER * IN_DIM / 8 / 256;       // 18750
constexpr int NB_CASTL = N_LLM * IN_DIM / 8 / 256;        // 1875
constexpr int NB_TCW   = IN_DIM * SEM / 256;              // 1536 (x2)
constexpr int NB_TCS   = SEM * HID / 256;                 // 256
constexpr int NB_TCO   = SEM * OUT_DIM / 256;             // 512
constexpr int NB_E1    = cdiv(2 * NE, 256);               // 3125
constexpr int PB0 = NB_FOLD;
constexpr int PB1 = PB0 + NB_CASTU;
constexpr int PB2 = PB1 + NB_CASTL;
constexpr int PB3 = PB2 + NB_TCW;
constexpr int PB4 = PB3 + NB_TCW;
constexpr int PB5 = PB4 + NB_TCS;
constexpr int PB6 = PB5 + NB_TCO;
constexpr int PB7 = PB6 + NB_E1;

__device__ __forceinline__ void tc_body(const float* __restrict__ W,
                                        ushort* __restrict__ Bt,
                                        int K, int Nw, int i)
{
  int n = i / K, k = i - n * K;
  Bt[i] = f2b(W[(size_t)k * Nw + n]);
}

__global__ __launch_bounds__(256) void prep_kernel(
    const float* __restrict__ x_user, const float* __restrict__ x_llm,
    ushort* __restrict__ xb_u, ushort* __restrict__ xb_l,
    const float* __restrict__ Wdst0, const float* __restrict__ adst0,
    const float* __restrict__ Wdst1, const float* __restrict__ adst1,
    const float* __restrict__ Wsrc1, const float* __restrict__ asrc1,
    const float* __restrict__ Wsrc0, const float* __restrict__ asrc0,
    ushort* __restrict__ Wt1x, ushort* __restrict__ Wt0x,
    const float* __restrict__ sem_W1, ushort* __restrict__ WtS,
    const float* __restrict__ out_W, ushort* __restrict__ WtO,
    const int* __restrict__ dst0, const int* __restrict__ dst1,
    int* __restrict__ deg)
{
  const int b = blockIdx.x, t = threadIdx.x;
  if (b < PB0) {
    // ---- fold: W (768x512) . att (4x128) -> bf16 rows 512+ of Wt1x/Wt0x
    int idxg = b * 256 + t;
    if (idxg >= IN_DIM * 16) return;
    int k = idxg >> 4, hh = idxg & 15;
    const float* W;
    const float* att;
    if (hh < 4)       { W = Wdst0; att = adst0; }
    else if (hh < 8)  { W = Wdst1; att = adst1; }
    else if (hh < 12) { W = Wsrc1; att = asrc1; }
    else              { W = Wsrc0; att = asrc0; }
    int h = hh & 3;
    float s = 0.f;
#pragma unroll 4
    for (int c = 0; c < HID; ++c)
      s += W[(size_t)k * SEM + h * HID + c] * att[h * HID + c];
    if (hh < 12) Wt1x[(size_t)(512 + hh) * IN_DIM + k] = f2b(s);
    else         Wt0x[(size_t)(512 + h) * IN_DIM + k] = f2b(s);
  } else if (b < PB1) {
    // ---- cast x_user -> bf16
    int i = (b - PB0) * 256 + t;
    const float4 a = *(const float4*)(x_user + (size_t)i * 8);
    const float4 c = *(const float4*)(x_user + (size_t)i * 8 + 4);
    uint4 o;
    o.x = (uint)f2b(a.x) | ((uint)f2b(a.y) << 16);
    o.y = (uint)f2b(a.z) | ((uint)f2b(a.w) << 16);
    o.z = (uint)f2b(c.x) | ((uint)f2b(c.y) << 16);
    o.w = (uint)f2b(c.z) | ((uint)f2b(c.w) << 16);
    *(uint4*)(xb_u + (size_t)i * 8) = o;
  } else if (b < PB2) {
    int i = (b - PB1) * 256 + t;
    const float4 a = *(const float4*)(x_llm + (size_t)i * 8);
    const float4 c = *(const float4*)(x_llm + (size_t)i * 8 + 4);
    uint4 o;
    o.x = (uint)f2b(a.x) | ((uint)f2b(a.y) << 16);
    o.y = (uint)f2b(a.z) | ((uint)f2b(a.w) << 16);
    o.z = (uint)f2b(c.x) | ((uint)f2b(c.y) << 16);
    o.w = (uint)f2b(c.z) | ((uint)f2b(c.w) << 16);
    *(uint4*)(xb_l + (size_t)i * 8) = o;
  } else if (b < PB3) {
    tc_body(Wsrc0, Wt0x, IN_DIM, SEM, (b - PB2) * 256 + t);
  } else if (b < PB4) {
    tc_body(Wsrc1, Wt1x, IN_DIM, SEM, (b - PB3) * 256 + t);
  } else if (b < PB5) {
    tc_body(sem_W1, WtS, SEM, HID, (b - PB4) * 256 + t);
  } else if (b < PB6) {
    tc_body(out_W, WtO, SEM, OUT_DIM, (b - PB5) * 256 + t);
  } else {
    // ---- edge degree histogram
    int e = (b - PB6) * 256 + t;
    if (e >= 2 * NE) return;
    int d = (e < NE) ? dst0[e] : (dst1[e - NE] + N_USER);
    atomicAdd(&deg[d], 1);
  }
}

// -------- scatter src (ushort) into CSR slots ------------------------------
__global__ void scatter_kernel(const int* __restrict__ src0, const int* __restrict__ dst0,
                               const int* __restrict__ src1, const int* __restrict__ dst1,
                               const int* __restrict__ rp, int* __restrict__ cur,
                               ushort* __restrict__ scsr)
{
  int e = blockIdx.x * 256 + threadIdx.x;
  if (e >= 2 * NE) return;
  bool p1 = (e >= NE);
  int ee = p1 ? e - NE : e;
  int s = p1 ? src1[ee] : src0[ee];
  int d = p1 ? (dst1[ee] + N_USER) : dst0[ee];
  int pos = rp[d] + atomicAdd(&cur[d], 1);
  scsr[pos] = (ushort)s;
}

// -------- 3-phase scan over deg[0..n) --------------------------------------
__global__ __launch_bounds__(256) void scan1(const int* __restrict__ deg,
                                             int* __restrict__ bsum, int n)
{
  __shared__ int sm[256];
  int b = blockIdx.x, t = threadIdx.x;
  int base = b * 1024 + t * 4;
  int s = 0;
#pragma unroll
  for (int i = 0; i < 4; ++i) if (base + i < n) s += deg[base + i];
  sm[t] = s;
  __syncthreads();
  for (int off = 128; off > 0; off >>= 1) {
    if (t < off) sm[t] += sm[t + off];
    __syncthreads();
  }
  if (t == 0) bsum[b] = sm[0];
}

__global__ __launch_bounds__(128) void scan2(const int* __restrict__ bsum,
                                             int* __restrict__ boff, int nb,
                                             int* __restrict__ rp_tail, int tailval)
{
  __shared__ int sm[128];
  int t = threadIdx.x;
  int v = (t < nb) ? bsum[t] : 0;
  sm[t] = v;
  __syncthreads();
  for (int off = 1; off < 128; off <<= 1) {
    int x = (t >= off) ? sm[t - off] : 0;
    __syncthreads();
    sm[t] += x;
    __syncthreads();
  }
  if (t < nb) boff[t] = sm[t] - v;
  if (t == 0) *rp_tail = tailval;
}

__global__ __launch_bounds__(256) void scan3(const int* __restrict__ deg,
                                             const int* __restrict__ boff,
                                             int* __restrict__ rp, int n)
{
  __shared__ int sm[256];
  int b = blockIdx.x, t = threadIdx.x;
  int base = b * 1024 + t * 4;
  int v[4];
#pragma unroll
  for (int i = 0; i < 4; ++i) v[i] = (base + i < n) ? deg[base + i] : 0;
  int tsum = v[0] + v[1] + v[2] + v[3];
  sm[t] = tsum;
  __syncthreads();
  for (int off = 1; off < 256; off <<= 1) {
    int x = (t >= off) ? sm[t - off] : 0;
    __syncthreads();
    sm[t] += x;
    __syncthreads();
  }
  int run = sm[t] - tsum + boff[b];
#pragma unroll
  for (int i = 0; i < 4; ++i) {
    if (base + i < n) rp[base + i] = run;
    run += v[i];
  }
}

// -------- unified aggregation: ONE WAVE per dst node -----------------------
__global__ __launch_bounds__(64) void agg_kernel(
    const ushort* __restrict__ hs0, const ushort* __restrict__ hs1,
    const ushort* __restrict__ srcs,
    const float* __restrict__ logitL, const float* __restrict__ logitU,
    const int* __restrict__ rp,
    const float* __restrict__ bias0, const float* __restrict__ bias1,
    ushort* __restrict__ Zout)
{
  __shared__ ushort s_src[64];
  __shared__ float  s_ev[64][4];
  int node = blockIdx.x, lane = threadIdx.x;
  bool p1 = (node >= N_USER);
  const ushort* hs   = p1 ? hs1 : hs0;
  const float*  bias = p1 ? bias1 : bias0;
  int nd = p1 ? node - N_USER : node;
  float4 ad4 = *(const float4*)(logitU + (size_t)nd * 16 + (p1 ? 4 : 0));
  ad4.x *= LOG2E; ad4.y *= LOG2E; ad4.z *= LOG2E; ad4.w *= LOG2E;
  const float* asbase = p1 ? (logitU + 8) : logitL;
  int h  = lane >> 4;
  int cb = lane * 8;
  float acc[8] = {};
  float dsum = 0.f;
  int jb = rp[node], je = rp[node + 1];
  for (int j0 = jb; j0 < je; j0 += 64) {
    int n = min(64, je - j0);
    __syncthreads();
    if (lane < n) {
      int s = srcs[j0 + lane];
      s_src[lane] = (ushort)s;
      float4 as4 = *(const float4*)(asbase + (size_t)s * 16);
      float v0 = as4.x * LOG2E + ad4.x, v1 = as4.y * LOG2E + ad4.y;
      float v2 = as4.z * LOG2E + ad4.z, v3 = as4.w * LOG2E + ad4.w;
      v0 = (v0 > 0.f) ? v0 : 0.2f * v0;
      v1 = (v1 > 0.f) ? v1 : 0.2f * v1;
      v2 = (v2 > 0.f) ? v2 : 0.2f * v2;
      v3 = (v3 > 0.f) ? v3 : 0.2f * v3;
      s_ev[lane][0] = fexp2(v0);
      s_ev[lane][1] = fexp2(v1);
      s_ev[lane][2] = fexp2(v2);
      s_ev[lane][3] = fexp2(v3);
    }
    __syncthreads();
#pragma unroll 4
    for (int j = 0; j < n; ++j) {
      int s = __builtin_amdgcn_readfirstlane((int)s_src[j]);
      float e = s_ev[j][h];
      const uint4 pv = *(const uint4*)(hs + ((size_t)s << 9) + cb);
      acc[0] += b2f(pv.x & 0xffffu) * e;  acc[1] += b2f(pv.x >> 16) * e;
      acc[2] += b2f(pv.y & 0xffffu) * e;  acc[3] += b2f(pv.y >> 16) * e;
      acc[4] += b2f(pv.z & 0xffffu) * e;  acc[5] += b2f(pv.z >> 16) * e;
      acc[6] += b2f(pv.w & 0xffffu) * e;  acc[7] += b2f(pv.w >> 16) * e;
      dsum += e;
    }
  }
  float inv = 1.f / (dsum + 1e-16f);
  float4 b4a = *(const float4*)(bias + cb);
  float4 b4b = *(const float4*)(bias + cb + 4);
  float bb[8] = { b4a.x, b4a.y, b4a.z, b4a.w, b4b.x, b4b.y, b4b.z, b4b.w };
  uint4 o;
  uint* op = (uint*)&o;
#pragma unroll
  for (int i = 0; i < 4; ++i) {
    float z0 = acc[2 * i]     * inv + bb[2 * i];
    float z1 = acc[2 * i + 1] * inv + bb[2 * i + 1];
    z0 = (z0 > 0.f) ? z0 : fexp2(z0 * LOG2E) - 1.f;
    z1 = (z1 > 0.f) ? z1 : fexp2(z1 * LOG2E) - 1.f;
    op[i] = (uint)f2b(z0) | ((uint)f2b(z1) << 16);
  }
  *(uint4*)(Zout + (size_t)node * SEM + cb) = o;
}

// -------- beta: semantic softmax weights per node (wave per node) ----------
__global__ __launch_bounds__(256) void beta_kernel(
    const ushort* __restrict__ T, const float* __restrict__ b1,
    const float* __restrict__ W2, float2* __restrict__ beta, int n)
{
  int wid = threadIdx.x >> 6, lane = threadIdx.x & 63;
  int node = blockIdx.x * 4 + wid;
  if (node >= n) return;
  const ushort* t0 = T + (size_t)node * HID;
  const ushort* t1 = T + (size_t)(N_USER + node) * HID;
  int j = 2 * lane;
  uint u0 = *(const uint*)(t0 + j);
  uint u1 = *(const uint*)(t1 + j);
  float wa = W2[j], wb = W2[j + 1];
  float ba = b1[j], bb = b1[j + 1];
  auto ftanh = [](float x) {
    x = fminf(fmaxf(x, -20.f), 20.f);
    float e = fexp2(2.f * LOG2E * x);
    return (e - 1.f) / (e + 1.f);
  };
  float s0 = ftanh(b2f(u0 & 0xffffu) + ba) * wa + ftanh(b2f(u0 >> 16) + bb) * wb;
  float s1 = ftanh(b2f(u1 & 0xffffu) + ba) * wa + ftanh(b2f(u1 >> 16) + bb) * wb;
#pragma unroll
  for (int off = 32; off > 0; off >>= 1) {
    s0 += __shfl_down(s0, off);
    s1 += __shfl_down(s1, off);
  }
  if (lane == 0) {
    float mx = fmaxf(s0, s1);
    float e0 = fexp2((s0 - mx) * LOG2E), e1 = fexp2((s1 - mx) * LOG2E);
    float s = e0 + e1;
    beta[node] = make_float2(e0 / s, e1 / s);
  }
}

extern "C" void kernel_launch(void* const* d_in, const int* in_sizes, int n_in,
                              void* d_out, int out_size, void* d_ws, size_t ws_size,
                              hipStream_t stream)
{
  const float* x_user = (const float*)d_in[0];
  const float* x_llm  = (const float*)d_in[1];
  const int* src0 = (const int*)d_in[2];
  const int* dst0 = (const int*)d_in[3];
  const int* src1 = (const int*)d_in[4];
  const int* dst1 = (const int*)d_in[5];
  const float* Wsrc0 = (const float*)d_in[6];
  const float* Wdst0 = (const float*)d_in[7];
  const float* asrc0 = (const float*)d_in[8];
  const float* adst0 = (const float*)d_in[9];
  const float* bias0 = (const float*)d_in[10];
  const float* Wsrc1 = (const float*)d_in[11];
  const float* Wdst1 = (const float*)d_in[12];
  const float* asrc1 = (const float*)d_in[13];
  const float* adst1 = (const float*)d_in[14];
  const float* bias1 = (const float*)d_in[15];
  const float* sem_W1 = (const float*)d_in[16];
  const float* sem_b1 = (const float*)d_in[17];
  const float* sem_W2 = (const float*)d_in[18];
  const float* out_W  = (const float*)d_in[19];
  const float* out_b  = (const float*)d_in[20];

  char* ws = (char*)d_ws;
  size_t off = 0;
  auto alloc = [&](size_t bytes) -> size_t {
    size_t o = off;
    off += (bytes + 255) & ~(size_t)255;
    return o;
  };

  size_t xbu_off  = alloc((size_t)MP_USER * IN_DIM * 2);   // later overlaid by T bf16
  size_t xbl_off  = alloc((size_t)MP_LLM  * IN_DIM * 2);
  size_t wt0_off  = alloc((size_t)640 * IN_DIM * 2);
  size_t wt1_off  = alloc((size_t)640 * IN_DIM * 2);
  size_t wts_off  = alloc((size_t)HID * SEM * 2);
  size_t wto_off  = alloc((size_t)OUT_DIM * SEM * 2);
  size_t hs0_off  = alloc((size_t)MP_LLM  * SEM * 2);
  size_t hs1_off  = alloc((size_t)MP_USER * SEM * 2);
  size_t Z_off    = alloc((size_t)MP_2U   * SEM * 2);
  size_t sc_off   = alloc((size_t)2 * NE * 2);
  size_t lgu_off  = alloc((size_t)MP_USER * 16 * 4);
  size_t lgl_off  = alloc((size_t)MP_LLM  * 16 * 4);
  size_t beta_off = alloc((size_t)MP_USER * 8);
  size_t deg_off  = alloc((size_t)2 * N_USER * 4);         // zeroed
  size_t cur_off  = alloc((size_t)2 * N_USER * 4);         // zeroed
  size_t zero_end = off;
  size_t rp_off   = alloc((size_t)(2 * N_USER + 1) * 4);
  size_t bs_off   = alloc((size_t)128 * 4);
  size_t bo_off   = alloc((size_t)128 * 4);

  ushort* xb_u  = (ushort*)(ws + xbu_off);
  ushort* xb_l  = (ushort*)(ws + xbl_off);
  ushort* Wt0x  = (ushort*)(ws + wt0_off);
  ushort* Wt1x  = (ushort*)(ws + wt1_off);
  ushort* WtS   = (ushort*)(ws + wts_off);
  ushort* WtO   = (ushort*)(ws + wto_off);
  ushort* hs0b  = (ushort*)(ws + hs0_off);
  ushort* hs1b  = (ushort*)(ws + hs1_off);
  ushort* Zsw   = (ushort*)(ws + Z_off);
  ushort* Tbuf  = (ushort*)(ws + xbu_off);  // overlay: xb dead after hs GEMMs
  ushort* scsr  = (ushort*)(ws + sc_off);
  float*  logU  = (float*)(ws + lgu_off);
  float*  logL  = (float*)(ws + lgl_off);
  float2* beta  = (float2*)(ws + beta_off);
  int*    deg   = (int*)(ws + deg_off);
  int*    cur   = (int*)(ws + cur_off);
  int*    rp    = (int*)(ws + rp_off);
  int*    bsum  = (int*)(ws + bs_off);
  int*    boff  = (int*)(ws + bo_off);

  hipMemsetAsync(ws + deg_off, 0, zero_end - deg_off, stream);
  hipMemsetAsync(Wt0x + (size_t)512 * IN_DIM, 0, (size_t)128 * IN_DIM * 2, stream);
  hipMemsetAsync(Wt1x + (size_t)512 * IN_DIM, 0, (size_t)128 * IN_DIM * 2, stream);

  // mega prep: fold + casts + transposes + degree histogram, one launch
  prep_kernel<<<PB7, 256, 0, stream>>>(
      x_user, x_llm, xb_u, xb_l,
      Wdst0, adst0, Wdst1, adst1, Wsrc1, asrc1, Wsrc0, asrc0,
      Wt1x, Wt0x, sem_W1, WtS, out_W, WtO,
      dst0, dst1, deg);

  // CSR build over unified node space
  const int NTOT = 2 * N_USER;
  const int NB = cdiv(NTOT, 1024);   // 98
  scan1<<<NB, 256, 0, stream>>>(deg, bsum, NTOT);
  scan2<<<1, 128, 0, stream>>>(bsum, boff, NB, rp + NTOT, 2 * NE);
  scan3<<<NB, 256, 0, stream>>>(deg, boff, rp, NTOT);
  scatter_kernel<<<cdiv(2 * NE, 256), 256, 0, stream>>>(src0, dst0, src1, dst1, rp, cur, scsr);

  // merged hs GEMMs (user rows + llm rows) with fused logits
  {
    dim3 g(640 / 128, GY_USER + GY_LLM);
    gemm_hs<<<g, 256, 0, stream>>>(xb_u, xb_l, Wt1x, Wt0x, hs1b, hs0b, logU, logL);
  }

  // unified aggregation (wave per node) -> bf16 Z
  agg_kernel<<<NTOT, 64, 0, stream>>>(hs0b, hs1b, scsr, logL, logU, rp,
                                      bias0, bias1, Zsw);

  // T = Z @ sem_W1 (bf16 out, overlays dead xb_u)
  {
    dim3 g(HID / 128, MP_2U / 128);
    gemm_bf16_0<<<g, 256, 0, stream>>>(Zsw, WtS, Tbuf, HID, SEM);
  }

  // semantic softmax weights
  beta_kernel<<<cdiv(N_USER, 4), 256, 0, stream>>>(Tbuf, sem_b1, sem_W2, beta, N_USER);

  // out = (beta0*Z0 + beta1*Z1) @ out_W + out_b, single 128x256 pass
  gemm_out<<<GY_USER, 256, 0, stream>>>(Zsw, WtO, (float*)d_out, out_b, beta);
}

// Round 11
// 390.904 us; speedup vs baseline: 5.2362x; 1.1431x over previous
//
#include <hip/hip_runtime.h>
#include <hip/hip_bf16.h>
#include <math.h>

constexpr int IN_DIM  = 768;
constexpr int HID     = 128;
constexpr int OUT_DIM = 256;
constexpr int SEM     = 512;     // HID*HEADS
constexpr int N_USER  = 50000;
constexpr int N_LLM   = 5000;
constexpr int NE      = 400000;

constexpr int MP_USER = 50048;   // 391*128
constexpr int MP_LLM  = 5120;    // 40*128
constexpr int MP_2U   = 100096;  // 782*128
constexpr int GY_USER = MP_USER / 128;   // 391
constexpr int GY_LLM  = MP_LLM / 128;    // 40

typedef unsigned int uint;
typedef unsigned short ushort;
typedef __attribute__((ext_vector_type(8))) short bf16x8;
typedef __attribute__((ext_vector_type(4))) float f32x4;

constexpr int cdiv(int a, int b) { return (a + b - 1) / b; }

__device__ __forceinline__ ushort f2b(float f) {
  uint u = __float_as_uint(f);
  u += 0x7FFFu + ((u >> 16) & 1u);       // RNE
  return (ushort)(u >> 16);
}
__device__ __forceinline__ float b2f(uint bits16) {
  return __uint_as_float(bits16 << 16);
}

__device__ __forceinline__ float fexp2(float x) { return __builtin_amdgcn_exp2f(x); }
#define LOG2E 1.4426950408889634f

#define GLOAD_LDS16(g, l) __builtin_amdgcn_global_load_lds( \
    (const __attribute__((address_space(1))) void*)(g), \
    (__attribute__((address_space(3))) void*)(l), 16, 0, 0)

// LDS XOR swizzle (T2, rule #21): LDS dest stays linear (gload_lds writes
// base+lane*16); the GLOBAL source slot is pre-permuted so that physical
// 16B-slot s of row r holds logical slot s^(r&7). Reads XOR the slot with
// (row&7), spreading a quarter-wave's 16 lanes across all 32 banks
// (16-way conflict -> 2-way, which is free).

// ---------------- generic bf16 MFMA GEMM (bf16 store) ----------------------
// 128x128 tile, BK=64, 256 threads (4 waves, 2x2 of 64x64 each).
__global__ __launch_bounds__(256) void gemm_bf16_0(
    const ushort* __restrict__ A, const ushort* __restrict__ Bt,
    ushort* __restrict__ Cout, int N, int K)
{
  __shared__ ushort As[128][64];
  __shared__ ushort Bs[128][64];
  const int t = threadIdx.x;
  const int wid = t >> 6, lane = t & 63;

  const int nwg  = gridDim.x * gridDim.y;
  const int orig = blockIdx.y * gridDim.x + blockIdx.x;
  const int q = nwg >> 3, r = nwg & 7;
  const int xcd = orig & 7, idx = orig >> 3;
  const int swz = (xcd < r ? xcd * (q + 1) : r * (q + 1) + (xcd - r) * q) + idx;
  const int bxi = swz % gridDim.x, byi = swz / gridDim.x;

  const int bm = byi * 128, bn = bxi * 128;
  const int lr = lane & 15, kg = lane >> 4;
  const int sw8 = lr & 7;
  const int mbase = (wid >> 1) * 64, nbase = (wid & 1) * 64;
  const int grow = lane >> 3;                         // 0..7
  const int gcol = (((lane & 7) ^ grow)) * 8;         // pre-swizzled source slot

  f32x4 acc[4][4] = {};

  for (int k0 = 0; k0 < K; k0 += 64) {
#pragma unroll
    for (int c = 0; c < 4; ++c) {
      int ch = wid * 4 + c;
      GLOAD_LDS16(A  + (size_t)(bm + ch * 8 + grow) * K + k0 + gcol, &As[ch * 8][0]);
      GLOAD_LDS16(Bt + (size_t)(bn + ch * 8 + grow) * K + k0 + gcol, &Bs[ch * 8][0]);
    }
    asm volatile("s_waitcnt vmcnt(0)" ::: "memory");
    __syncthreads();
#pragma unroll
    for (int kb = 0; kb < 2; ++kb) {
      const int csw = ((kb * 4 + kg) ^ sw8) * 8;      // swizzled read slot
      bf16x8 av[4], bv[4];
#pragma unroll
      for (int m = 0; m < 4; ++m)
        av[m] = *(const bf16x8*)&As[mbase + m * 16 + lr][csw];
#pragma unroll
      for (int n = 0; n < 4; ++n)
        bv[n] = *(const bf16x8*)&Bs[nbase + n * 16 + lr][csw];
#pragma unroll
      for (int m = 0; m < 4; ++m)
#pragma unroll
        for (int n = 0; n < 4; ++n)
          acc[m][n] = __builtin_amdgcn_mfma_f32_16x16x32_bf16(av[m], bv[n], acc[m][n], 0, 0, 0);
    }
    __syncthreads();
  }

#pragma unroll
  for (int m = 0; m < 4; ++m)
#pragma unroll
    for (int j = 0; j < 4; ++j) {
      int row = bm + mbase + m * 16 + kg * 4 + j;
#pragma unroll
      for (int n = 0; n < 4; ++n) {
        int col = bn + nbase + n * 16 + lr;
        Cout[(size_t)row * N + col] = f2b(acc[m][n][j]);
      }
    }
}

// ------------- merged hs GEMM (user + llm) with fused logit columns --------
__global__ __launch_bounds__(256) void gemm_hs(
    const ushort* __restrict__ A_u, const ushort* __restrict__ A_l,
    const ushort* __restrict__ Bt_u, const ushort* __restrict__ Bt_l,
    ushort* __restrict__ hs_u, ushort* __restrict__ hs_l,
    float* __restrict__ logU, float* __restrict__ logL)
{
  __shared__ ushort As[128][64];
  __shared__ ushort Bs[128][64];
  const int t = threadIdx.x;
  const int wid = t >> 6, lane = t & 63;
  const int K = IN_DIM;

  const int nwg  = gridDim.x * gridDim.y;
  const int orig = blockIdx.y * gridDim.x + blockIdx.x;
  const int q = nwg >> 3, r = nwg & 7;
  const int xcd = orig & 7, idx = orig >> 3;
  const int swz = (xcd < r ? xcd * (q + 1) : r * (q + 1) + (xcd - r) * q) + idx;
  const int bxi = swz % gridDim.x, byi0 = swz / gridDim.x;

  const bool llm = (byi0 >= GY_USER);
  const int byi = llm ? byi0 - GY_USER : byi0;
  const ushort* A    = llm ? A_l : A_u;
  const ushort* Bt   = llm ? Bt_l : Bt_u;
  ushort* hs         = llm ? hs_l : hs_u;
  float* logit       = llm ? logL : logU;

  const int bm = byi * 128, bn = bxi * 128;
  const int lr = lane & 15, kg = lane >> 4;
  const int sw8 = lr & 7;
  const int mbase = (wid >> 1) * 64, nbase = (wid & 1) * 64;
  const int grow = lane >> 3;
  const int gcol = (((lane & 7) ^ grow)) * 8;

  f32x4 acc[4][4] = {};

  for (int k0 = 0; k0 < K; k0 += 64) {
#pragma unroll
    for (int c = 0; c < 4; ++c) {
      int ch = wid * 4 + c;
      GLOAD_LDS16(A  + (size_t)(bm + ch * 8 + grow) * K + k0 + gcol, &As[ch * 8][0]);
      GLOAD_LDS16(Bt + (size_t)(bn + ch * 8 + grow) * K + k0 + gcol, &Bs[ch * 8][0]);
    }
    asm volatile("s_waitcnt vmcnt(0)" ::: "memory");
    __syncthreads();
#pragma unroll
    for (int kb = 0; kb < 2; ++kb) {
      const int csw = ((kb * 4 + kg) ^ sw8) * 8;
      bf16x8 av[4], bv[4];
#pragma unroll
      for (int m = 0; m < 4; ++m)
        av[m] = *(const bf16x8*)&As[mbase + m * 16 + lr][csw];
#pragma unroll
      for (int n = 0; n < 4; ++n)
        bv[n] = *(const bf16x8*)&Bs[nbase + n * 16 + lr][csw];
#pragma unroll
      for (int m = 0; m < 4; ++m)
#pragma unroll
        for (int n = 0; n < 4; ++n)
          acc[m][n] = __builtin_amdgcn_mfma_f32_16x16x32_bf16(av[m], bv[n], acc[m][n], 0, 0, 0);
    }
    __syncthreads();
  }

  if (bxi == (int)gridDim.x - 1) {
    if (nbase == 0) {
#pragma unroll
      for (int m = 0; m < 4; ++m)
#pragma unroll
        for (int j = 0; j < 4; ++j) {
          int row = bm + mbase + m * 16 + kg * 4 + j;
          logit[(size_t)row * 16 + lr] = acc[m][0][j];
        }
    }
    return;
  }

#pragma unroll
  for (int m = 0; m < 4; ++m)
#pragma unroll
    for (int j = 0; j < 4; ++j) {
      int row = bm + mbase + m * 16 + kg * 4 + j;
#pragma unroll
      for (int n = 0; n < 4; ++n) {
        int col = bn + nbase + n * 16 + lr;
        hs[(size_t)row * SEM + col] = f2b(acc[m][n][j]);
      }
    }
}

// ------------- fused combine + out GEMM: 128x256 tile, single N pass -------
__global__ __launch_bounds__(256) void gemm_out(
    const ushort* __restrict__ Z, const ushort* __restrict__ WtO,
    float* __restrict__ out, const float* __restrict__ out_b,
    const float2* __restrict__ beta)
{
  __shared__ ushort As[128][64];   // 16 KB
  __shared__ ushort Bs[256][64];   // 32 KB
  const int t = threadIdx.x;
  const int wid = t >> 6, lane = t & 63;
  const int K = SEM;

  const int nwg  = gridDim.x;
  const int orig = blockIdx.x;
  const int q = nwg >> 3, r = nwg & 7;
  const int xcd = orig & 7, idx = orig >> 3;
  const int swz = (xcd < r ? xcd * (q + 1) : r * (q + 1) + (xcd - r) * q) + idx;

  const int bm = swz * 128;
  const int lr = lane & 15, kg = lane >> 4;
  const int sw8 = lr & 7;
  const int mbase = (wid >> 1) * 64, nbase = (wid & 1) * 128;
  const int grow = lane >> 3;
  const int gcol = (((lane & 7) ^ grow)) * 8;
  const int wcol = (((lane & 7) ^ grow)) * 8;   // swizzled ds_write slot

  f32x4 acc[4][8] = {};

  for (int k0 = 0; k0 < K; k0 += 64) {
    // Bs: 32 chunks of 8 rows via gload_lds (8 per wave), source pre-swizzled
#pragma unroll
    for (int c = 0; c < 8; ++c) {
      int ch = wid * 8 + c;            // 0..31
      GLOAD_LDS16(WtO + (size_t)(ch * 8 + grow) * K + k0 + gcol, &Bs[ch * 8][0]);
    }
    // As: 16 chunks of 8 rows, beta-combined in registers, swizzled ds_write
#pragma unroll
    for (int c = 0; c < 4; ++c) {
      int ch = wid * 4 + c;
      int rl = ch * 8 + grow;          // 0..127 ; rl&7 == grow
      int row = bm + rl;
      const ushort* z0p = Z + (size_t)row * SEM + k0 + (lane & 7) * 8;
      const ushort* z1p = Z + (size_t)(N_USER + row) * SEM + k0 + (lane & 7) * 8;
      float2 bb = beta[row];
      uint4 a0 = *(const uint4*)z0p;
      uint4 a1 = *(const uint4*)z1p;
      uint rpk[4];
#pragma unroll
      for (int qq = 0; qq < 4; ++qq) {
        uint x0 = ((const uint*)&a0)[qq], x1 = ((const uint*)&a1)[qq];
        float lo = bb.x * b2f(x0 & 0xffffu) + bb.y * b2f(x1 & 0xffffu);
        float hi = bb.x * b2f(x0 >> 16)     + bb.y * b2f(x1 >> 16);
        rpk[qq] = (uint)f2b(lo) | ((uint)f2b(hi) << 16);
      }
      *(uint4*)&As[rl][wcol] = make_uint4(rpk[0], rpk[1], rpk[2], rpk[3]);
    }
    asm volatile("s_waitcnt vmcnt(0)" ::: "memory");
    __syncthreads();
#pragma unroll
    for (int kb = 0; kb < 2; ++kb) {
      const int csw = ((kb * 4 + kg) ^ sw8) * 8;
      bf16x8 av[4], bv[8];
#pragma unroll
      for (int m = 0; m < 4; ++m)
        av[m] = *(const bf16x8*)&As[mbase + m * 16 + lr][csw];
#pragma unroll
      for (int n = 0; n < 8; ++n)
        bv[n] = *(const bf16x8*)&Bs[nbase + n * 16 + lr][csw];
#pragma unroll
      for (int m = 0; m < 4; ++m)
#pragma unroll
        for (int n = 0; n < 8; ++n)
          acc[m][n] = __builtin_amdgcn_mfma_f32_16x16x32_bf16(av[m], bv[n], acc[m][n], 0, 0, 0);
    }
    __syncthreads();
  }

#pragma unroll
  for (int m = 0; m < 4; ++m)
#pragma unroll
    for (int j = 0; j < 4; ++j) {
      int row = bm + mbase + m * 16 + kg * 4 + j;
      if (row >= N_USER) continue;
#pragma unroll
      for (int n = 0; n < 8; ++n) {
        int col = nbase + n * 16 + lr;
        out[(size_t)row * OUT_DIM + col] = acc[m][n][j] + out_b[col];
      }
    }
}

// NOTE: gemm_out As-write swizzle: lane writes logical slot (lane&7) of row
// rl; physical slot = (lane&7)^(rl&7) = wcol/16B. The z0p/z1p source uses the
// LOGICAL slot (lane&7)*8 since the data itself is being permuted at write.

// ---------------- mega prep kernel: fold | casts | transposes | edge-rank --
constexpr int NB_FOLD  = cdiv(IN_DIM * 16, 256);          // 48
constexpr int NB_CASTU = N_USER * IN_DIM / 8 / 256;       // 18750
constexpr int NB_CASTL = N_LLM * IN_DIM / 8 / 256;        // 1875
constexpr int NB_TCW   = IN_DIM * SEM / 256;              // 1536 (x2)
constexpr int NB_TCS   = SEM * HID / 256;                 // 256
constexpr int NB_TCO   = SEM * OUT_DIM / 256;             // 512
constexpr int NB_E1    = cdiv(2 * NE, 256);               // 3125
constexpr int PB0 = NB_FOLD;
constexpr int PB1 = PB0 + NB_CASTU;
constexpr int PB2 = PB1 + NB_CASTL;
constexpr int PB3 = PB2 + NB_TCW;
constexpr int PB4 = PB3 + NB_TCW;
constexpr int PB5 = PB4 + NB_TCS;
constexpr int PB6 = PB5 + NB_TCO;
constexpr int PB7 = PB6 + NB_E1;

__device__ __forceinline__ void tc_body(const float* __restrict__ W,
                                        ushort* __restrict__ Bt,
                                        int K, int Nw, int i)
{
  int n = i / K, k = i - n * K;
  Bt[i] = f2b(W[(size_t)k * Nw + n]);
}

__global__ __launch_bounds__(256) void prep_kernel(
    const float* __restrict__ x_user, const float* __restrict__ x_llm,
    ushort* __restrict__ xb_u, ushort* __restrict__ xb_l,
    const float* __restrict__ Wdst0, const float* __restrict__ adst0,
    const float* __restrict__ Wdst1, const float* __restrict__ adst1,
    const float* __restrict__ Wsrc1, const float* __restrict__ asrc1,
    const float* __restrict__ Wsrc0, const float* __restrict__ asrc0,
    ushort* __restrict__ Wt1x, ushort* __restrict__ Wt0x,
    const float* __restrict__ sem_W1, ushort* __restrict__ WtS,
    const float* __restrict__ out_W, ushort* __restrict__ WtO,
    const int* __restrict__ dst0, const int* __restrict__ dst1,
    int* __restrict__ deg, int* __restrict__ rank)
{
  const int b = blockIdx.x, t = threadIdx.x;
  if (b < PB0) {
    int idxg = b * 256 + t;
    if (idxg >= IN_DIM * 16) return;
    int k = idxg >> 4, hh = idxg & 15;
    const float* W;
    const float* att;
    if (hh < 4)       { W = Wdst0; att = adst0; }
    else if (hh < 8)  { W = Wdst1; att = adst1; }
    else if (hh < 12) { W = Wsrc1; att = asrc1; }
    else              { W = Wsrc0; att = asrc0; }
    int h = hh & 3;
    float s = 0.f;
#pragma unroll 4
    for (int c = 0; c < HID; ++c)
      s += W[(size_t)k * SEM + h * HID + c] * att[h * HID + c];
    if (hh < 12) Wt1x[(size_t)(512 + hh) * IN_DIM + k] = f2b(s);
    else         Wt0x[(size_t)(512 + h) * IN_DIM + k] = f2b(s);
  } else if (b < PB1) {
    int i = (b - PB0) * 256 + t;
    const float4 a = *(const float4*)(x_user + (size_t)i * 8);
    const float4 c = *(const float4*)(x_user + (size_t)i * 8 + 4);
    uint4 o;
    o.x = (uint)f2b(a.x) | ((uint)f2b(a.y) << 16);
    o.y = (uint)f2b(a.z) | ((uint)f2b(a.w) << 16);
    o.z = (uint)f2b(c.x) | ((uint)f2b(c.y) << 16);
    o.w = (uint)f2b(c.z) | ((uint)f2b(c.w) << 16);
    *(uint4*)(xb_u + (size_t)i * 8) = o;
  } else if (b < PB2) {
    int i = (b - PB1) * 256 + t;
    const float4 a = *(const float4*)(x_llm + (size_t)i * 8);
    const float4 c = *(const float4*)(x_llm + (size_t)i * 8 + 4);
    uint4 o;
    o.x = (uint)f2b(a.x) | ((uint)f2b(a.y) << 16);
    o.y = (uint)f2b(a.z) | ((uint)f2b(a.w) << 16);
    o.z = (uint)f2b(c.x) | ((uint)f2b(c.y) << 16);
    o.w = (uint)f2b(c.z) | ((uint)f2b(c.w) << 16);
    *(uint4*)(xb_l + (size_t)i * 8) = o;
  } else if (b < PB3) {
    tc_body(Wsrc0, Wt0x, IN_DIM, SEM, (b - PB2) * 256 + t);
  } else if (b < PB4) {
    tc_body(Wsrc1, Wt1x, IN_DIM, SEM, (b - PB3) * 256 + t);
  } else if (b < PB5) {
    tc_body(sem_W1, WtS, SEM, HID, (b - PB4) * 256 + t);
  } else if (b < PB6) {
    tc_body(out_W, WtO, SEM, OUT_DIM, (b - PB5) * 256 + t);
  } else {
    // ---- edge degree histogram + per-edge rank (one atomic per edge)
    int e = (b - PB6) * 256 + t;
    if (e >= 2 * NE) return;
    int d = (e < NE) ? dst0[e] : (dst1[e - NE] + N_USER);
    rank[e] = atomicAdd(&deg[d], 1);
  }
}

// -------- scatter src (ushort) into CSR slots — atomic-free ----------------
__global__ void scatter_kernel(const int* __restrict__ src0, const int* __restrict__ dst0,
                               const int* __restrict__ src1, const int* __restrict__ dst1,
                               const int* __restrict__ rp, const int* __restrict__ rank,
                               ushort* __restrict__ scsr)
{
  int e = blockIdx.x * 256 + threadIdx.x;
  if (e >= 2 * NE) return;
  bool p1 = (e >= NE);
  int ee = p1 ? e - NE : e;
  int s = p1 ? src1[ee] : src0[ee];
  int d = p1 ? (dst1[ee] + N_USER) : dst0[ee];
  scsr[rp[d] + rank[e]] = (ushort)s;
}

// -------- 3-phase scan over deg[0..n) --------------------------------------
__global__ __launch_bounds__(256) void scan1(const int* __restrict__ deg,
                                             int* __restrict__ bsum, int n)
{
  __shared__ int sm[256];
  int b = blockIdx.x, t = threadIdx.x;
  int base = b * 1024 + t * 4;
  int s = 0;
#pragma unroll
  for (int i = 0; i < 4; ++i) if (base + i < n) s += deg[base + i];
  sm[t] = s;
  __syncthreads();
  for (int off = 128; off > 0; off >>= 1) {
    if (t < off) sm[t] += sm[t + off];
    __syncthreads();
  }
  if (t == 0) bsum[b] = sm[0];
}

__global__ __launch_bounds__(128) void scan2(const int* __restrict__ bsum,
                                             int* __restrict__ boff, int nb,
                                             int* __restrict__ rp_tail, int tailval)
{
  __shared__ int sm[128];
  int t = threadIdx.x;
  int v = (t < nb) ? bsum[t] : 0;
  sm[t] = v;
  __syncthreads();
  for (int off = 1; off < 128; off <<= 1) {
    int x = (t >= off) ? sm[t - off] : 0;
    __syncthreads();
    sm[t] += x;
    __syncthreads();
  }
  if (t < nb) boff[t] = sm[t] - v;
  if (t == 0) *rp_tail = tailval;
}

__global__ __launch_bounds__(256) void scan3(const int* __restrict__ deg,
                                             const int* __restrict__ boff,
                                             int* __restrict__ rp, int n)
{
  __shared__ int sm[256];
  int b = blockIdx.x, t = threadIdx.x;
  int base = b * 1024 + t * 4;
  int v[4];
#pragma unroll
  for (int i = 0; i < 4; ++i) v[i] = (base + i < n) ? deg[base + i] : 0;
  int tsum = v[0] + v[1] + v[2] + v[3];
  sm[t] = tsum;
  __syncthreads();
  for (int off = 1; off < 256; off <<= 1) {
    int x = (t >= off) ? sm[t - off] : 0;
    __syncthreads();
    sm[t] += x;
    __syncthreads();
  }
  int run = sm[t] - tsum + boff[b];
#pragma unroll
  for (int i = 0; i < 4; ++i) {
    if (base + i < n) rp[base + i] = run;
    run += v[i];
  }
}

// -------- unified aggregation: ONE WAVE per dst node -----------------------
__global__ __launch_bounds__(64) void agg_kernel(
    const ushort* __restrict__ hs0, const ushort* __restrict__ hs1,
    const ushort* __restrict__ srcs,
    const float* __restrict__ logitL, const float* __restrict__ logitU,
    const int* __restrict__ rp,
    const float* __restrict__ bias0, const float* __restrict__ bias1,
    ushort* __restrict__ Zout)
{
  __shared__ ushort s_src[64];
  __shared__ float  s_ev[64][4];
  int node = blockIdx.x, lane = threadIdx.x;
  bool p1 = (node >= N_USER);
  const ushort* hs   = p1 ? hs1 : hs0;
  const float*  bias = p1 ? bias1 : bias0;
  int nd = p1 ? node - N_USER : node;
  float4 ad4 = *(const float4*)(logitU + (size_t)nd * 16 + (p1 ? 4 : 0));
  ad4.x *= LOG2E; ad4.y *= LOG2E; ad4.z *= LOG2E; ad4.w *= LOG2E;
  const float* asbase = p1 ? (logitU + 8) : logitL;
  int h  = lane >> 4;
  int cb = lane * 8;
  float acc[8] = {};
  float dsum = 0.f;
  int jb = rp[node], je = rp[node + 1];
  for (int j0 = jb; j0 < je; j0 += 64) {
    int n = min(64, je - j0);
    __syncthreads();
    if (lane < n) {
      int s = srcs[j0 + lane];
      s_src[lane] = (ushort)s;
      float4 as4 = *(const float4*)(asbase + (size_t)s * 16);
      float v0 = as4.x * LOG2E + ad4.x, v1 = as4.y * LOG2E + ad4.y;
      float v2 = as4.z * LOG2E + ad4.z, v3 = as4.w * LOG2E + ad4.w;
      v0 = (v0 > 0.f) ? v0 : 0.2f * v0;
      v1 = (v1 > 0.f) ? v1 : 0.2f * v1;
      v2 = (v2 > 0.f) ? v2 : 0.2f * v2;
      v3 = (v3 > 0.f) ? v3 : 0.2f * v3;
      s_ev[lane][0] = fexp2(v0);
      s_ev[lane][1] = fexp2(v1);
      s_ev[lane][2] = fexp2(v2);
      s_ev[lane][3] = fexp2(v3);
    }
    __syncthreads();
#pragma unroll 4
    for (int j = 0; j < n; ++j) {
      int s = __builtin_amdgcn_readfirstlane((int)s_src[j]);
      float e = s_ev[j][h];
      const uint4 pv = *(const uint4*)(hs + ((size_t)s << 9) + cb);
      acc[0] += b2f(pv.x & 0xffffu) * e;  acc[1] += b2f(pv.x >> 16) * e;
      acc[2] += b2f(pv.y & 0xffffu) * e;  acc[3] += b2f(pv.y >> 16) * e;
      acc[4] += b2f(pv.z & 0xffffu) * e;  acc[5] += b2f(pv.z >> 16) * e;
      acc[6] += b2f(pv.w & 0xffffu) * e;  acc[7] += b2f(pv.w >> 16) * e;
      dsum += e;
    }
  }
  float inv = 1.f / (dsum + 1e-16f);
  float4 b4a = *(const float4*)(bias + cb);
  float4 b4b = *(const float4*)(bias + cb + 4);
  float bb[8] = { b4a.x, b4a.y, b4a.z, b4a.w, b4b.x, b4b.y, b4b.z, b4b.w };
  uint4 o;
  uint* op = (uint*)&o;
#pragma unroll
  for (int i = 0; i < 4; ++i) {
    float z0 = acc[2 * i]     * inv + bb[2 * i];
    float z1 = acc[2 * i + 1] * inv + bb[2 * i + 1];
    z0 = (z0 > 0.f) ? z0 : fexp2(z0 * LOG2E) - 1.f;
    z1 = (z1 > 0.f) ? z1 : fexp2(z1 * LOG2E) - 1.f;
    op[i] = (uint)f2b(z0) | ((uint)f2b(z1) << 16);
  }
  *(uint4*)(Zout + (size_t)node * SEM + cb) = o;
}

// -------- beta: semantic softmax weights per node (wave per node) ----------
__global__ __launch_bounds__(256) void beta_kernel(
    const ushort* __restrict__ T, const float* __restrict__ b1,
    const float* __restrict__ W2, float2* __restrict__ beta, int n)
{
  int wid = threadIdx.x >> 6, lane = threadIdx.x & 63;
  int node = blockIdx.x * 4 + wid;
  if (node >= n) return;
  const ushort* t0 = T + (size_t)node * HID;
  const ushort* t1 = T + (size_t)(N_USER + node) * HID;
  int j = 2 * lane;
  uint u0 = *(const uint*)(t0 + j);
  uint u1 = *(const uint*)(t1 + j);
  float wa = W2[j], wb = W2[j + 1];
  float ba = b1[j], bb = b1[j + 1];
  auto ftanh = [](float x) {
    x = fminf(fmaxf(x, -20.f), 20.f);
    float e = fexp2(2.f * LOG2E * x);
    return (e - 1.f) / (e + 1.f);
  };
  float s0 = ftanh(b2f(u0 & 0xffffu) + ba) * wa + ftanh(b2f(u0 >> 16) + bb) * wb;
  float s1 = ftanh(b2f(u1 & 0xffffu) + ba) * wa + ftanh(b2f(u1 >> 16) + bb) * wb;
#pragma unroll
  for (int off = 32; off > 0; off >>= 1) {
    s0 += __shfl_down(s0, off);
    s1 += __shfl_down(s1, off);
  }
  if (lane == 0) {
    float mx = fmaxf(s0, s1);
    float e0 = fexp2((s0 - mx) * LOG2E), e1 = fexp2((s1 - mx) * LOG2E);
    float s = e0 + e1;
    beta[node] = make_float2(e0 / s, e1 / s);
  }
}

extern "C" void kernel_launch(void* const* d_in, const int* in_sizes, int n_in,
                              void* d_out, int out_size, void* d_ws, size_t ws_size,
                              hipStream_t stream)
{
  const float* x_user = (const float*)d_in[0];
  const float* x_llm  = (const float*)d_in[1];
  const int* src0 = (const int*)d_in[2];
  const int* dst0 = (const int*)d_in[3];
  const int* src1 = (const int*)d_in[4];
  const int* dst1 = (const int*)d_in[5];
  const float* Wsrc0 = (const float*)d_in[6];
  const float* Wdst0 = (const float*)d_in[7];
  const float* asrc0 = (const float*)d_in[8];
  const float* adst0 = (const float*)d_in[9];
  const float* bias0 = (const float*)d_in[10];
  const float* Wsrc1 = (const float*)d_in[11];
  const float* Wdst1 = (const float*)d_in[12];
  const float* asrc1 = (const float*)d_in[13];
  const float* adst1 = (const float*)d_in[14];
  const float* bias1 = (const float*)d_in[15];
  const float* sem_W1 = (const float*)d_in[16];
  const float* sem_b1 = (const float*)d_in[17];
  const float* sem_W2 = (const float*)d_in[18];
  const float* out_W  = (const float*)d_in[19];
  const float* out_b  = (const float*)d_in[20];

  char* ws = (char*)d_ws;
  size_t off = 0;
  auto alloc = [&](size_t bytes) -> size_t {
    size_t o = off;
    off += (bytes + 255) & ~(size_t)255;
    return o;
  };

  size_t xbu_off  = alloc((size_t)MP_USER * IN_DIM * 2);   // later overlaid by T bf16
  size_t xbl_off  = alloc((size_t)MP_LLM  * IN_DIM * 2);
  size_t wt0_off  = alloc((size_t)640 * IN_DIM * 2);
  size_t wt1_off  = alloc((size_t)640 * IN_DIM * 2);
  size_t wts_off  = alloc((size_t)HID * SEM * 2);
  size_t wto_off  = alloc((size_t)OUT_DIM * SEM * 2);
  size_t hs0_off  = alloc((size_t)MP_LLM  * SEM * 2);
  size_t hs1_off  = alloc((size_t)MP_USER * SEM * 2);
  size_t Z_off    = alloc((size_t)MP_2U   * SEM * 2);
  size_t sc_off   = alloc((size_t)2 * NE * 2);
  size_t rank_off = alloc((size_t)2 * NE * 4);
  size_t lgu_off  = alloc((size_t)MP_USER * 16 * 4);
  size_t lgl_off  = alloc((size_t)MP_LLM  * 16 * 4);
  size_t beta_off = alloc((size_t)MP_USER * 8);
  size_t deg_off  = alloc((size_t)2 * N_USER * 4);         // zeroed
  size_t zero_end = off;
  size_t rp_off   = alloc((size_t)(2 * N_USER + 1) * 4);
  size_t bs_off   = alloc((size_t)128 * 4);
  size_t bo_off   = alloc((size_t)128 * 4);

  ushort* xb_u  = (ushort*)(ws + xbu_off);
  ushort* xb_l  = (ushort*)(ws + xbl_off);
  ushort* Wt0x  = (ushort*)(ws + wt0_off);
  ushort* Wt1x  = (ushort*)(ws + wt1_off);
  ushort* WtS   = (ushort*)(ws + wts_off);
  ushort* WtO   = (ushort*)(ws + wto_off);
  ushort* hs0b  = (ushort*)(ws + hs0_off);
  ushort* hs1b  = (ushort*)(ws + hs1_off);
  ushort* Zsw   = (ushort*)(ws + Z_off);
  ushort* Tbuf  = (ushort*)(ws + xbu_off);  // overlay: xb dead after hs GEMMs
  ushort* scsr  = (ushort*)(ws + sc_off);
  int*    rank  = (int*)(ws + rank_off);
  float*  logU  = (float*)(ws + lgu_off);
  float*  logL  = (float*)(ws + lgl_off);
  float2* beta  = (float2*)(ws + beta_off);
  int*    deg   = (int*)(ws + deg_off);
  int*    rp    = (int*)(ws + rp_off);
  int*    bsum  = (int*)(ws + bs_off);
  int*    boff  = (int*)(ws + bo_off);

  hipMemsetAsync(ws + deg_off, 0, zero_end - deg_off, stream);
  hipMemsetAsync(Wt0x + (size_t)512 * IN_DIM, 0, (size_t)128 * IN_DIM * 2, stream);
  hipMemsetAsync(Wt1x + (size_t)512 * IN_DIM, 0, (size_t)128 * IN_DIM * 2, stream);

  // mega prep: fold + casts + transposes + degree/rank histogram, one launch
  prep_kernel<<<PB7, 256, 0, stream>>>(
      x_user, x_llm, xb_u, xb_l,
      Wdst0, adst0, Wdst1, adst1, Wsrc1, asrc1, Wsrc0, asrc0,
      Wt1x, Wt0x, sem_W1, WtS, out_W, WtO,
      dst0, dst1, deg, rank);

  // CSR build over unified node space
  const int NTOT = 2 * N_USER;
  const int NB = cdiv(NTOT, 1024);   // 98
  scan1<<<NB, 256, 0, stream>>>(deg, bsum, NTOT);
  scan2<<<1, 128, 0, stream>>>(bsum, boff, NB, rp + NTOT, 2 * NE);
  scan3<<<NB, 256, 0, stream>>>(deg, boff, rp, NTOT);
  scatter_kernel<<<cdiv(2 * NE, 256), 256, 0, stream>>>(src0, dst0, src1, dst1, rp, rank, scsr);

  // merged hs GEMMs (user rows + llm rows) with fused logits
  {
    dim3 g(640 / 128, GY_USER + GY_LLM);
    gemm_hs<<<g, 256, 0, stream>>>(xb_u, xb_l, Wt1x, Wt0x, hs1b, hs0b, logU, logL);
  }

  // unified aggregation (wave per node) -> bf16 Z
  agg_kernel<<<NTOT, 64, 0, stream>>>(hs0b, hs1b, scsr, logL, logU, rp,
                                      bias0, bias1, Zsw);

  // T = Z @ sem_W1 (bf16 out, overlays dead xb_u)
  {
    dim3 g(HID / 128, MP_2U / 128);
    gemm_bf16_0<<<g, 256, 0, stream>>>(Zsw, WtS, Tbuf, HID, SEM);
  }

  // semantic softmax weights
  beta_kernel<<<cdiv(N_USER, 4), 256, 0, stream>>>(Tbuf, sem_b1, sem_W2, beta, N_USER);

  // out = (beta0*Z0 + beta1*Z1) @ out_W + out_b, single 128x256 pass
  gemm_out<<<GY_USER, 256, 0, stream>>>(Zsw, WtO, (float*)d_out, out_b, beta);
}